// Round 1
// baseline (1185.061 us; speedup 1.0000x reference)
//
#include <hip/hip_runtime.h>
#include <hip/hip_bf16.h>
#include <math.h>

#define BATCH 16
#define NNODE 1024
#define DIM   512
#define KNN   16
#define KP1   17
#define NEG   0.2f
#define TILE  64

// ---------------- column mean over nodes: mean[b][d] ----------------
__global__ void colmean_kernel(const float* __restrict__ x, float* __restrict__ mean) {
    int id = blockIdx.x * 256 + threadIdx.x;        // b*DIM + d
    if (id >= BATCH * DIM) return;
    int b = id / DIM, d = id % DIM;
    const float* p = x + (size_t)b * NNODE * DIM + d;
    float s = 0.f;
    for (int n = 0; n < NNODE; ++n) s += p[(size_t)n * DIM];
    mean[id] = s * (1.0f / NNODE);
}

// ---------------- row squared norms of raw pos: sq[b*N+n] ----------------
__global__ void rowsq_kernel(const float* __restrict__ x, float* __restrict__ sq) {
    int row = blockIdx.x * 4 + (threadIdx.x >> 6);  // 4 waves/block
    int lane = threadIdx.x & 63;
    const float* p = x + (size_t)row * DIM;
    float s = 0.f;
    for (int i = lane; i < DIM; i += 64) { float v = p[i]; s += v * v; }
    #pragma unroll
    for (int off = 32; off > 0; off >>= 1) s += __shfl_down(s, off, 64);
    if (lane == 0) sq[row] = s;
}

// ---------------- distance matrix: d2[b][m][n] = sq_m + sq_n - 2 pos_m . pos_n ----------------
__global__ __launch_bounds__(256) void dist_kernel(const float* __restrict__ x,
                                                   const float* __restrict__ sq,
                                                   float* __restrict__ d2) {
    __shared__ float As[16][TILE + 4];
    __shared__ float Bs[16][TILE + 4];
    int b = blockIdx.z;
    int m0 = blockIdx.y * TILE, n0 = blockIdx.x * TILE;
    const float* A = x + (size_t)b * NNODE * DIM;
    int t = threadIdx.x;
    int tx = t & 15, ty = t >> 4;
    float acc[4][4] = {};
    for (int k0 = 0; k0 < DIM; k0 += 16) {
        int m = t >> 2, k4 = (t & 3) * 4;
        float4 v = *(const float4*)(A + (size_t)(m0 + m) * DIM + k0 + k4);
        As[k4 + 0][m] = v.x; As[k4 + 1][m] = v.y; As[k4 + 2][m] = v.z; As[k4 + 3][m] = v.w;
        float4 w = *(const float4*)(A + (size_t)(n0 + m) * DIM + k0 + k4);
        Bs[k4 + 0][m] = w.x; Bs[k4 + 1][m] = w.y; Bs[k4 + 2][m] = w.z; Bs[k4 + 3][m] = w.w;
        __syncthreads();
        #pragma unroll
        for (int kk = 0; kk < 16; ++kk) {
            float4 a4 = *(const float4*)&As[kk][ty * 4];
            float4 b4 = *(const float4*)&Bs[kk][tx * 4];
            acc[0][0] += a4.x * b4.x; acc[0][1] += a4.x * b4.y; acc[0][2] += a4.x * b4.z; acc[0][3] += a4.x * b4.w;
            acc[1][0] += a4.y * b4.x; acc[1][1] += a4.y * b4.y; acc[1][2] += a4.y * b4.z; acc[1][3] += a4.y * b4.w;
            acc[2][0] += a4.z * b4.x; acc[2][1] += a4.z * b4.y; acc[2][2] += a4.z * b4.z; acc[2][3] += a4.z * b4.w;
            acc[3][0] += a4.w * b4.x; acc[3][1] += a4.w * b4.y; acc[3][2] += a4.w * b4.z; acc[3][3] += a4.w * b4.w;
        }
        __syncthreads();
    }
    const float* sqb = sq + b * NNODE;
    #pragma unroll
    for (int i = 0; i < 4; ++i) {
        int m = m0 + ty * 4 + i;
        float sm = sqb[m];
        float4 o;
        float* po = (float*)&o;
        #pragma unroll
        for (int j = 0; j < 4; ++j) {
            int n = n0 + tx * 4 + j;
            float val = sm + sqb[n] - 2.f * acc[i][j];
            if (m == n) val = INFINITY;
            po[j] = val;
        }
        *(float4*)(d2 + ((size_t)b * NNODE + m) * NNODE + n0 + tx * 4) = o;
    }
}

// ---------------- top-16 smallest per row (self already INF) ----------------
__global__ __launch_bounds__(256) void knn_kernel(const float* __restrict__ d2, int* __restrict__ nbr) {
    __shared__ float row[NNODE];
    __shared__ float rv[256];
    __shared__ int   ri[256];
    int id = blockIdx.x;                 // b*N + n
    int n = id & (NNODE - 1);
    const float* src = d2 + (size_t)id * NNODE;
    int t = threadIdx.x;
    *(float4*)&row[t * 4] = *(const float4*)(src + t * 4);
    __syncthreads();
    int* dst = nbr + id * KP1;
    for (int it = 0; it < KNN; ++it) {
        float bv = INFINITY; int bi = NNODE;
        #pragma unroll
        for (int jo = 0; jo < 4; ++jo) {
            int j = t * 4 + jo;
            float v = row[j];
            if (v < bv) { bv = v; bi = j; }     // strict < keeps lowest index on ties
        }
        rv[t] = bv; ri[t] = bi;
        __syncthreads();
        for (int s = 128; s > 0; s >>= 1) {
            if (t < s) {
                float ov = rv[t + s]; int oi = ri[t + s];
                if (ov < rv[t] || (ov == rv[t] && oi < ri[t])) { rv[t] = ov; ri[t] = oi; }
            }
            __syncthreads();
        }
        if (t == 0) { dst[it] = ri[0]; row[ri[0]] = INFINITY; }
        __syncthreads();
    }
    if (t == 0) dst[KNN] = n;            // self loop
}

// ---------------- per-graph max|x - mean| ----------------
__global__ void init_maxabs(unsigned* maxabs) { if (threadIdx.x < BATCH) maxabs[threadIdx.x] = 0u; }

__global__ __launch_bounds__(256) void maxabs_kernel(const float* __restrict__ x,
                                                     const float* __restrict__ mean,
                                                     unsigned* __restrict__ maxabs) {
    int b = blockIdx.y;
    const float* p = x + ((size_t)b * NNODE + blockIdx.x * 64) * DIM;
    const float* mb = mean + b * DIM;
    float m = 0.f;
    for (int i = threadIdx.x; i < 64 * DIM; i += 256) {
        int d = i & (DIM - 1);
        m = fmaxf(m, fabsf(p[i] - mb[d]));
    }
    __shared__ float red[256];
    red[threadIdx.x] = m; __syncthreads();
    for (int s = 128; s > 0; s >>= 1) {
        if (threadIdx.x < s) red[threadIdx.x] = fmaxf(red[threadIdx.x], red[threadIdx.x + s]);
        __syncthreads();
    }
    if (threadIdx.x == 0) atomicMax(maxabs + b, __float_as_uint(red[0]));
}

// ---------------- h0 = (x - mean) * 0.999999/maxabs ----------------
__global__ void normalize_kernel(const float* __restrict__ x, const float* __restrict__ mean,
                                 const unsigned* __restrict__ maxabs, float* __restrict__ h) {
    int id = blockIdx.x * 256 + threadIdx.x;    // over B*N*D = 8M
    int b = id >> 19;                            // / (N*D)
    int d = id & (DIM - 1);
    float scale = 0.999999f / __uint_as_float(maxabs[b]);
    h[id] = (x[id] - mean[b * DIM + d]) * scale;
}

// ---------------- C[16384x512] = A[16384x512] @ W[512x512] ----------------
__global__ __launch_bounds__(256) void gemm_kernel(const float* __restrict__ Ag,
                                                   const float* __restrict__ Wg,
                                                   float* __restrict__ Cg) {
    __shared__ float As[16][TILE + 4];
    __shared__ float Bs[16][TILE + 4];
    int m0 = blockIdx.y * TILE, n0 = blockIdx.x * TILE;
    int t = threadIdx.x, tx = t & 15, ty = t >> 4;
    float acc[4][4] = {};
    for (int k0 = 0; k0 < DIM; k0 += 16) {
        int m = t >> 2, k4 = (t & 3) * 4;
        float4 v = *(const float4*)(Ag + (size_t)(m0 + m) * DIM + k0 + k4);
        As[k4 + 0][m] = v.x; As[k4 + 1][m] = v.y; As[k4 + 2][m] = v.z; As[k4 + 3][m] = v.w;
        int kb = t >> 4, n4 = (t & 15) * 4;
        *(float4*)&Bs[kb][n4] = *(const float4*)(Wg + (size_t)(k0 + kb) * DIM + n0 + n4);
        __syncthreads();
        #pragma unroll
        for (int kk = 0; kk < 16; ++kk) {
            float4 a4 = *(const float4*)&As[kk][ty * 4];
            float4 b4 = *(const float4*)&Bs[kk][tx * 4];
            acc[0][0] += a4.x * b4.x; acc[0][1] += a4.x * b4.y; acc[0][2] += a4.x * b4.z; acc[0][3] += a4.x * b4.w;
            acc[1][0] += a4.y * b4.x; acc[1][1] += a4.y * b4.y; acc[1][2] += a4.y * b4.z; acc[1][3] += a4.y * b4.w;
            acc[2][0] += a4.z * b4.x; acc[2][1] += a4.z * b4.y; acc[2][2] += a4.z * b4.z; acc[2][3] += a4.z * b4.w;
            acc[3][0] += a4.w * b4.x; acc[3][1] += a4.w * b4.y; acc[3][2] += a4.w * b4.z; acc[3][3] += a4.w * b4.w;
        }
        __syncthreads();
    }
    #pragma unroll
    for (int i = 0; i < 4; ++i) {
        int r = m0 + ty * 4 + i;
        float4 o; o.x = acc[i][0]; o.y = acc[i][1]; o.z = acc[i][2]; o.w = acc[i][3];
        *(float4*)(Cg + (size_t)r * DIM + n0 + tx * 4) = o;
    }
}

// ---------------- a_s = hp @ asrc, a_d = hp @ adst ----------------
__global__ void attvec_kernel(const float* __restrict__ hp, const float* __restrict__ asrc,
                              const float* __restrict__ adst, float* __restrict__ as_,
                              float* __restrict__ ad_) {
    int row = blockIdx.x * 4 + (threadIdx.x >> 6);
    int lane = threadIdx.x & 63;
    const float* p = hp + (size_t)row * DIM;
    float s = 0.f, d = 0.f;
    for (int i = lane; i < DIM; i += 64) { float v = p[i]; s += v * asrc[i]; d += v * adst[i]; }
    #pragma unroll
    for (int off = 32; off > 0; off >>= 1) { s += __shfl_down(s, off, 64); d += __shfl_down(d, off, 64); }
    if (lane == 0) { as_[row] = s; ad_[row] = d; }
}

// ---------------- GAT attention + aggregation (+bias, optional relu) ----------------
template<int RELU>
__global__ __launch_bounds__(256) void aggr_kernel(const float* __restrict__ hp, const int* __restrict__ nbr,
                                                   const float* __restrict__ as_, const float* __restrict__ ad_,
                                                   const float* __restrict__ bias, float* __restrict__ out) {
    int id = blockIdx.x;                 // b*N + n
    int b = id >> 10;
    __shared__ float att[KP1];
    __shared__ int   jj[KP1];
    int t = threadIdx.x;
    if (t < KP1) {
        int j = nbr[id * KP1 + t];
        jj[t] = j;
        float e = as_[b * NNODE + j] + ad_[id];
        att[t] = (e >= 0.f) ? e : NEG * e;
    }
    __syncthreads();
    if (t == 0) {
        float mx = -INFINITY;
        for (int k = 0; k < KP1; ++k) mx = fmaxf(mx, att[k]);
        float s = 0.f;
        for (int k = 0; k < KP1; ++k) { float e = expf(att[k] - mx); att[k] = e; s += e; }
        float inv = 1.f / s;
        for (int k = 0; k < KP1; ++k) att[k] *= inv;
    }
    __syncthreads();
    const float* base = hp + (size_t)b * NNODE * DIM;
    float* orow = out + (size_t)id * DIM;
    for (int d = t; d < DIM; d += 256) {
        float o = bias[d];
        #pragma unroll
        for (int k = 0; k < KP1; ++k) o += att[k] * base[(size_t)jj[k] * DIM + d];
        if (RELU) o = fmaxf(o, 0.f);
        orow[d] = o;
    }
}

// ---------------- global max pool over nodes ----------------
__global__ void maxpool_kernel(const float* __restrict__ h, float* __restrict__ g) {
    int id = blockIdx.x * 256 + threadIdx.x;     // b*DIM + d
    if (id >= BATCH * DIM) return;
    int b = id / DIM, d = id % DIM;
    const float* p = h + (size_t)b * NNODE * DIM + d;
    float m = -INFINITY;
    for (int n = 0; n < NNODE; ++n) m = fmaxf(m, p[(size_t)n * DIM]);
    g[id] = m;
}

// ---------------- final linear g @ Wc + bc ----------------
__global__ void final_kernel(const float* __restrict__ g, const float* __restrict__ Wc,
                             const float* __restrict__ bc, float* __restrict__ out) {
    int b = blockIdx.x, t = threadIdx.x;
    float s0 = 0.f, s1 = 0.f;
    for (int d = t; d < DIM; d += 256) {
        float v = g[b * DIM + d];
        s0 += v * Wc[d * 2 + 0];
        s1 += v * Wc[d * 2 + 1];
    }
    __shared__ float r0[256], r1[256];
    r0[t] = s0; r1[t] = s1; __syncthreads();
    for (int s = 128; s > 0; s >>= 1) {
        if (t < s) { r0[t] += r0[t + s]; r1[t] += r1[t + s]; }
        __syncthreads();
    }
    if (t == 0) { out[b * 2] = r0[0] + bc[0]; out[b * 2 + 1] = r1[0] + bc[1]; }
}

extern "C" void kernel_launch(void* const* d_in, const int* in_sizes, int n_in,
                              void* d_out, int out_size, void* d_ws, size_t ws_size,
                              hipStream_t stream) {
    const float* x     = (const float*)d_in[0];
    const float* W1    = (const float*)d_in[1];
    const float* asrc1 = (const float*)d_in[2];
    const float* adst1 = (const float*)d_in[3];
    const float* b1    = (const float*)d_in[4];
    const float* W2    = (const float*)d_in[5];
    const float* asrc2 = (const float*)d_in[6];
    const float* adst2 = (const float*)d_in[7];
    const float* b2    = (const float*)d_in[8];
    const float* W3    = (const float*)d_in[9];
    const float* asrc3 = (const float*)d_in[10];
    const float* adst3 = (const float*)d_in[11];
    const float* b3    = (const float*)d_in[12];
    const float* Wc    = (const float*)d_in[13];
    const float* bc    = (const float*)d_in[14];
    float* out = (float*)d_out;

    char* ws = (char*)d_ws;
    float* bufA = (float*)ws;                          // 32MB (aliases d2 low)
    float* bufB = (float*)(ws + (32ull << 20));        // 32MB (aliases d2 high)
    float* bufC = (float*)(ws + (64ull << 20));        // 32MB
    float* d2   = (float*)ws;                          // 64MB, dead before bufA written
    size_t off = 96ull << 20;
    int*      nbr    = (int*)(ws + off);      off += (size_t)BATCH * NNODE * KP1 * 4;
    float*    sq     = (float*)(ws + off);    off += (size_t)BATCH * NNODE * 4;
    float*    mean   = (float*)(ws + off);    off += (size_t)BATCH * DIM * 4;
    unsigned* maxabs = (unsigned*)(ws + off); off += 256;
    float*    as_    = (float*)(ws + off);    off += (size_t)BATCH * NNODE * 4;
    float*    ad_    = (float*)(ws + off);    off += (size_t)BATCH * NNODE * 4;
    float*    g      = (float*)(ws + off);    off += (size_t)BATCH * DIM * 4;
    (void)ws_size; (void)in_sizes; (void)n_in; (void)out_size;

    // graph construction
    colmean_kernel<<<32, 256, 0, stream>>>(x, mean);
    rowsq_kernel<<<BATCH * NNODE / 4, 256, 0, stream>>>(x, sq);
    dist_kernel<<<dim3(NNODE / TILE, NNODE / TILE, BATCH), 256, 0, stream>>>(x, sq, d2);
    knn_kernel<<<BATCH * NNODE, 256, 0, stream>>>(d2, nbr);
    // normalize (d2 dead from here)
    init_maxabs<<<1, 64, 0, stream>>>(maxabs);
    maxabs_kernel<<<dim3(16, BATCH), 256, 0, stream>>>(x, mean, maxabs);
    normalize_kernel<<<BATCH * NNODE * DIM / 256, 256, 0, stream>>>(x, mean, maxabs, bufA);

    const int gm = BATCH * NNODE / TILE;   // 256 m-tiles
    // layer 1: A -> hp(B) -> C
    gemm_kernel<<<dim3(DIM / TILE, gm), 256, 0, stream>>>(bufA, W1, bufB);
    attvec_kernel<<<BATCH * NNODE / 4, 256, 0, stream>>>(bufB, asrc1, adst1, as_, ad_);
    aggr_kernel<1><<<BATCH * NNODE, 256, 0, stream>>>(bufB, nbr, as_, ad_, b1, bufC);
    // layer 2: C -> hp(A) -> B
    gemm_kernel<<<dim3(DIM / TILE, gm), 256, 0, stream>>>(bufC, W2, bufA);
    attvec_kernel<<<BATCH * NNODE / 4, 256, 0, stream>>>(bufA, asrc2, adst2, as_, ad_);
    aggr_kernel<1><<<BATCH * NNODE, 256, 0, stream>>>(bufA, nbr, as_, ad_, b2, bufB);
    // layer 3: B -> hp(C) -> A
    gemm_kernel<<<dim3(DIM / TILE, gm), 256, 0, stream>>>(bufB, W3, bufC);
    attvec_kernel<<<BATCH * NNODE / 4, 256, 0, stream>>>(bufC, asrc3, adst3, as_, ad_);
    aggr_kernel<0><<<BATCH * NNODE, 256, 0, stream>>>(bufC, nbr, as_, ad_, b3, bufA);
    // pool + classify
    maxpool_kernel<<<BATCH * DIM / 256, 256, 0, stream>>>(bufA, g);
    final_kernel<<<BATCH, 256, 0, stream>>>(g, Wc, bc, out);
}

// Round 2
// 999.325 us; speedup vs baseline: 1.1859x; 1.1859x over previous
//
#include <hip/hip_runtime.h>
#include <hip/hip_bf16.h>
#include <math.h>

#define BATCH 16
#define NNODE 1024
#define DIM   512
#define KNN   16
#define KP1   17
#define NEG   0.2f
#define BT    128   // block tile for GEMM-shaped kernels

// ---------------- column mean over nodes: mean[b][d] ----------------
__global__ void colmean_kernel(const float* __restrict__ x, float* __restrict__ mean) {
    int id = blockIdx.x * 256 + threadIdx.x;        // b*DIM + d
    if (id >= BATCH * DIM) return;
    int b = id / DIM, d = id % DIM;
    const float* p = x + (size_t)b * NNODE * DIM + d;
    float s = 0.f;
    for (int n = 0; n < NNODE; ++n) s += p[(size_t)n * DIM];
    mean[id] = s * (1.0f / NNODE);
}

// ---------------- row squared norms of raw pos: sq[b*N+n] ----------------
__global__ void rowsq_kernel(const float* __restrict__ x, float* __restrict__ sq) {
    int row = blockIdx.x * 4 + (threadIdx.x >> 6);  // 4 waves/block
    int lane = threadIdx.x & 63;
    const float* p = x + (size_t)row * DIM;
    float s = 0.f;
    for (int i = lane; i < DIM; i += 64) { float v = p[i]; s += v * v; }
    #pragma unroll
    for (int off = 32; off > 0; off >>= 1) s += __shfl_down(s, off, 64);
    if (lane == 0) sq[row] = s;
}

// ---------------- distance matrix, 128x128 tile, 8x8 microtile ----------------
__global__ __launch_bounds__(256) void dist_kernel(const float* __restrict__ x,
                                                   const float* __restrict__ sq,
                                                   float* __restrict__ d2) {
    __shared__ float As[16][BT + 4];
    __shared__ float Bs[16][BT + 4];
    int b = blockIdx.z;
    int m0 = blockIdx.y * BT, n0 = blockIdx.x * BT;
    const float* A = x + (size_t)b * NNODE * DIM;
    int t = threadIdx.x, tx = t & 15, ty = t >> 4;
    float acc[8][8] = {};
    int r = t >> 2, k4 = (t & 3) * 4;
    for (int k0 = 0; k0 < DIM; k0 += 16) {
        float4 va0 = *(const float4*)(A + (size_t)(m0 + r) * DIM + k0 + k4);
        float4 va1 = *(const float4*)(A + (size_t)(m0 + r + 64) * DIM + k0 + k4);
        float4 vb0 = *(const float4*)(A + (size_t)(n0 + r) * DIM + k0 + k4);
        float4 vb1 = *(const float4*)(A + (size_t)(n0 + r + 64) * DIM + k0 + k4);
        As[k4 + 0][r] = va0.x; As[k4 + 1][r] = va0.y; As[k4 + 2][r] = va0.z; As[k4 + 3][r] = va0.w;
        As[k4 + 0][r + 64] = va1.x; As[k4 + 1][r + 64] = va1.y; As[k4 + 2][r + 64] = va1.z; As[k4 + 3][r + 64] = va1.w;
        Bs[k4 + 0][r] = vb0.x; Bs[k4 + 1][r] = vb0.y; Bs[k4 + 2][r] = vb0.z; Bs[k4 + 3][r] = vb0.w;
        Bs[k4 + 0][r + 64] = vb1.x; Bs[k4 + 1][r + 64] = vb1.y; Bs[k4 + 2][r + 64] = vb1.z; Bs[k4 + 3][r + 64] = vb1.w;
        __syncthreads();
        #pragma unroll
        for (int kk = 0; kk < 16; ++kk) {
            float4 a0 = *(const float4*)&As[kk][ty * 4];
            float4 a1 = *(const float4*)&As[kk][ty * 4 + 64];
            float4 b0 = *(const float4*)&Bs[kk][tx * 4];
            float4 b1 = *(const float4*)&Bs[kk][tx * 4 + 64];
            float aa[8] = {a0.x, a0.y, a0.z, a0.w, a1.x, a1.y, a1.z, a1.w};
            float bb[8] = {b0.x, b0.y, b0.z, b0.w, b1.x, b1.y, b1.z, b1.w};
            #pragma unroll
            for (int i = 0; i < 8; ++i)
                #pragma unroll
                for (int j = 0; j < 8; ++j) acc[i][j] += aa[i] * bb[j];
        }
        __syncthreads();
    }
    const float* sqb = sq + b * NNODE;
    #pragma unroll
    for (int ih = 0; ih < 2; ++ih)
    #pragma unroll
    for (int i = 0; i < 4; ++i) {
        int m = m0 + ih * 64 + ty * 4 + i;
        float sm = sqb[m];
        #pragma unroll
        for (int jh = 0; jh < 2; ++jh) {
            float4 o; float* po = (float*)&o;
            #pragma unroll
            for (int j = 0; j < 4; ++j) {
                int n = n0 + jh * 64 + tx * 4 + j;
                float val = sm + sqb[n] - 2.f * acc[ih * 4 + i][jh * 4 + j];
                if (m == n) val = INFINITY;
                po[j] = val;
            }
            *(float4*)(d2 + ((size_t)b * NNODE + m) * NNODE + n0 + jh * 64 + tx * 4) = o;
        }
    }
}

// ---------------- top-16 smallest per row: one wave per row, no barriers ----------------
__global__ __launch_bounds__(256) void knn_kernel(const float* __restrict__ d2, int* __restrict__ nbr) {
    int row = blockIdx.x * 4 + (threadIdx.x >> 6);   // b*N + n
    int l = threadIdx.x & 63;
    const float* src = d2 + (size_t)row * NNODE;
    float v[16];
    #pragma unroll
    for (int j = 0; j < 16; ++j) v[j] = src[l + (j << 6)];
    int* dst = nbr + row * KP1;
    for (int it = 0; it < KNN; ++it) {
        unsigned long long key = ~0ull;
        #pragma unroll
        for (int j = 0; j < 16; ++j) {
            unsigned long long k = ((unsigned long long)__float_as_uint(v[j]) << 32)
                                 | (unsigned)(l + (j << 6));
            if (k < key) key = k;
        }
        #pragma unroll
        for (int off = 1; off < 64; off <<= 1) {
            unsigned long long o = __shfl_xor(key, off, 64);
            if (o < key) key = o;
        }
        int idx = (int)(key & 0xFFFFFFFFull);
        if ((idx & 63) == l) v[idx >> 6] = INFINITY;   // remove winner
        if (l == 0) dst[it] = idx;
    }
    if (l == 0) dst[KNN] = row & (NNODE - 1);          // self loop
}

// ---------------- per-graph max|x - mean| ----------------
__global__ void init_maxabs(unsigned* maxabs) { if (threadIdx.x < BATCH) maxabs[threadIdx.x] = 0u; }

__global__ __launch_bounds__(256) void maxabs_kernel(const float* __restrict__ x,
                                                     const float* __restrict__ mean,
                                                     unsigned* __restrict__ maxabs) {
    int b = blockIdx.y;
    const float* p = x + ((size_t)b * NNODE + blockIdx.x * 64) * DIM;
    const float* mb = mean + b * DIM;
    float m = 0.f;
    for (int i = threadIdx.x; i < 64 * DIM; i += 256) {
        int d = i & (DIM - 1);
        m = fmaxf(m, fabsf(p[i] - mb[d]));
    }
    __shared__ float red[256];
    red[threadIdx.x] = m; __syncthreads();
    for (int s = 128; s > 0; s >>= 1) {
        if (threadIdx.x < s) red[threadIdx.x] = fmaxf(red[threadIdx.x], red[threadIdx.x + s]);
        __syncthreads();
    }
    if (threadIdx.x == 0) atomicMax(maxabs + b, __float_as_uint(red[0]));
}

// ---------------- h0 = (x - mean) * 0.999999/maxabs ----------------
__global__ void normalize_kernel(const float* __restrict__ x, const float* __restrict__ mean,
                                 const unsigned* __restrict__ maxabs, float* __restrict__ h) {
    int id = blockIdx.x * 256 + threadIdx.x;    // over B*N*D = 8M
    int b = id >> 19;                            // / (N*D)
    int d = id & (DIM - 1);
    float scale = 0.999999f / __uint_as_float(maxabs[b]);
    h[id] = (x[id] - mean[b * DIM + d]) * scale;
}

// ---------------- C[16384x512] = A[16384x512] @ W[512x512], 128x128 tile ----------------
__global__ __launch_bounds__(256) void gemm_kernel(const float* __restrict__ Ag,
                                                   const float* __restrict__ Wg,
                                                   float* __restrict__ Cg) {
    __shared__ float As[16][BT + 4];
    __shared__ float Bs[16][BT + 4];
    int m0 = blockIdx.y * BT, n0 = blockIdx.x * BT;
    int t = threadIdx.x, tx = t & 15, ty = t >> 4;
    float acc[8][8] = {};
    int r = t >> 2, k4 = (t & 3) * 4;
    int kb = t >> 4, n4 = (t & 15) * 4;
    for (int k0 = 0; k0 < DIM; k0 += 16) {
        float4 va0 = *(const float4*)(Ag + (size_t)(m0 + r) * DIM + k0 + k4);
        float4 va1 = *(const float4*)(Ag + (size_t)(m0 + r + 64) * DIM + k0 + k4);
        As[k4 + 0][r] = va0.x; As[k4 + 1][r] = va0.y; As[k4 + 2][r] = va0.z; As[k4 + 3][r] = va0.w;
        As[k4 + 0][r + 64] = va1.x; As[k4 + 1][r + 64] = va1.y; As[k4 + 2][r + 64] = va1.z; As[k4 + 3][r + 64] = va1.w;
        *(float4*)&Bs[kb][n4]      = *(const float4*)(Wg + (size_t)(k0 + kb) * DIM + n0 + n4);
        *(float4*)&Bs[kb][n4 + 64] = *(const float4*)(Wg + (size_t)(k0 + kb) * DIM + n0 + n4 + 64);
        __syncthreads();
        #pragma unroll
        for (int kk = 0; kk < 16; ++kk) {
            float4 a0 = *(const float4*)&As[kk][ty * 4];
            float4 a1 = *(const float4*)&As[kk][ty * 4 + 64];
            float4 b0 = *(const float4*)&Bs[kk][tx * 4];
            float4 b1 = *(const float4*)&Bs[kk][tx * 4 + 64];
            float aa[8] = {a0.x, a0.y, a0.z, a0.w, a1.x, a1.y, a1.z, a1.w};
            float bb[8] = {b0.x, b0.y, b0.z, b0.w, b1.x, b1.y, b1.z, b1.w};
            #pragma unroll
            for (int i = 0; i < 8; ++i)
                #pragma unroll
                for (int j = 0; j < 8; ++j) acc[i][j] += aa[i] * bb[j];
        }
        __syncthreads();
    }
    #pragma unroll
    for (int ih = 0; ih < 2; ++ih)
    #pragma unroll
    for (int i = 0; i < 4; ++i) {
        int m = m0 + ih * 64 + ty * 4 + i;
        #pragma unroll
        for (int jh = 0; jh < 2; ++jh) {
            float4 o;
            o.x = acc[ih * 4 + i][jh * 4 + 0];
            o.y = acc[ih * 4 + i][jh * 4 + 1];
            o.z = acc[ih * 4 + i][jh * 4 + 2];
            o.w = acc[ih * 4 + i][jh * 4 + 3];
            *(float4*)(Cg + (size_t)m * DIM + n0 + jh * 64 + tx * 4) = o;
        }
    }
}

// ---------------- a_s = hp @ asrc, a_d = hp @ adst ----------------
__global__ void attvec_kernel(const float* __restrict__ hp, const float* __restrict__ asrc,
                              const float* __restrict__ adst, float* __restrict__ as_,
                              float* __restrict__ ad_) {
    int row = blockIdx.x * 4 + (threadIdx.x >> 6);
    int lane = threadIdx.x & 63;
    const float* p = hp + (size_t)row * DIM;
    float s = 0.f, d = 0.f;
    for (int i = lane; i < DIM; i += 64) { float v = p[i]; s += v * asrc[i]; d += v * adst[i]; }
    #pragma unroll
    for (int off = 32; off > 0; off >>= 1) { s += __shfl_down(s, off, 64); d += __shfl_down(d, off, 64); }
    if (lane == 0) { as_[row] = s; ad_[row] = d; }
}

// ---------------- GAT attention + aggregation (+bias, optional relu) ----------------
template<int RELU>
__global__ __launch_bounds__(256) void aggr_kernel(const float* __restrict__ hp, const int* __restrict__ nbr,
                                                   const float* __restrict__ as_, const float* __restrict__ ad_,
                                                   const float* __restrict__ bias, float* __restrict__ out) {
    int id = blockIdx.x;                 // b*N + n
    int b = id >> 10;
    __shared__ float att[KP1];
    __shared__ int   jj[KP1];
    int t = threadIdx.x;
    if (t < KP1) {
        int j = nbr[id * KP1 + t];
        jj[t] = j;
        float e = as_[b * NNODE + j] + ad_[id];
        att[t] = (e >= 0.f) ? e : NEG * e;
    }
    __syncthreads();
    if (t == 0) {
        float mx = -INFINITY;
        for (int k = 0; k < KP1; ++k) mx = fmaxf(mx, att[k]);
        float s = 0.f;
        for (int k = 0; k < KP1; ++k) { float e = expf(att[k] - mx); att[k] = e; s += e; }
        float inv = 1.f / s;
        for (int k = 0; k < KP1; ++k) att[k] *= inv;
    }
    __syncthreads();
    const float* base = hp + (size_t)b * NNODE * DIM;
    float* orow = out + (size_t)id * DIM;
    for (int d = t; d < DIM; d += 256) {
        float o = bias[d];
        #pragma unroll
        for (int k = 0; k < KP1; ++k) o += att[k] * base[(size_t)jj[k] * DIM + d];
        if (RELU) o = fmaxf(o, 0.f);
        orow[d] = o;
    }
}

// ---------------- global max pool over nodes ----------------
__global__ void maxpool_kernel(const float* __restrict__ h, float* __restrict__ g) {
    int id = blockIdx.x * 256 + threadIdx.x;     // b*DIM + d
    if (id >= BATCH * DIM) return;
    int b = id / DIM, d = id % DIM;
    const float* p = h + (size_t)b * NNODE * DIM + d;
    float m = -INFINITY;
    for (int n = 0; n < NNODE; ++n) m = fmaxf(m, p[(size_t)n * DIM]);
    g[id] = m;
}

// ---------------- final linear g @ Wc + bc ----------------
__global__ void final_kernel(const float* __restrict__ g, const float* __restrict__ Wc,
                             const float* __restrict__ bc, float* __restrict__ out) {
    int b = blockIdx.x, t = threadIdx.x;
    float s0 = 0.f, s1 = 0.f;
    for (int d = t; d < DIM; d += 256) {
        float v = g[b * DIM + d];
        s0 += v * Wc[d * 2 + 0];
        s1 += v * Wc[d * 2 + 1];
    }
    __shared__ float r0[256], r1[256];
    r0[t] = s0; r1[t] = s1; __syncthreads();
    for (int s = 128; s > 0; s >>= 1) {
        if (t < s) { r0[t] += r0[t + s]; r1[t] += r1[t + s]; }
        __syncthreads();
    }
    if (t == 0) { out[b * 2] = r0[0] + bc[0]; out[b * 2 + 1] = r1[0] + bc[1]; }
}

extern "C" void kernel_launch(void* const* d_in, const int* in_sizes, int n_in,
                              void* d_out, int out_size, void* d_ws, size_t ws_size,
                              hipStream_t stream) {
    const float* x     = (const float*)d_in[0];
    const float* W1    = (const float*)d_in[1];
    const float* asrc1 = (const float*)d_in[2];
    const float* adst1 = (const float*)d_in[3];
    const float* b1    = (const float*)d_in[4];
    const float* W2    = (const float*)d_in[5];
    const float* asrc2 = (const float*)d_in[6];
    const float* adst2 = (const float*)d_in[7];
    const float* b2    = (const float*)d_in[8];
    const float* W3    = (const float*)d_in[9];
    const float* asrc3 = (const float*)d_in[10];
    const float* adst3 = (const float*)d_in[11];
    const float* b3    = (const float*)d_in[12];
    const float* Wc    = (const float*)d_in[13];
    const float* bc    = (const float*)d_in[14];
    float* out = (float*)d_out;

    char* ws = (char*)d_ws;
    float* bufA = (float*)ws;                          // 32MB (aliases d2 low)
    float* bufB = (float*)(ws + (32ull << 20));        // 32MB (aliases d2 high)
    float* bufC = (float*)(ws + (64ull << 20));        // 32MB
    float* d2   = (float*)ws;                          // 64MB, dead before bufA written
    size_t off = 96ull << 20;
    int*      nbr    = (int*)(ws + off);      off += (size_t)BATCH * NNODE * KP1 * 4;
    float*    sq     = (float*)(ws + off);    off += (size_t)BATCH * NNODE * 4;
    float*    mean   = (float*)(ws + off);    off += (size_t)BATCH * DIM * 4;
    unsigned* maxabs = (unsigned*)(ws + off); off += 256;
    float*    as_    = (float*)(ws + off);    off += (size_t)BATCH * NNODE * 4;
    float*    ad_    = (float*)(ws + off);    off += (size_t)BATCH * NNODE * 4;
    float*    g      = (float*)(ws + off);    off += (size_t)BATCH * DIM * 4;
    (void)ws_size; (void)in_sizes; (void)n_in; (void)out_size;

    // graph construction
    colmean_kernel<<<32, 256, 0, stream>>>(x, mean);
    rowsq_kernel<<<BATCH * NNODE / 4, 256, 0, stream>>>(x, sq);
    dist_kernel<<<dim3(NNODE / BT, NNODE / BT, BATCH), 256, 0, stream>>>(x, sq, d2);
    knn_kernel<<<BATCH * NNODE / 4, 256, 0, stream>>>(d2, nbr);
    // normalize (d2 dead from here)
    init_maxabs<<<1, 64, 0, stream>>>(maxabs);
    maxabs_kernel<<<dim3(16, BATCH), 256, 0, stream>>>(x, mean, maxabs);
    normalize_kernel<<<BATCH * NNODE * DIM / 256, 256, 0, stream>>>(x, mean, maxabs, bufA);

    const int gm = BATCH * NNODE / BT;   // 128 m-tiles
    // layer 1: A -> hp(B) -> C
    gemm_kernel<<<dim3(DIM / BT, gm), 256, 0, stream>>>(bufA, W1, bufB);
    attvec_kernel<<<BATCH * NNODE / 4, 256, 0, stream>>>(bufB, asrc1, adst1, as_, ad_);
    aggr_kernel<1><<<BATCH * NNODE, 256, 0, stream>>>(bufB, nbr, as_, ad_, b1, bufC);
    // layer 2: C -> hp(A) -> B
    gemm_kernel<<<dim3(DIM / BT, gm), 256, 0, stream>>>(bufC, W2, bufA);
    attvec_kernel<<<BATCH * NNODE / 4, 256, 0, stream>>>(bufA, asrc2, adst2, as_, ad_);
    aggr_kernel<1><<<BATCH * NNODE, 256, 0, stream>>>(bufA, nbr, as_, ad_, b2, bufB);
    // layer 3: B -> hp(C) -> A
    gemm_kernel<<<dim3(DIM / BT, gm), 256, 0, stream>>>(bufB, W3, bufC);
    attvec_kernel<<<BATCH * NNODE / 4, 256, 0, stream>>>(bufC, asrc3, adst3, as_, ad_);
    aggr_kernel<0><<<BATCH * NNODE, 256, 0, stream>>>(bufC, nbr, as_, ad_, b3, bufA);
    // pool + classify
    maxpool_kernel<<<BATCH * DIM / 256, 256, 0, stream>>>(bufA, g);
    final_kernel<<<BATCH, 256, 0, stream>>>(g, Wc, bc, out);
}

// Round 3
// 803.904 us; speedup vs baseline: 1.4741x; 1.2431x over previous
//
#include <hip/hip_runtime.h>
#include <hip/hip_bf16.h>
#include <math.h>

#define BATCH 16
#define NNODE 1024
#define DIM   512
#define KNN   16
#define KP1   17
#define NEG   0.2f
#define BT    128   // block tile

typedef __attribute__((ext_vector_type(8))) short bf16x8;
typedef __attribute__((ext_vector_type(4))) float f32x4;

__device__ __forceinline__ unsigned short f2bf(float f) {
    unsigned u = __float_as_uint(f);
    unsigned r = (u + 0x7FFFu + ((u >> 16) & 1u)) >> 16;   // RNE
    return (unsigned short)r;
}
__device__ __forceinline__ float bf2f(unsigned short h) {
    return __uint_as_float(((unsigned)h) << 16);
}
__device__ __forceinline__ void split_store(float v, unsigned short* hi, unsigned short* lo, size_t idx) {
    unsigned short h = f2bf(v);
    hi[idx] = h;
    lo[idx] = f2bf(v - bf2f(h));
}

// ---------------- column mean over nodes: mean[b][d] ----------------
__global__ void colmean_kernel(const float* __restrict__ x, float* __restrict__ mean) {
    int id = blockIdx.x * 256 + threadIdx.x;        // b*DIM + d
    if (id >= BATCH * DIM) return;
    int b = id / DIM, d = id % DIM;
    const float* p = x + (size_t)b * NNODE * DIM + d;
    float s = 0.f;
    for (int n = 0; n < NNODE; ++n) s += p[(size_t)n * DIM];
    mean[id] = s * (1.0f / NNODE);
}

// ---------------- row squared norms of raw pos ----------------
__global__ void rowsq_kernel(const float* __restrict__ x, float* __restrict__ sq) {
    int row = blockIdx.x * 4 + (threadIdx.x >> 6);
    int lane = threadIdx.x & 63;
    const float* p = x + (size_t)row * DIM;
    float s = 0.f;
    for (int i = lane; i < DIM; i += 64) { float v = p[i]; s += v * v; }
    #pragma unroll
    for (int off = 32; off > 0; off >>= 1) s += __shfl_down(s, off, 64);
    if (lane == 0) sq[row] = s;
}

// ---------------- distance matrix, 128x128 tile, 8x8 microtile (f32, exact selection) ----------------
__global__ __launch_bounds__(256, 2) void dist_kernel(const float* __restrict__ x,
                                                      const float* __restrict__ sq,
                                                      float* __restrict__ d2) {
    __shared__ float As[16][BT + 4];
    __shared__ float Bs[16][BT + 4];
    int b = blockIdx.z;
    int m0 = blockIdx.y * BT, n0 = blockIdx.x * BT;
    const float* A = x + (size_t)b * NNODE * DIM;
    int t = threadIdx.x, tx = t & 15, ty = t >> 4;
    float acc[8][8] = {};
    int r = t >> 2, k4 = (t & 3) * 4;
    for (int k0 = 0; k0 < DIM; k0 += 16) {
        float4 va0 = *(const float4*)(A + (size_t)(m0 + r) * DIM + k0 + k4);
        float4 va1 = *(const float4*)(A + (size_t)(m0 + r + 64) * DIM + k0 + k4);
        float4 vb0 = *(const float4*)(A + (size_t)(n0 + r) * DIM + k0 + k4);
        float4 vb1 = *(const float4*)(A + (size_t)(n0 + r + 64) * DIM + k0 + k4);
        As[k4 + 0][r] = va0.x; As[k4 + 1][r] = va0.y; As[k4 + 2][r] = va0.z; As[k4 + 3][r] = va0.w;
        As[k4 + 0][r + 64] = va1.x; As[k4 + 1][r + 64] = va1.y; As[k4 + 2][r + 64] = va1.z; As[k4 + 3][r + 64] = va1.w;
        Bs[k4 + 0][r] = vb0.x; Bs[k4 + 1][r] = vb0.y; Bs[k4 + 2][r] = vb0.z; Bs[k4 + 3][r] = vb0.w;
        Bs[k4 + 0][r + 64] = vb1.x; Bs[k4 + 1][r + 64] = vb1.y; Bs[k4 + 2][r + 64] = vb1.z; Bs[k4 + 3][r + 64] = vb1.w;
        __syncthreads();
        #pragma unroll
        for (int kk = 0; kk < 16; ++kk) {
            float4 a0 = *(const float4*)&As[kk][ty * 4];
            float4 a1 = *(const float4*)&As[kk][ty * 4 + 64];
            float4 b0 = *(const float4*)&Bs[kk][tx * 4];
            float4 b1 = *(const float4*)&Bs[kk][tx * 4 + 64];
            float aa[8] = {a0.x, a0.y, a0.z, a0.w, a1.x, a1.y, a1.z, a1.w};
            float bb[8] = {b0.x, b0.y, b0.z, b0.w, b1.x, b1.y, b1.z, b1.w};
            #pragma unroll
            for (int i = 0; i < 8; ++i)
                #pragma unroll
                for (int j = 0; j < 8; ++j) acc[i][j] += aa[i] * bb[j];
        }
        __syncthreads();
    }
    const float* sqb = sq + b * NNODE;
    #pragma unroll
    for (int ih = 0; ih < 2; ++ih)
    #pragma unroll
    for (int i = 0; i < 4; ++i) {
        int m = m0 + ih * 64 + ty * 4 + i;
        float sm = sqb[m];
        #pragma unroll
        for (int jh = 0; jh < 2; ++jh) {
            float4 o; float* po = (float*)&o;
            #pragma unroll
            for (int j = 0; j < 4; ++j) {
                int n = n0 + jh * 64 + tx * 4 + j;
                float val = sm + sqb[n] - 2.f * acc[ih * 4 + i][jh * 4 + j];
                if (m == n) val = INFINITY;
                po[j] = val;
            }
            *(float4*)(d2 + ((size_t)b * NNODE + m) * NNODE + n0 + jh * 64 + tx * 4) = o;
        }
    }
}

// ---------------- top-16 smallest per row: one wave per row ----------------
__global__ __launch_bounds__(256) void knn_kernel(const float* __restrict__ d2, int* __restrict__ nbr) {
    int row = blockIdx.x * 4 + (threadIdx.x >> 6);   // b*N + n
    int l = threadIdx.x & 63;
    const float* src = d2 + (size_t)row * NNODE;
    float v[16];
    #pragma unroll
    for (int j = 0; j < 16; ++j) v[j] = src[l + (j << 6)];
    int* dst = nbr + row * KP1;
    for (int it = 0; it < KNN; ++it) {
        unsigned long long key = ~0ull;
        #pragma unroll
        for (int j = 0; j < 16; ++j) {
            unsigned long long k = ((unsigned long long)__float_as_uint(v[j]) << 32)
                                 | (unsigned)(l + (j << 6));
            if (k < key) key = k;
        }
        #pragma unroll
        for (int off = 1; off < 64; off <<= 1) {
            unsigned long long o = __shfl_xor(key, off, 64);
            if (o < key) key = o;
        }
        int idx = (int)(key & 0xFFFFFFFFull);
        if ((idx & 63) == l) v[idx >> 6] = INFINITY;
        if (l == 0) dst[it] = idx;
    }
    if (l == 0) dst[KNN] = row & (NNODE - 1);
}

// ---------------- per-graph max|x - mean| ----------------
__global__ void init_maxabs(unsigned* maxabs) { if (threadIdx.x < BATCH) maxabs[threadIdx.x] = 0u; }

__global__ __launch_bounds__(256) void maxabs_kernel(const float* __restrict__ x,
                                                     const float* __restrict__ mean,
                                                     unsigned* __restrict__ maxabs) {
    int b = blockIdx.y;
    const float* p = x + ((size_t)b * NNODE + blockIdx.x * 64) * DIM;
    const float* mb = mean + b * DIM;
    float m = 0.f;
    for (int i = threadIdx.x; i < 64 * DIM; i += 256) {
        int d = i & (DIM - 1);
        m = fmaxf(m, fabsf(p[i] - mb[d]));
    }
    __shared__ float red[256];
    red[threadIdx.x] = m; __syncthreads();
    for (int s = 128; s > 0; s >>= 1) {
        if (threadIdx.x < s) red[threadIdx.x] = fmaxf(red[threadIdx.x], red[threadIdx.x + s]);
        __syncthreads();
    }
    if (threadIdx.x == 0) atomicMax(maxabs + b, __float_as_uint(red[0]));
}

// ---------------- h0 = (x - mean) * 0.999999/maxabs -> split bf16 hi/lo ----------------
__global__ void normalize_kernel(const float* __restrict__ x, const float* __restrict__ mean,
                                 const unsigned* __restrict__ maxabs,
                                 unsigned short* __restrict__ h_hi, unsigned short* __restrict__ h_lo) {
    int id = blockIdx.x * 256 + threadIdx.x;    // over B*N*D
    int b = id >> 19;
    int d = id & (DIM - 1);
    float scale = 0.999999f / __uint_as_float(maxabs[b]);
    float v = (x[id] - mean[b * DIM + d]) * scale;
    split_store(v, h_hi, h_lo, id);
}

// ---------------- W[512x512] -> Wt hi/lo bf16 [n][k] (transpose + split) ----------------
__global__ void wsplit_kernel(const float* __restrict__ W,
                              unsigned short* __restrict__ Wh, unsigned short* __restrict__ Wl) {
    __shared__ float tile[32][33];
    int bx = blockIdx.x * 32, by = blockIdx.y * 32;   // bx: n-block, by: k-block
    int tx = threadIdx.x & 31, ty = threadIdx.x >> 5; // 32 x 8
    #pragma unroll
    for (int i = 0; i < 4; ++i)
        tile[ty + i * 8][tx] = W[(size_t)(by + ty + i * 8) * DIM + bx + tx];
    __syncthreads();
    #pragma unroll
    for (int i = 0; i < 4; ++i) {
        int n = bx + ty + i * 8;
        float v = tile[tx][ty + i * 8];               // = W[by+tx][n]
        split_store(v, Wh, Wl, (size_t)n * DIM + by + tx);
    }
}

// ---------------- C[16384x512] f32 = (Ah+Al)[M][K] . (Wh+Wl)[K][N], split-bf16 MFMA ----------------
// A given row-major [M][K] bf16 hi/lo; W given TRANSPOSED row-major Wt[n][k] bf16 hi/lo.
__global__ __launch_bounds__(256, 2) void gemm_mfma(const unsigned short* __restrict__ Agh,
                                                    const unsigned short* __restrict__ Agl,
                                                    const unsigned short* __restrict__ Bgh,
                                                    const unsigned short* __restrict__ Bgl,
                                                    float* __restrict__ C) {
    // LDS tiles padded to 40 elems/row (80B = 5 bank-quads, coprime 8 -> 2-way max on b128 reads)
    __shared__ unsigned short AhL[128][40], AlL[128][40], BhL[128][40], BlL[128][40];
    int m0 = blockIdx.y * BT, n0 = blockIdx.x * BT;
    int t = threadIdx.x;
    int lane = t & 63, w = t >> 6;
    int wm = (w >> 1) * 64, wn = (w & 1) * 64;
    int fr = lane & 15, fk = (lane >> 4) * 8;
    f32x4 acc[4][4];
    #pragma unroll
    for (int i = 0; i < 4; ++i)
        #pragma unroll
        for (int j = 0; j < 4; ++j) acc[i][j] = (f32x4){0.f, 0.f, 0.f, 0.f};

    for (int k0 = 0; k0 < DIM; k0 += 32) {
        if (k0) __syncthreads();
        #pragma unroll
        for (int p = 0; p < 2; ++p) {
            int u = t + p * 256;
            int row = u >> 2, seg = (u & 3) * 8;
            *(uint4*)&AhL[row][seg] = *(const uint4*)(Agh + (size_t)(m0 + row) * DIM + k0 + seg);
            *(uint4*)&AlL[row][seg] = *(const uint4*)(Agl + (size_t)(m0 + row) * DIM + k0 + seg);
            *(uint4*)&BhL[row][seg] = *(const uint4*)(Bgh + (size_t)(n0 + row) * DIM + k0 + seg);
            *(uint4*)&BlL[row][seg] = *(const uint4*)(Bgl + (size_t)(n0 + row) * DIM + k0 + seg);
        }
        __syncthreads();
        bf16x8 ah[4], al[4], bh[4], bl[4];
        #pragma unroll
        for (int i = 0; i < 4; ++i) {
            ah[i] = *(const bf16x8*)&AhL[wm + i * 16 + fr][fk];
            al[i] = *(const bf16x8*)&AlL[wm + i * 16 + fr][fk];
            bh[i] = *(const bf16x8*)&BhL[wn + i * 16 + fr][fk];
            bl[i] = *(const bf16x8*)&BlL[wn + i * 16 + fr][fk];
        }
        #pragma unroll
        for (int i = 0; i < 4; ++i)
            #pragma unroll
            for (int j = 0; j < 4; ++j) {
                acc[i][j] = __builtin_amdgcn_mfma_f32_16x16x32_bf16(ah[i], bh[j], acc[i][j], 0, 0, 0);
                acc[i][j] = __builtin_amdgcn_mfma_f32_16x16x32_bf16(ah[i], bl[j], acc[i][j], 0, 0, 0);
                acc[i][j] = __builtin_amdgcn_mfma_f32_16x16x32_bf16(al[i], bh[j], acc[i][j], 0, 0, 0);
            }
    }
    // C/D layout: col = lane&15, row = (lane>>4)*4 + r   [m89/m91-verified]
    #pragma unroll
    for (int i = 0; i < 4; ++i) {
        int mrow = m0 + wm + i * 16 + (lane >> 4) * 4;
        #pragma unroll
        for (int j = 0; j < 4; ++j) {
            int col = n0 + wn + j * 16 + fr;
            #pragma unroll
            for (int r = 0; r < 4; ++r)
                C[(size_t)(mrow + r) * DIM + col] = acc[i][j][r];
        }
    }
}

// ---------------- a_s = hp @ asrc, a_d = hp @ adst ----------------
__global__ void attvec_kernel(const float* __restrict__ hp, const float* __restrict__ asrc,
                              const float* __restrict__ adst, float* __restrict__ as_,
                              float* __restrict__ ad_) {
    int row = blockIdx.x * 4 + (threadIdx.x >> 6);
    int lane = threadIdx.x & 63;
    const float* p = hp + (size_t)row * DIM;
    float s = 0.f, d = 0.f;
    for (int i = lane; i < DIM; i += 64) { float v = p[i]; s += v * asrc[i]; d += v * adst[i]; }
    #pragma unroll
    for (int off = 32; off > 0; off >>= 1) { s += __shfl_down(s, off, 64); d += __shfl_down(d, off, 64); }
    if (lane == 0) { as_[row] = s; ad_[row] = d; }
}

// ---------------- GAT attention + aggregation ----------------
template<int RELU, int SPLIT>
__global__ __launch_bounds__(256) void aggr_kernel(const float* __restrict__ hp, const int* __restrict__ nbr,
                                                   const float* __restrict__ as_, const float* __restrict__ ad_,
                                                   const float* __restrict__ bias,
                                                   float* __restrict__ outf,
                                                   unsigned short* __restrict__ oh,
                                                   unsigned short* __restrict__ ol) {
    int id = blockIdx.x;                 // b*N + n
    int b = id >> 10;
    __shared__ float att[KP1];
    __shared__ int   jj[KP1];
    int t = threadIdx.x;
    if (t < KP1) {
        int j = nbr[id * KP1 + t];
        jj[t] = j;
        float e = as_[b * NNODE + j] + ad_[id];
        att[t] = (e >= 0.f) ? e : NEG * e;
    }
    __syncthreads();
    if (t == 0) {
        float mx = -INFINITY;
        for (int k = 0; k < KP1; ++k) mx = fmaxf(mx, att[k]);
        float s = 0.f;
        for (int k = 0; k < KP1; ++k) { float e = expf(att[k] - mx); att[k] = e; s += e; }
        float inv = 1.f / s;
        for (int k = 0; k < KP1; ++k) att[k] *= inv;
    }
    __syncthreads();
    const float* base = hp + (size_t)b * NNODE * DIM;
    for (int d = t; d < DIM; d += 256) {
        float o = bias[d];
        #pragma unroll
        for (int k = 0; k < KP1; ++k) o += att[k] * base[(size_t)jj[k] * DIM + d];
        if (RELU) o = fmaxf(o, 0.f);
        size_t idx = (size_t)id * DIM + d;
        if (SPLIT) split_store(o, oh, ol, idx);
        else       outf[idx] = o;
    }
}

// ---------------- global max pool over nodes ----------------
__global__ void maxpool_kernel(const float* __restrict__ h, float* __restrict__ g) {
    int id = blockIdx.x * 256 + threadIdx.x;     // b*DIM + d
    if (id >= BATCH * DIM) return;
    int b = id / DIM, d = id % DIM;
    const float* p = h + (size_t)b * NNODE * DIM + d;
    float m = -INFINITY;
    for (int n = 0; n < NNODE; ++n) m = fmaxf(m, p[(size_t)n * DIM]);
    g[id] = m;
}

// ---------------- final linear g @ Wc + bc ----------------
__global__ void final_kernel(const float* __restrict__ g, const float* __restrict__ Wc,
                             const float* __restrict__ bc, float* __restrict__ out) {
    int b = blockIdx.x, t = threadIdx.x;
    float s0 = 0.f, s1 = 0.f;
    for (int d = t; d < DIM; d += 256) {
        float v = g[b * DIM + d];
        s0 += v * Wc[d * 2 + 0];
        s1 += v * Wc[d * 2 + 1];
    }
    __shared__ float r0[256], r1[256];
    r0[t] = s0; r1[t] = s1; __syncthreads();
    for (int s = 128; s > 0; s >>= 1) {
        if (t < s) { r0[t] += r0[t + s]; r1[t] += r1[t + s]; }
        __syncthreads();
    }
    if (t == 0) { out[b * 2] = r0[0] + bc[0]; out[b * 2 + 1] = r1[0] + bc[1]; }
}

extern "C" void kernel_launch(void* const* d_in, const int* in_sizes, int n_in,
                              void* d_out, int out_size, void* d_ws, size_t ws_size,
                              hipStream_t stream) {
    const float* x     = (const float*)d_in[0];
    const float* W1    = (const float*)d_in[1];
    const float* asrc1 = (const float*)d_in[2];
    const float* adst1 = (const float*)d_in[3];
    const float* b1    = (const float*)d_in[4];
    const float* W2    = (const float*)d_in[5];
    const float* asrc2 = (const float*)d_in[6];
    const float* adst2 = (const float*)d_in[7];
    const float* b2    = (const float*)d_in[8];
    const float* W3    = (const float*)d_in[9];
    const float* asrc3 = (const float*)d_in[10];
    const float* adst3 = (const float*)d_in[11];
    const float* b3    = (const float*)d_in[12];
    const float* Wc    = (const float*)d_in[13];
    const float* bc    = (const float*)d_in[14];
    float* out = (float*)d_out;

    char* ws = (char*)d_ws;
    // d2 occupies [0,64MB) and is dead after knn. hp aliases its low half,
    // hA aliases its high half (both written after knn).
    float*          d2    = (float*)ws;                         // 64MB
    float*          hp    = (float*)ws;                         // 32MB f32
    unsigned short* hA_hi = (unsigned short*)(ws + (32ull << 20)); // 16MB
    unsigned short* hA_lo = (unsigned short*)(ws + (48ull << 20)); // 16MB
    unsigned short* hB_hi = (unsigned short*)(ws + (64ull << 20)); // 16MB
    unsigned short* hB_lo = (unsigned short*)(ws + (80ull << 20)); // 16MB
    float*          h3    = (float*)(ws + (64ull << 20));          // 32MB, alias hB (dead after gemm3)
    size_t off = 96ull << 20;
    unsigned short* Wt1h = (unsigned short*)(ws + off); off += (size_t)DIM * DIM * 2;
    unsigned short* Wt1l = (unsigned short*)(ws + off); off += (size_t)DIM * DIM * 2;
    unsigned short* Wt2h = (unsigned short*)(ws + off); off += (size_t)DIM * DIM * 2;
    unsigned short* Wt2l = (unsigned short*)(ws + off); off += (size_t)DIM * DIM * 2;
    unsigned short* Wt3h = (unsigned short*)(ws + off); off += (size_t)DIM * DIM * 2;
    unsigned short* Wt3l = (unsigned short*)(ws + off); off += (size_t)DIM * DIM * 2;
    int*      nbr    = (int*)(ws + off);      off += (size_t)BATCH * NNODE * KP1 * 4;
    float*    sq     = (float*)(ws + off);    off += (size_t)BATCH * NNODE * 4;
    float*    mean   = (float*)(ws + off);    off += (size_t)BATCH * DIM * 4;
    unsigned* maxabs = (unsigned*)(ws + off); off += 256;
    float*    as_    = (float*)(ws + off);    off += (size_t)BATCH * NNODE * 4;
    float*    ad_    = (float*)(ws + off);    off += (size_t)BATCH * NNODE * 4;
    float*    g      = (float*)(ws + off);    off += (size_t)BATCH * DIM * 4;
    (void)ws_size; (void)in_sizes; (void)n_in; (void)out_size;

    // graph construction (f32 exact)
    colmean_kernel<<<32, 256, 0, stream>>>(x, mean);
    rowsq_kernel<<<BATCH * NNODE / 4, 256, 0, stream>>>(x, sq);
    dist_kernel<<<dim3(NNODE / BT, NNODE / BT, BATCH), 256, 0, stream>>>(x, sq, d2);
    knn_kernel<<<BATCH * NNODE / 4, 256, 0, stream>>>(d2, nbr);
    // weight transpose + split (d2 dead from here)
    wsplit_kernel<<<dim3(16, 16), 256, 0, stream>>>(W1, Wt1h, Wt1l);
    wsplit_kernel<<<dim3(16, 16), 256, 0, stream>>>(W2, Wt2h, Wt2l);
    wsplit_kernel<<<dim3(16, 16), 256, 0, stream>>>(W3, Wt3h, Wt3l);
    // normalize -> hA (split bf16)
    init_maxabs<<<1, 64, 0, stream>>>(maxabs);
    maxabs_kernel<<<dim3(16, BATCH), 256, 0, stream>>>(x, mean, maxabs);
    normalize_kernel<<<BATCH * NNODE * DIM / 256, 256, 0, stream>>>(x, mean, maxabs, hA_hi, hA_lo);

    const dim3 ggrid(DIM / BT, BATCH * NNODE / BT);   // (4, 128)
    // layer 1
    gemm_mfma<<<ggrid, 256, 0, stream>>>(hA_hi, hA_lo, Wt1h, Wt1l, hp);
    attvec_kernel<<<BATCH * NNODE / 4, 256, 0, stream>>>(hp, asrc1, adst1, as_, ad_);
    aggr_kernel<1, 1><<<BATCH * NNODE, 256, 0, stream>>>(hp, nbr, as_, ad_, b1, nullptr, hB_hi, hB_lo);
    // layer 2
    gemm_mfma<<<ggrid, 256, 0, stream>>>(hB_hi, hB_lo, Wt2h, Wt2l, hp);
    attvec_kernel<<<BATCH * NNODE / 4, 256, 0, stream>>>(hp, asrc2, adst2, as_, ad_);
    aggr_kernel<1, 1><<<BATCH * NNODE, 256, 0, stream>>>(hp, nbr, as_, ad_, b2, nullptr, hA_hi, hA_lo);
    // layer 3
    gemm_mfma<<<ggrid, 256, 0, stream>>>(hA_hi, hA_lo, Wt3h, Wt3l, hp);
    attvec_kernel<<<BATCH * NNODE / 4, 256, 0, stream>>>(hp, asrc3, adst3, as_, ad_);
    aggr_kernel<0, 0><<<BATCH * NNODE, 256, 0, stream>>>(hp, nbr, as_, ad_, b3, h3, nullptr, nullptr);
    // pool + classify
    maxpool_kernel<<<BATCH * DIM / 256, 256, 0, stream>>>(h3, g);
    final_kernel<<<BATCH, 256, 0, stream>>>(g, Wc, bc, out);
}

// Round 4
// 724.465 us; speedup vs baseline: 1.6358x; 1.1097x over previous
//
#include <hip/hip_runtime.h>
#include <hip/hip_bf16.h>
#include <math.h>

#define BATCH 16
#define NNODE 1024
#define DIM   512
#define KNN   16
#define KP1   17
#define NCAND 24
#define NEG   0.2f
#define BT    128   // block tile

typedef __attribute__((ext_vector_type(8))) short bf16x8;
typedef __attribute__((ext_vector_type(4))) float f32x4;

__device__ __forceinline__ unsigned short f2bf(float f) {
    unsigned u = __float_as_uint(f);
    unsigned r = (u + 0x7FFFu + ((u >> 16) & 1u)) >> 16;   // RNE
    return (unsigned short)r;
}
__device__ __forceinline__ float bf2f(unsigned short h) {
    return __uint_as_float(((unsigned)h) << 16);
}
__device__ __forceinline__ void split_store(float v, unsigned short* hi, unsigned short* lo, size_t idx) {
    unsigned short h = f2bf(v);
    hi[idx] = h;
    lo[idx] = f2bf(v - bf2f(h));
}

// ---------------- column mean over nodes: mean[b][d] ----------------
__global__ void colmean_kernel(const float* __restrict__ x, float* __restrict__ mean) {
    int id = blockIdx.x * 256 + threadIdx.x;        // b*DIM + d
    if (id >= BATCH * DIM) return;
    int b = id / DIM, d = id % DIM;
    const float* p = x + (size_t)b * NNODE * DIM + d;
    float s = 0.f;
    for (int n = 0; n < NNODE; ++n) s += p[(size_t)n * DIM];
    mean[id] = s * (1.0f / NNODE);
}

// ---------------- row squared norms of raw pos ----------------
__global__ void rowsq_kernel(const float* __restrict__ x, float* __restrict__ sq) {
    int row = blockIdx.x * 4 + (threadIdx.x >> 6);
    int lane = threadIdx.x & 63;
    const float* p = x + (size_t)row * DIM;
    float s = 0.f;
    for (int i = lane; i < DIM; i += 64) { float v = p[i]; s += v * v; }
    #pragma unroll
    for (int off = 32; off > 0; off >>= 1) s += __shfl_down(s, off, 64);
    if (lane == 0) sq[row] = s;
}

// ---------------- x -> bf16 (for approximate candidate distances) ----------------
__global__ void xtobf_kernel(const float* __restrict__ x, unsigned short* __restrict__ xh) {
    int id = blockIdx.x * 256 + threadIdx.x;
    float4 v = *(const float4*)(x + (size_t)id * 4);
    ushort4 o;
    o.x = f2bf(v.x); o.y = f2bf(v.y); o.z = f2bf(v.z); o.w = f2bf(v.w);
    *(ushort4*)(xh + (size_t)id * 4) = o;
}

// ---------------- approx distance matrix via bf16 MFMA (candidate stage) ----------------
// d2[b][m][n] ~= sq_m + sq_n - 2 * dot_bf16(x_m, x_n); diag = INF
__global__ __launch_bounds__(256, 2) void dist_mfma(const unsigned short* __restrict__ xh,
                                                    const float* __restrict__ sq,
                                                    float* __restrict__ d2) {
    __shared__ unsigned short AhL[128][40], BhL[128][40];
    int mt = blockIdx.y;                 // global m-tile (128 rows, within one batch)
    int b = mt >> 3;
    int m0 = mt * BT;                    // global row base
    int n0 = blockIdx.x * BT;            // node index base within batch
    int bn0 = b * NNODE + n0;            // global row base for B side
    int t = threadIdx.x;
    int lane = t & 63, w = t >> 6;
    int wm = (w >> 1) * 64, wn = (w & 1) * 64;
    int fr = lane & 15, fk = (lane >> 4) * 8;
    f32x4 acc[4][4];
    #pragma unroll
    for (int i = 0; i < 4; ++i)
        #pragma unroll
        for (int j = 0; j < 4; ++j) acc[i][j] = (f32x4){0.f, 0.f, 0.f, 0.f};

    for (int k0 = 0; k0 < DIM; k0 += 32) {
        if (k0) __syncthreads();
        #pragma unroll
        for (int p = 0; p < 2; ++p) {
            int u = t + p * 256;
            int row = u >> 2, seg = (u & 3) * 8;
            *(uint4*)&AhL[row][seg] = *(const uint4*)(xh + (size_t)(m0 + row) * DIM + k0 + seg);
            *(uint4*)&BhL[row][seg] = *(const uint4*)(xh + (size_t)(bn0 + row) * DIM + k0 + seg);
        }
        __syncthreads();
        bf16x8 ah[4], bh[4];
        #pragma unroll
        for (int i = 0; i < 4; ++i) {
            ah[i] = *(const bf16x8*)&AhL[wm + i * 16 + fr][fk];
            bh[i] = *(const bf16x8*)&BhL[wn + i * 16 + fr][fk];
        }
        #pragma unroll
        for (int i = 0; i < 4; ++i)
            #pragma unroll
            for (int j = 0; j < 4; ++j)
                acc[i][j] = __builtin_amdgcn_mfma_f32_16x16x32_bf16(ah[i], bh[j], acc[i][j], 0, 0, 0);
    }
    const float* sqb = sq + b * NNODE;
    int mloc0 = m0 - b * NNODE;
    #pragma unroll
    for (int i = 0; i < 4; ++i) {
        int mloc = mloc0 + wm + i * 16 + (lane >> 4) * 4;   // node index of acc row r=0
        #pragma unroll
        for (int j = 0; j < 4; ++j) {
            int n = n0 + wn + j * 16 + fr;
            float sqn = sqb[n];
            #pragma unroll
            for (int r = 0; r < 4; ++r) {
                float val = sqb[mloc + r] + sqn - 2.f * acc[i][j][r];
                if (mloc + r == n) val = INFINITY;
                d2[((size_t)b * NNODE + mloc + r) * NNODE + n] = val;
            }
        }
    }
}

// ---------------- top-24 smallest per row (approx) -> candidates ----------------
__global__ __launch_bounds__(256) void knn_kernel(const float* __restrict__ d2, int* __restrict__ cand) {
    int row = blockIdx.x * 4 + (threadIdx.x >> 6);   // b*N + n
    int l = threadIdx.x & 63;
    const float* src = d2 + (size_t)row * NNODE;
    float v[16];
    #pragma unroll
    for (int j = 0; j < 16; ++j) v[j] = src[l + (j << 6)];
    int* dst = cand + row * NCAND;
    for (int it = 0; it < NCAND; ++it) {
        unsigned long long key = ~0ull;
        #pragma unroll
        for (int j = 0; j < 16; ++j) {
            unsigned long long k = ((unsigned long long)__float_as_uint(v[j]) << 32)
                                 | (unsigned)(l + (j << 6));
            if (k < key) key = k;
        }
        #pragma unroll
        for (int off = 1; off < 64; off <<= 1) {
            unsigned long long o = __shfl_xor(key, off, 64);
            if (o < key) key = o;
        }
        int idx = (int)(key & 0xFFFFFFFFull);
        if ((idx & 63) == l) v[idx >> 6] = INFINITY;
        if (l == 0) dst[it] = idx;
    }
}

// ---------------- exact f32 re-rank of candidates -> nbr[17] ----------------
__global__ __launch_bounds__(256) void rerank_kernel(const float* __restrict__ x,
                                                     const float* __restrict__ sq,
                                                     const int* __restrict__ cand,
                                                     int* __restrict__ nbr) {
    int row = blockIdx.x;                // b*N + m
    int b = row >> 10;
    int w = threadIdx.x >> 6, l = threadIdx.x & 63;
    const float* xm = x + (size_t)row * DIM;
    float4 m0v = *(const float4*)(xm + l * 8);
    float4 m1v = *(const float4*)(xm + l * 8 + 4);
    __shared__ float dval[NCAND];
    __shared__ int   didx[NCAND];
    const float* xb = x + (size_t)b * NNODE * DIM;
    const float* sqb = sq + b * NNODE;
    float sqm = sq[row];
    for (int c = w; c < NCAND; c += 4) {
        int j = cand[row * NCAND + c];
        const float* xj = xb + (size_t)j * DIM;
        float4 j0 = *(const float4*)(xj + l * 8);
        float4 j1 = *(const float4*)(xj + l * 8 + 4);
        float s = m0v.x * j0.x + m0v.y * j0.y + m0v.z * j0.z + m0v.w * j0.w
                + m1v.x * j1.x + m1v.y * j1.y + m1v.z * j1.z + m1v.w * j1.w;
        #pragma unroll
        for (int off = 32; off > 0; off >>= 1) s += __shfl_down(s, off, 64);
        if (l == 0) { dval[c] = sqm + sqb[j] - 2.f * s; didx[c] = j; }
    }
    __syncthreads();
    if (w == 0) {
        unsigned long long mykey = ~0ull;
        if (l < NCAND)
            mykey = ((unsigned long long)__float_as_uint(dval[l]) << 32) | (unsigned)didx[l];
        int* dst = nbr + row * KP1;
        for (int it = 0; it < KNN; ++it) {
            unsigned long long kmin = mykey;
            #pragma unroll
            for (int off = 1; off < 32; off <<= 1) {     // butterfly within lanes 0..31 (keys live in 0..23)
                unsigned long long o = __shfl_xor(kmin, off, 64);
                if (o < kmin) kmin = o;
            }
            if (mykey == kmin && mykey != ~0ull) mykey = ~0ull;   // owner removes (keys unique: idx differs)
            if (l == 0) dst[it] = (int)(kmin & 0xFFFFFFFFull);
        }
        if (l == 0) dst[KNN] = row & (NNODE - 1);        // self loop
    }
}

// ---------------- per-graph max|x - mean| ----------------
__global__ void init_maxabs(unsigned* maxabs) { if (threadIdx.x < BATCH) maxabs[threadIdx.x] = 0u; }

__global__ __launch_bounds__(256) void maxabs_kernel(const float* __restrict__ x,
                                                     const float* __restrict__ mean,
                                                     unsigned* __restrict__ maxabs) {
    int b = blockIdx.y;
    const float* p = x + ((size_t)b * NNODE + blockIdx.x * 64) * DIM;
    const float* mb = mean + b * DIM;
    float m = 0.f;
    for (int i = threadIdx.x; i < 64 * DIM; i += 256) {
        int d = i & (DIM - 1);
        m = fmaxf(m, fabsf(p[i] - mb[d]));
    }
    __shared__ float red[256];
    red[threadIdx.x] = m; __syncthreads();
    for (int s = 128; s > 0; s >>= 1) {
        if (threadIdx.x < s) red[threadIdx.x] = fmaxf(red[threadIdx.x], red[threadIdx.x + s]);
        __syncthreads();
    }
    if (threadIdx.x == 0) atomicMax(maxabs + b, __float_as_uint(red[0]));
}

// ---------------- h0 = (x - mean) * 0.999999/maxabs -> split bf16 hi/lo ----------------
__global__ void normalize_kernel(const float* __restrict__ x, const float* __restrict__ mean,
                                 const unsigned* __restrict__ maxabs,
                                 unsigned short* __restrict__ h_hi, unsigned short* __restrict__ h_lo) {
    int id = blockIdx.x * 256 + threadIdx.x;    // over B*N*D
    int b = id >> 19;
    int d = id & (DIM - 1);
    float scale = 0.999999f / __uint_as_float(maxabs[b]);
    float v = (x[id] - mean[b * DIM + d]) * scale;
    split_store(v, h_hi, h_lo, id);
}

// ---------------- W[512x512] -> Wt hi/lo bf16 [n][k] (transpose + split) ----------------
__global__ void wsplit_kernel(const float* __restrict__ W,
                              unsigned short* __restrict__ Wh, unsigned short* __restrict__ Wl) {
    __shared__ float tile[32][33];
    int bx = blockIdx.x * 32, by = blockIdx.y * 32;   // bx: n-block, by: k-block
    int tx = threadIdx.x & 31, ty = threadIdx.x >> 5; // 32 x 8
    #pragma unroll
    for (int i = 0; i < 4; ++i)
        tile[ty + i * 8][tx] = W[(size_t)(by + ty + i * 8) * DIM + bx + tx];
    __syncthreads();
    #pragma unroll
    for (int i = 0; i < 4; ++i) {
        int n = bx + ty + i * 8;
        float v = tile[tx][ty + i * 8];               // = W[by+tx][n]
        split_store(v, Wh, Wl, (size_t)n * DIM + by + tx);
    }
}

// ---------------- C f32 = (Ah+Al) . (Wh+Wl), split-bf16 MFMA ----------------
__global__ __launch_bounds__(256, 2) void gemm_mfma(const unsigned short* __restrict__ Agh,
                                                    const unsigned short* __restrict__ Agl,
                                                    const unsigned short* __restrict__ Bgh,
                                                    const unsigned short* __restrict__ Bgl,
                                                    float* __restrict__ C) {
    __shared__ unsigned short AhL[128][40], AlL[128][40], BhL[128][40], BlL[128][40];
    int m0 = blockIdx.y * BT, n0 = blockIdx.x * BT;
    int t = threadIdx.x;
    int lane = t & 63, w = t >> 6;
    int wm = (w >> 1) * 64, wn = (w & 1) * 64;
    int fr = lane & 15, fk = (lane >> 4) * 8;
    f32x4 acc[4][4];
    #pragma unroll
    for (int i = 0; i < 4; ++i)
        #pragma unroll
        for (int j = 0; j < 4; ++j) acc[i][j] = (f32x4){0.f, 0.f, 0.f, 0.f};

    for (int k0 = 0; k0 < DIM; k0 += 32) {
        if (k0) __syncthreads();
        #pragma unroll
        for (int p = 0; p < 2; ++p) {
            int u = t + p * 256;
            int row = u >> 2, seg = (u & 3) * 8;
            *(uint4*)&AhL[row][seg] = *(const uint4*)(Agh + (size_t)(m0 + row) * DIM + k0 + seg);
            *(uint4*)&AlL[row][seg] = *(const uint4*)(Agl + (size_t)(m0 + row) * DIM + k0 + seg);
            *(uint4*)&BhL[row][seg] = *(const uint4*)(Bgh + (size_t)(n0 + row) * DIM + k0 + seg);
            *(uint4*)&BlL[row][seg] = *(const uint4*)(Bgl + (size_t)(n0 + row) * DIM + k0 + seg);
        }
        __syncthreads();
        bf16x8 ah[4], al[4], bh[4], bl[4];
        #pragma unroll
        for (int i = 0; i < 4; ++i) {
            ah[i] = *(const bf16x8*)&AhL[wm + i * 16 + fr][fk];
            al[i] = *(const bf16x8*)&AlL[wm + i * 16 + fr][fk];
            bh[i] = *(const bf16x8*)&BhL[wn + i * 16 + fr][fk];
            bl[i] = *(const bf16x8*)&BlL[wn + i * 16 + fr][fk];
        }
        #pragma unroll
        for (int i = 0; i < 4; ++i)
            #pragma unroll
            for (int j = 0; j < 4; ++j) {
                acc[i][j] = __builtin_amdgcn_mfma_f32_16x16x32_bf16(ah[i], bh[j], acc[i][j], 0, 0, 0);
                acc[i][j] = __builtin_amdgcn_mfma_f32_16x16x32_bf16(ah[i], bl[j], acc[i][j], 0, 0, 0);
                acc[i][j] = __builtin_amdgcn_mfma_f32_16x16x32_bf16(al[i], bh[j], acc[i][j], 0, 0, 0);
            }
    }
    #pragma unroll
    for (int i = 0; i < 4; ++i) {
        int mrow = m0 + wm + i * 16 + (lane >> 4) * 4;
        #pragma unroll
        for (int j = 0; j < 4; ++j) {
            int col = n0 + wn + j * 16 + fr;
            #pragma unroll
            for (int r = 0; r < 4; ++r)
                C[(size_t)(mrow + r) * DIM + col] = acc[i][j][r];
        }
    }
}

// ---------------- a_s = hp @ asrc, a_d = hp @ adst ----------------
__global__ void attvec_kernel(const float* __restrict__ hp, const float* __restrict__ asrc,
                              const float* __restrict__ adst, float* __restrict__ as_,
                              float* __restrict__ ad_) {
    int row = blockIdx.x * 4 + (threadIdx.x >> 6);
    int lane = threadIdx.x & 63;
    const float* p = hp + (size_t)row * DIM;
    float s = 0.f, d = 0.f;
    for (int i = lane; i < DIM; i += 64) { float v = p[i]; s += v * asrc[i]; d += v * adst[i]; }
    #pragma unroll
    for (int off = 32; off > 0; off >>= 1) { s += __shfl_down(s, off, 64); d += __shfl_down(d, off, 64); }
    if (lane == 0) { as_[row] = s; ad_[row] = d; }
}

// ---------------- GAT attention + aggregation ----------------
template<int RELU, int SPLIT>
__global__ __launch_bounds__(256) void aggr_kernel(const float* __restrict__ hp, const int* __restrict__ nbr,
                                                   const float* __restrict__ as_, const float* __restrict__ ad_,
                                                   const float* __restrict__ bias,
                                                   float* __restrict__ outf,
                                                   unsigned short* __restrict__ oh,
                                                   unsigned short* __restrict__ ol) {
    int id = blockIdx.x;                 // b*N + n
    int b = id >> 10;
    __shared__ float att[KP1];
    __shared__ int   jj[KP1];
    int t = threadIdx.x;
    if (t < KP1) {
        int j = nbr[id * KP1 + t];
        jj[t] = j;
        float e = as_[b * NNODE + j] + ad_[id];
        att[t] = (e >= 0.f) ? e : NEG * e;
    }
    __syncthreads();
    if (t == 0) {
        float mx = -INFINITY;
        for (int k = 0; k < KP1; ++k) mx = fmaxf(mx, att[k]);
        float s = 0.f;
        for (int k = 0; k < KP1; ++k) { float e = expf(att[k] - mx); att[k] = e; s += e; }
        float inv = 1.f / s;
        for (int k = 0; k < KP1; ++k) att[k] *= inv;
    }
    __syncthreads();
    const float* base = hp + (size_t)b * NNODE * DIM;
    for (int d = t; d < DIM; d += 256) {
        float o = bias[d];
        #pragma unroll
        for (int k = 0; k < KP1; ++k) o += att[k] * base[(size_t)jj[k] * DIM + d];
        if (RELU) o = fmaxf(o, 0.f);
        size_t idx = (size_t)id * DIM + d;
        if (SPLIT) split_store(o, oh, ol, idx);
        else       outf[idx] = o;
    }
}

// ---------------- global max pool over nodes ----------------
__global__ void maxpool_kernel(const float* __restrict__ h, float* __restrict__ g) {
    int id = blockIdx.x * 256 + threadIdx.x;     // b*DIM + d
    if (id >= BATCH * DIM) return;
    int b = id / DIM, d = id % DIM;
    const float* p = h + (size_t)b * NNODE * DIM + d;
    float m = -INFINITY;
    for (int n = 0; n < NNODE; ++n) m = fmaxf(m, p[(size_t)n * DIM]);
    g[id] = m;
}

// ---------------- final linear g @ Wc + bc ----------------
__global__ void final_kernel(const float* __restrict__ g, const float* __restrict__ Wc,
                             const float* __restrict__ bc, float* __restrict__ out) {
    int b = blockIdx.x, t = threadIdx.x;
    float s0 = 0.f, s1 = 0.f;
    for (int d = t; d < DIM; d += 256) {
        float v = g[b * DIM + d];
        s0 += v * Wc[d * 2 + 0];
        s1 += v * Wc[d * 2 + 1];
    }
    __shared__ float r0[256], r1[256];
    r0[t] = s0; r1[t] = s1; __syncthreads();
    for (int s = 128; s > 0; s >>= 1) {
        if (t < s) { r0[t] += r0[t + s]; r1[t] += r1[t + s]; }
        __syncthreads();
    }
    if (t == 0) { out[b * 2] = r0[0] + bc[0]; out[b * 2 + 1] = r1[0] + bc[1]; }
}

extern "C" void kernel_launch(void* const* d_in, const int* in_sizes, int n_in,
                              void* d_out, int out_size, void* d_ws, size_t ws_size,
                              hipStream_t stream) {
    const float* x     = (const float*)d_in[0];
    const float* W1    = (const float*)d_in[1];
    const float* asrc1 = (const float*)d_in[2];
    const float* adst1 = (const float*)d_in[3];
    const float* b1    = (const float*)d_in[4];
    const float* W2    = (const float*)d_in[5];
    const float* asrc2 = (const float*)d_in[6];
    const float* adst2 = (const float*)d_in[7];
    const float* b2    = (const float*)d_in[8];
    const float* W3    = (const float*)d_in[9];
    const float* asrc3 = (const float*)d_in[10];
    const float* adst3 = (const float*)d_in[11];
    const float* b3    = (const float*)d_in[12];
    const float* Wc    = (const float*)d_in[13];
    const float* bc    = (const float*)d_in[14];
    float* out = (float*)d_out;

    char* ws = (char*)d_ws;
    // [0,64MB): d2 (dead after knn). hp aliases low half, hA aliases high half.
    float*          d2    = (float*)ws;                            // 64MB
    float*          hp    = (float*)ws;                            // 32MB f32
    unsigned short* hA_hi = (unsigned short*)(ws + (32ull << 20)); // 16MB
    unsigned short* hA_lo = (unsigned short*)(ws + (48ull << 20)); // 16MB
    // [64,96MB): xh during graph build (dead after dist_mfma), then hB / h3.
    unsigned short* xh    = (unsigned short*)(ws + (64ull << 20)); // 16MB
    unsigned short* hB_hi = (unsigned short*)(ws + (64ull << 20)); // 16MB
    unsigned short* hB_lo = (unsigned short*)(ws + (80ull << 20)); // 16MB
    float*          h3    = (float*)(ws + (64ull << 20));          // 32MB, alias hB
    size_t off = 96ull << 20;
    unsigned short* Wt1h = (unsigned short*)(ws + off); off += (size_t)DIM * DIM * 2;
    unsigned short* Wt1l = (unsigned short*)(ws + off); off += (size_t)DIM * DIM * 2;
    unsigned short* Wt2h = (unsigned short*)(ws + off); off += (size_t)DIM * DIM * 2;
    unsigned short* Wt2l = (unsigned short*)(ws + off); off += (size_t)DIM * DIM * 2;
    unsigned short* Wt3h = (unsigned short*)(ws + off); off += (size_t)DIM * DIM * 2;
    unsigned short* Wt3l = (unsigned short*)(ws + off); off += (size_t)DIM * DIM * 2;
    int*      nbr    = (int*)(ws + off);      off += (size_t)BATCH * NNODE * KP1 * 4;
    int*      cand   = (int*)(ws + off);      off += (size_t)BATCH * NNODE * NCAND * 4;
    float*    sq     = (float*)(ws + off);    off += (size_t)BATCH * NNODE * 4;
    float*    mean   = (float*)(ws + off);    off += (size_t)BATCH * DIM * 4;
    unsigned* maxabs = (unsigned*)(ws + off); off += 256;
    float*    as_    = (float*)(ws + off);    off += (size_t)BATCH * NNODE * 4;
    float*    ad_    = (float*)(ws + off);    off += (size_t)BATCH * NNODE * 4;
    float*    g      = (float*)(ws + off);    off += (size_t)BATCH * DIM * 4;
    (void)ws_size; (void)in_sizes; (void)n_in; (void)out_size;

    // ---- graph construction: approx bf16 MFMA distances + exact f32 re-rank ----
    colmean_kernel<<<32, 256, 0, stream>>>(x, mean);
    rowsq_kernel<<<BATCH * NNODE / 4, 256, 0, stream>>>(x, sq);
    xtobf_kernel<<<BATCH * NNODE * DIM / 1024, 256, 0, stream>>>(x, xh);
    dist_mfma<<<dim3(NNODE / BT, BATCH * NNODE / BT), 256, 0, stream>>>(xh, sq, d2);
    knn_kernel<<<BATCH * NNODE / 4, 256, 0, stream>>>(d2, cand);
    rerank_kernel<<<BATCH * NNODE, 256, 0, stream>>>(x, sq, cand, nbr);
    // ---- weights transpose + split ----
    wsplit_kernel<<<dim3(16, 16), 256, 0, stream>>>(W1, Wt1h, Wt1l);
    wsplit_kernel<<<dim3(16, 16), 256, 0, stream>>>(W2, Wt2h, Wt2l);
    wsplit_kernel<<<dim3(16, 16), 256, 0, stream>>>(W3, Wt3h, Wt3l);
    // ---- normalize -> hA (split bf16); d2/xh dead from here ----
    init_maxabs<<<1, 64, 0, stream>>>(maxabs);
    maxabs_kernel<<<dim3(16, BATCH), 256, 0, stream>>>(x, mean, maxabs);
    normalize_kernel<<<BATCH * NNODE * DIM / 256, 256, 0, stream>>>(x, mean, maxabs, hA_hi, hA_lo);

    const dim3 ggrid(DIM / BT, BATCH * NNODE / BT);   // (4, 128)
    // layer 1
    gemm_mfma<<<ggrid, 256, 0, stream>>>(hA_hi, hA_lo, Wt1h, Wt1l, hp);
    attvec_kernel<<<BATCH * NNODE / 4, 256, 0, stream>>>(hp, asrc1, adst1, as_, ad_);
    aggr_kernel<1, 1><<<BATCH * NNODE, 256, 0, stream>>>(hp, nbr, as_, ad_, b1, nullptr, hB_hi, hB_lo);
    // layer 2
    gemm_mfma<<<ggrid, 256, 0, stream>>>(hB_hi, hB_lo, Wt2h, Wt2l, hp);
    attvec_kernel<<<BATCH * NNODE / 4, 256, 0, stream>>>(hp, asrc2, adst2, as_, ad_);
    aggr_kernel<1, 1><<<BATCH * NNODE, 256, 0, stream>>>(hp, nbr, as_, ad_, b2, hA_hi ? nullptr : nullptr, hA_hi, hA_lo);
    // layer 3
    gemm_mfma<<<ggrid, 256, 0, stream>>>(hA_hi, hA_lo, Wt3h, Wt3l, hp);
    attvec_kernel<<<BATCH * NNODE / 4, 256, 0, stream>>>(hp, asrc3, adst3, as_, ad_);
    aggr_kernel<0, 0><<<BATCH * NNODE, 256, 0, stream>>>(hp, nbr, as_, ad_, b3, h3, nullptr, nullptr);
    // pool + classify
    maxpool_kernel<<<BATCH * DIM / 256, 256, 0, stream>>>(h3, g);
    final_kernel<<<BATCH, 256, 0, stream>>>(g, Wc, bc, out);
}

// Round 5
// 550.406 us; speedup vs baseline: 2.1531x; 1.3162x over previous
//
#include <hip/hip_runtime.h>
#include <hip/hip_bf16.h>
#include <math.h>

#define BATCH 16
#define NNODE 1024
#define DIM   512
#define KNN   16
#define KP1   17
#define NCAND 24
#define NEG   0.2f
#define BT    128   // block tile
#define NCH   16    // n-chunks for column reductions

typedef __attribute__((ext_vector_type(8))) short bf16x8;
typedef __attribute__((ext_vector_type(4))) float f32x4;

__device__ __forceinline__ unsigned short f2bf(float f) {
    unsigned u = __float_as_uint(f);
    unsigned r = (u + 0x7FFFu + ((u >> 16) & 1u)) >> 16;   // RNE
    return (unsigned short)r;
}
__device__ __forceinline__ float bf2f(unsigned short h) {
    return __uint_as_float(((unsigned)h) << 16);
}
__device__ __forceinline__ void split_store(float v, unsigned short* hi, unsigned short* lo, size_t idx) {
    unsigned short h = f2bf(v);
    hi[idx] = h;
    lo[idx] = f2bf(v - bf2f(h));
}

// ---------------- column mean, stage 1: partial sums over 64-node chunks ----------------
__global__ __launch_bounds__(256) void colmean_part(const float* __restrict__ x, float* __restrict__ part) {
    int b = blockIdx.x, dc = blockIdx.y, ch = blockIdx.z;
    int d = dc * 256 + threadIdx.x;
    const float* p = x + ((size_t)b * NNODE + ch * (NNODE / NCH)) * DIM + d;
    float s = 0.f;
    #pragma unroll 4
    for (int n = 0; n < NNODE / NCH; ++n) s += p[(size_t)n * DIM];
    part[((size_t)b * NCH + ch) * DIM + d] = s;
}
__global__ void colmean_fin(const float* __restrict__ part, float* __restrict__ mean) {
    int id = blockIdx.x * 256 + threadIdx.x;   // b*DIM + d
    int b = id >> 9, d = id & (DIM - 1);
    float s = 0.f;
    #pragma unroll
    for (int ch = 0; ch < NCH; ++ch) s += part[((size_t)b * NCH + ch) * DIM + d];
    mean[id] = s * (1.0f / NNODE);
}

// ---------------- row squared norms of raw pos ----------------
__global__ void rowsq_kernel(const float* __restrict__ x, float* __restrict__ sq) {
    int row = blockIdx.x * 4 + (threadIdx.x >> 6);
    int lane = threadIdx.x & 63;
    const float* p = x + (size_t)row * DIM;
    float s = 0.f;
    for (int i = lane; i < DIM; i += 64) { float v = p[i]; s += v * v; }
    #pragma unroll
    for (int off = 32; off > 0; off >>= 1) s += __shfl_down(s, off, 64);
    if (lane == 0) sq[row] = s;
}

// ---------------- x -> bf16 (for approximate candidate distances) ----------------
__global__ void xtobf_kernel(const float* __restrict__ x, unsigned short* __restrict__ xh) {
    int id = blockIdx.x * 256 + threadIdx.x;
    float4 v = *(const float4*)(x + (size_t)id * 4);
    ushort4 o;
    o.x = f2bf(v.x); o.y = f2bf(v.y); o.z = f2bf(v.z); o.w = f2bf(v.w);
    *(ushort4*)(xh + (size_t)id * 4) = o;
}

// ---------------- approx distance matrix via bf16 MFMA (candidate stage) ----------------
__global__ __launch_bounds__(256, 2) void dist_mfma(const unsigned short* __restrict__ xh,
                                                    const float* __restrict__ sq,
                                                    float* __restrict__ d2) {
    __shared__ unsigned short AhL[128][40], BhL[128][40];
    int mt = blockIdx.y;
    int b = mt >> 3;
    int m0 = mt * BT;
    int n0 = blockIdx.x * BT;
    int bn0 = b * NNODE + n0;
    int t = threadIdx.x;
    int lane = t & 63, w = t >> 6;
    int wm = (w >> 1) * 64, wn = (w & 1) * 64;
    int fr = lane & 15, fk = (lane >> 4) * 8;
    f32x4 acc[4][4];
    #pragma unroll
    for (int i = 0; i < 4; ++i)
        #pragma unroll
        for (int j = 0; j < 4; ++j) acc[i][j] = (f32x4){0.f, 0.f, 0.f, 0.f};

    for (int k0 = 0; k0 < DIM; k0 += 32) {
        if (k0) __syncthreads();
        #pragma unroll
        for (int p = 0; p < 2; ++p) {
            int u = t + p * 256;
            int row = u >> 2, seg = (u & 3) * 8;
            *(uint4*)&AhL[row][seg] = *(const uint4*)(xh + (size_t)(m0 + row) * DIM + k0 + seg);
            *(uint4*)&BhL[row][seg] = *(const uint4*)(xh + (size_t)(bn0 + row) * DIM + k0 + seg);
        }
        __syncthreads();
        bf16x8 ah[4], bh[4];
        #pragma unroll
        for (int i = 0; i < 4; ++i) {
            ah[i] = *(const bf16x8*)&AhL[wm + i * 16 + fr][fk];
            bh[i] = *(const bf16x8*)&BhL[wn + i * 16 + fr][fk];
        }
        #pragma unroll
        for (int i = 0; i < 4; ++i)
            #pragma unroll
            for (int j = 0; j < 4; ++j)
                acc[i][j] = __builtin_amdgcn_mfma_f32_16x16x32_bf16(ah[i], bh[j], acc[i][j], 0, 0, 0);
    }
    const float* sqb = sq + b * NNODE;
    int mloc0 = m0 - b * NNODE;
    #pragma unroll
    for (int i = 0; i < 4; ++i) {
        int mloc = mloc0 + wm + i * 16 + (lane >> 4) * 4;
        #pragma unroll
        for (int j = 0; j < 4; ++j) {
            int n = n0 + wn + j * 16 + fr;
            float sqn = sqb[n];
            #pragma unroll
            for (int r = 0; r < 4; ++r) {
                float val = sqb[mloc + r] + sqn - 2.f * acc[i][j][r];
                if (mloc + r == n) val = INFINITY;
                d2[((size_t)b * NNODE + mloc + r) * NNODE + n] = val;
            }
        }
    }
}

// ---------------- top-24 smallest per row (approx) -> candidates ----------------
__global__ __launch_bounds__(256) void knn_kernel(const float* __restrict__ d2, int* __restrict__ cand) {
    int row = blockIdx.x * 4 + (threadIdx.x >> 6);   // b*N + n
    int l = threadIdx.x & 63;
    const float* src = d2 + (size_t)row * NNODE;
    float v[16];
    #pragma unroll
    for (int j = 0; j < 16; ++j) v[j] = src[l + (j << 6)];
    int* dst = cand + row * NCAND;
    for (int it = 0; it < NCAND; ++it) {
        unsigned long long key = ~0ull;
        #pragma unroll
        for (int j = 0; j < 16; ++j) {
            unsigned long long k = ((unsigned long long)__float_as_uint(v[j]) << 32)
                                 | (unsigned)(l + (j << 6));
            if (k < key) key = k;
        }
        #pragma unroll
        for (int off = 1; off < 64; off <<= 1) {
            unsigned long long o = __shfl_xor(key, off, 64);
            if (o < key) key = o;
        }
        int idx = (int)(key & 0xFFFFFFFFull);
        if ((idx & 63) == l) v[idx >> 6] = INFINITY;
        if (l == 0) dst[it] = idx;
    }
}

// ---------------- exact f32 re-rank of candidates -> nbr[17] ----------------
__global__ __launch_bounds__(256) void rerank_kernel(const float* __restrict__ x,
                                                     const float* __restrict__ sq,
                                                     const int* __restrict__ cand,
                                                     int* __restrict__ nbr) {
    int row = blockIdx.x;                // b*N + m
    int b = row >> 10;
    int w = threadIdx.x >> 6, l = threadIdx.x & 63;
    const float* xm = x + (size_t)row * DIM;
    float4 m0v = *(const float4*)(xm + l * 8);
    float4 m1v = *(const float4*)(xm + l * 8 + 4);
    __shared__ float dval[NCAND];
    __shared__ int   didx[NCAND];
    const float* xb = x + (size_t)b * NNODE * DIM;
    const float* sqb = sq + b * NNODE;
    float sqm = sq[row];
    for (int c = w; c < NCAND; c += 4) {
        int j = cand[row * NCAND + c];
        const float* xj = xb + (size_t)j * DIM;
        float4 j0 = *(const float4*)(xj + l * 8);
        float4 j1 = *(const float4*)(xj + l * 8 + 4);
        float s = m0v.x * j0.x + m0v.y * j0.y + m0v.z * j0.z + m0v.w * j0.w
                + m1v.x * j1.x + m1v.y * j1.y + m1v.z * j1.z + m1v.w * j1.w;
        #pragma unroll
        for (int off = 32; off > 0; off >>= 1) s += __shfl_down(s, off, 64);
        if (l == 0) { dval[c] = sqm + sqb[j] - 2.f * s; didx[c] = j; }
    }
    __syncthreads();
    if (w == 0) {
        unsigned long long mykey = ~0ull;
        if (l < NCAND)
            mykey = ((unsigned long long)__float_as_uint(dval[l]) << 32) | (unsigned)didx[l];
        int* dst = nbr + row * KP1;
        for (int it = 0; it < KNN; ++it) {
            unsigned long long kmin = mykey;
            #pragma unroll
            for (int off = 1; off < 32; off <<= 1) {
                unsigned long long o = __shfl_xor(kmin, off, 64);
                if (o < kmin) kmin = o;
            }
            if (mykey == kmin && mykey != ~0ull) mykey = ~0ull;
            if (l == 0) dst[it] = (int)(kmin & 0xFFFFFFFFull);
        }
        if (l == 0) dst[KNN] = row & (NNODE - 1);
    }
}

// ---------------- per-graph max|x - mean| ----------------
__global__ void init_maxabs(unsigned* maxabs) { if (threadIdx.x < BATCH) maxabs[threadIdx.x] = 0u; }

__global__ __launch_bounds__(256) void maxabs_kernel(const float* __restrict__ x,
                                                     const float* __restrict__ mean,
                                                     unsigned* __restrict__ maxabs) {
    int b = blockIdx.y;
    const float* p = x + ((size_t)b * NNODE + blockIdx.x * 64) * DIM;
    const float* mb = mean + b * DIM;
    float m = 0.f;
    for (int i = threadIdx.x; i < 64 * DIM; i += 256) {
        int d = i & (DIM - 1);
        m = fmaxf(m, fabsf(p[i] - mb[d]));
    }
    __shared__ float red[256];
    red[threadIdx.x] = m; __syncthreads();
    for (int s = 128; s > 0; s >>= 1) {
        if (threadIdx.x < s) red[threadIdx.x] = fmaxf(red[threadIdx.x], red[threadIdx.x + s]);
        __syncthreads();
    }
    if (threadIdx.x == 0) atomicMax(maxabs + b, __float_as_uint(red[0]));
}

// ---------------- h0 = (x - mean) * 0.999999/maxabs -> split bf16 hi/lo ----------------
__global__ void normalize_kernel(const float* __restrict__ x, const float* __restrict__ mean,
                                 const unsigned* __restrict__ maxabs,
                                 unsigned short* __restrict__ h_hi, unsigned short* __restrict__ h_lo) {
    int id = blockIdx.x * 256 + threadIdx.x;
    int b = id >> 19;
    int d = id & (DIM - 1);
    float scale = 0.999999f / __uint_as_float(maxabs[b]);
    float v = (x[id] - mean[b * DIM + d]) * scale;
    split_store(v, h_hi, h_lo, id);
}

// ---------------- W[512x512] -> Wt hi/lo bf16 [n][k] (transpose + split) ----------------
__global__ void wsplit_kernel(const float* __restrict__ W,
                              unsigned short* __restrict__ Wh, unsigned short* __restrict__ Wl) {
    __shared__ float tile[32][33];
    int bx = blockIdx.x * 32, by = blockIdx.y * 32;
    int tx = threadIdx.x & 31, ty = threadIdx.x >> 5;
    #pragma unroll
    for (int i = 0; i < 4; ++i)
        tile[ty + i * 8][tx] = W[(size_t)(by + ty + i * 8) * DIM + bx + tx];
    __syncthreads();
    #pragma unroll
    for (int i = 0; i < 4; ++i) {
        int n = bx + ty + i * 8;
        float v = tile[tx][ty + i * 8];
        split_store(v, Wh, Wl, (size_t)n * DIM + by + tx);
    }
}

// ---------------- C f32 = (Ah+Al) . (Wh+Wl), split-bf16 MFMA ----------------
__global__ __launch_bounds__(256, 2) void gemm_mfma(const unsigned short* __restrict__ Agh,
                                                    const unsigned short* __restrict__ Agl,
                                                    const unsigned short* __restrict__ Bgh,
                                                    const unsigned short* __restrict__ Bgl,
                                                    float* __restrict__ C) {
    __shared__ unsigned short AhL[128][40], AlL[128][40], BhL[128][40], BlL[128][40];
    int m0 = blockIdx.y * BT, n0 = blockIdx.x * BT;
    int t = threadIdx.x;
    int lane = t & 63, w = t >> 6;
    int wm = (w >> 1) * 64, wn = (w & 1) * 64;
    int fr = lane & 15, fk = (lane >> 4) * 8;
    f32x4 acc[4][4];
    #pragma unroll
    for (int i = 0; i < 4; ++i)
        #pragma unroll
        for (int j = 0; j < 4; ++j) acc[i][j] = (f32x4){0.f, 0.f, 0.f, 0.f};

    for (int k0 = 0; k0 < DIM; k0 += 32) {
        if (k0) __syncthreads();
        #pragma unroll
        for (int p = 0; p < 2; ++p) {
            int u = t + p * 256;
            int row = u >> 2, seg = (u & 3) * 8;
            *(uint4*)&AhL[row][seg] = *(const uint4*)(Agh + (size_t)(m0 + row) * DIM + k0 + seg);
            *(uint4*)&AlL[row][seg] = *(const uint4*)(Agl + (size_t)(m0 + row) * DIM + k0 + seg);
            *(uint4*)&BhL[row][seg] = *(const uint4*)(Bgh + (size_t)(n0 + row) * DIM + k0 + seg);
            *(uint4*)&BlL[row][seg] = *(const uint4*)(Bgl + (size_t)(n0 + row) * DIM + k0 + seg);
        }
        __syncthreads();
        bf16x8 ah[4], al[4], bh[4], bl[4];
        #pragma unroll
        for (int i = 0; i < 4; ++i) {
            ah[i] = *(const bf16x8*)&AhL[wm + i * 16 + fr][fk];
            al[i] = *(const bf16x8*)&AlL[wm + i * 16 + fr][fk];
            bh[i] = *(const bf16x8*)&BhL[wn + i * 16 + fr][fk];
            bl[i] = *(const bf16x8*)&BlL[wn + i * 16 + fr][fk];
        }
        #pragma unroll
        for (int i = 0; i < 4; ++i)
            #pragma unroll
            for (int j = 0; j < 4; ++j) {
                acc[i][j] = __builtin_amdgcn_mfma_f32_16x16x32_bf16(ah[i], bh[j], acc[i][j], 0, 0, 0);
                acc[i][j] = __builtin_amdgcn_mfma_f32_16x16x32_bf16(ah[i], bl[j], acc[i][j], 0, 0, 0);
                acc[i][j] = __builtin_amdgcn_mfma_f32_16x16x32_bf16(al[i], bh[j], acc[i][j], 0, 0, 0);
            }
    }
    #pragma unroll
    for (int i = 0; i < 4; ++i) {
        int mrow = m0 + wm + i * 16 + (lane >> 4) * 4;
        #pragma unroll
        for (int j = 0; j < 4; ++j) {
            int col = n0 + wn + j * 16 + fr;
            #pragma unroll
            for (int r = 0; r < 4; ++r)
                C[(size_t)(mrow + r) * DIM + col] = acc[i][j][r];
        }
    }
}

// ---------------- a_s = hp @ asrc, a_d = hp @ adst ----------------
__global__ void attvec_kernel(const float* __restrict__ hp, const float* __restrict__ asrc,
                              const float* __restrict__ adst, float* __restrict__ as_,
                              float* __restrict__ ad_) {
    int row = blockIdx.x * 4 + (threadIdx.x >> 6);
    int lane = threadIdx.x & 63;
    const float* p = hp + (size_t)row * DIM;
    float s = 0.f, d = 0.f;
    for (int i = lane; i < DIM; i += 64) { float v = p[i]; s += v * asrc[i]; d += v * adst[i]; }
    #pragma unroll
    for (int off = 32; off > 0; off >>= 1) { s += __shfl_down(s, off, 64); d += __shfl_down(d, off, 64); }
    if (lane == 0) { as_[row] = s; ad_[row] = d; }
}

// ---------------- GAT attention + aggregation ----------------
template<int RELU, int SPLIT>
__global__ __launch_bounds__(256) void aggr_kernel(const float* __restrict__ hp, const int* __restrict__ nbr,
                                                   const float* __restrict__ as_, const float* __restrict__ ad_,
                                                   const float* __restrict__ bias,
                                                   float* __restrict__ outf,
                                                   unsigned short* __restrict__ oh,
                                                   unsigned short* __restrict__ ol) {
    int id = blockIdx.x;                 // b*N + n
    int b = id >> 10;
    __shared__ float att[KP1];
    __shared__ int   jj[KP1];
    int t = threadIdx.x;
    if (t < KP1) {
        int j = nbr[id * KP1 + t];
        jj[t] = j;
        float e = as_[b * NNODE + j] + ad_[id];
        att[t] = (e >= 0.f) ? e : NEG * e;
    }
    __syncthreads();
    if (t == 0) {
        float mx = -INFINITY;
        for (int k = 0; k < KP1; ++k) mx = fmaxf(mx, att[k]);
        float s = 0.f;
        for (int k = 0; k < KP1; ++k) { float e = expf(att[k] - mx); att[k] = e; s += e; }
        float inv = 1.f / s;
        for (int k = 0; k < KP1; ++k) att[k] *= inv;
    }
    __syncthreads();
    const float* base = hp + (size_t)b * NNODE * DIM;
    for (int d = t; d < DIM; d += 256) {
        float o = bias[d];
        #pragma unroll
        for (int k = 0; k < KP1; ++k) o += att[k] * base[(size_t)jj[k] * DIM + d];
        if (RELU) o = fmaxf(o, 0.f);
        size_t idx = (size_t)id * DIM + d;
        if (SPLIT) split_store(o, oh, ol, idx);
        else       outf[idx] = o;
    }
}

// ---------------- global max pool, stage 1: partial max over 64-node chunks ----------------
__global__ __launch_bounds__(256) void maxpool_part(const float* __restrict__ h, float* __restrict__ part) {
    int b = blockIdx.x, dc = blockIdx.y, ch = blockIdx.z;
    int d = dc * 256 + threadIdx.x;
    const float* p = h + ((size_t)b * NNODE + ch * (NNODE / NCH)) * DIM + d;
    float m = -INFINITY;
    #pragma unroll 4
    for (int n = 0; n < NNODE / NCH; ++n) m = fmaxf(m, p[(size_t)n * DIM]);
    part[((size_t)b * NCH + ch) * DIM + d] = m;
}
__global__ void maxpool_fin(const float* __restrict__ part, float* __restrict__ g) {
    int id = blockIdx.x * 256 + threadIdx.x;   // b*DIM + d
    int b = id >> 9, d = id & (DIM - 1);
    float m = -INFINITY;
    #pragma unroll
    for (int ch = 0; ch < NCH; ++ch) m = fmaxf(m, part[((size_t)b * NCH + ch) * DIM + d]);
    g[id] = m;
}

// ---------------- final linear g @ Wc + bc ----------------
__global__ void final_kernel(const float* __restrict__ g, const float* __restrict__ Wc,
                             const float* __restrict__ bc, float* __restrict__ out) {
    int b = blockIdx.x, t = threadIdx.x;
    float s0 = 0.f, s1 = 0.f;
    for (int d = t; d < DIM; d += 256) {
        float v = g[b * DIM + d];
        s0 += v * Wc[d * 2 + 0];
        s1 += v * Wc[d * 2 + 1];
    }
    __shared__ float r0[256], r1[256];
    r0[t] = s0; r1[t] = s1; __syncthreads();
    for (int s = 128; s > 0; s >>= 1) {
        if (t < s) { r0[t] += r0[t + s]; r1[t] += r1[t + s]; }
        __syncthreads();
    }
    if (t == 0) { out[b * 2] = r0[0] + bc[0]; out[b * 2 + 1] = r1[0] + bc[1]; }
}

extern "C" void kernel_launch(void* const* d_in, const int* in_sizes, int n_in,
                              void* d_out, int out_size, void* d_ws, size_t ws_size,
                              hipStream_t stream) {
    const float* x     = (const float*)d_in[0];
    const float* W1    = (const float*)d_in[1];
    const float* asrc1 = (const float*)d_in[2];
    const float* adst1 = (const float*)d_in[3];
    const float* b1    = (const float*)d_in[4];
    const float* W2    = (const float*)d_in[5];
    const float* asrc2 = (const float*)d_in[6];
    const float* adst2 = (const float*)d_in[7];
    const float* b2    = (const float*)d_in[8];
    const float* W3    = (const float*)d_in[9];
    const float* asrc3 = (const float*)d_in[10];
    const float* adst3 = (const float*)d_in[11];
    const float* b3    = (const float*)d_in[12];
    const float* Wc    = (const float*)d_in[13];
    const float* bc    = (const float*)d_in[14];
    float* out = (float*)d_out;

    char* ws = (char*)d_ws;
    float*          d2    = (float*)ws;                            // 64MB (graph build only)
    float*          hp    = (float*)ws;                            // 32MB f32
    unsigned short* hA_hi = (unsigned short*)(ws + (32ull << 20)); // 16MB
    unsigned short* hA_lo = (unsigned short*)(ws + (48ull << 20)); // 16MB
    unsigned short* xh    = (unsigned short*)(ws + (64ull << 20)); // 16MB (graph build only)
    unsigned short* hB_hi = (unsigned short*)(ws + (64ull << 20)); // 16MB
    unsigned short* hB_lo = (unsigned short*)(ws + (80ull << 20)); // 16MB
    float*          h3    = (float*)(ws + (64ull << 20));          // 32MB, alias hB
    size_t off = 96ull << 20;
    unsigned short* Wt1h = (unsigned short*)(ws + off); off += (size_t)DIM * DIM * 2;
    unsigned short* Wt1l = (unsigned short*)(ws + off); off += (size_t)DIM * DIM * 2;
    unsigned short* Wt2h = (unsigned short*)(ws + off); off += (size_t)DIM * DIM * 2;
    unsigned short* Wt2l = (unsigned short*)(ws + off); off += (size_t)DIM * DIM * 2;
    unsigned short* Wt3h = (unsigned short*)(ws + off); off += (size_t)DIM * DIM * 2;
    unsigned short* Wt3l = (unsigned short*)(ws + off); off += (size_t)DIM * DIM * 2;
    int*      nbr    = (int*)(ws + off);      off += (size_t)BATCH * NNODE * KP1 * 4;
    int*      cand   = (int*)(ws + off);      off += (size_t)BATCH * NNODE * NCAND * 4;
    float*    sq     = (float*)(ws + off);    off += (size_t)BATCH * NNODE * 4;
    float*    mean   = (float*)(ws + off);    off += (size_t)BATCH * DIM * 4;
    unsigned* maxabs = (unsigned*)(ws + off); off += 256;
    float*    as_    = (float*)(ws + off);    off += (size_t)BATCH * NNODE * 4;
    float*    ad_    = (float*)(ws + off);    off += (size_t)BATCH * NNODE * 4;
    float*    g      = (float*)(ws + off);    off += (size_t)BATCH * DIM * 4;
    float*    part   = (float*)(ws + off);    off += (size_t)BATCH * NCH * DIM * 4;  // 512KB scratch
    (void)ws_size; (void)in_sizes; (void)n_in; (void)out_size;

    const dim3 cgrid(BATCH, DIM / 256, NCH);
    // ---- graph construction: approx bf16 MFMA distances + exact f32 re-rank ----
    colmean_part<<<cgrid, 256, 0, stream>>>(x, part);
    colmean_fin<<<BATCH * DIM / 256, 256, 0, stream>>>(part, mean);
    rowsq_kernel<<<BATCH * NNODE / 4, 256, 0, stream>>>(x, sq);
    xtobf_kernel<<<BATCH * NNODE * DIM / 1024, 256, 0, stream>>>(x, xh);
    dist_mfma<<<dim3(NNODE / BT, BATCH * NNODE / BT), 256, 0, stream>>>(xh, sq, d2);
    knn_kernel<<<BATCH * NNODE / 4, 256, 0, stream>>>(d2, cand);
    rerank_kernel<<<BATCH * NNODE, 256, 0, stream>>>(x, sq, cand, nbr);
    // ---- weights transpose + split ----
    wsplit_kernel<<<dim3(16, 16), 256, 0, stream>>>(W1, Wt1h, Wt1l);
    wsplit_kernel<<<dim3(16, 16), 256, 0, stream>>>(W2, Wt2h, Wt2l);
    wsplit_kernel<<<dim3(16, 16), 256, 0, stream>>>(W3, Wt3h, Wt3l);
    // ---- normalize -> hA (split bf16); d2/xh dead from here ----
    init_maxabs<<<1, 64, 0, stream>>>(maxabs);
    maxabs_kernel<<<dim3(16, BATCH), 256, 0, stream>>>(x, mean, maxabs);
    normalize_kernel<<<BATCH * NNODE * DIM / 256, 256, 0, stream>>>(x, mean, maxabs, hA_hi, hA_lo);

    const dim3 ggrid(DIM / BT, BATCH * NNODE / BT);   // (4, 128)
    // layer 1
    gemm_mfma<<<ggrid, 256, 0, stream>>>(hA_hi, hA_lo, Wt1h, Wt1l, hp);
    attvec_kernel<<<BATCH * NNODE / 4, 256, 0, stream>>>(hp, asrc1, adst1, as_, ad_);
    aggr_kernel<1, 1><<<BATCH * NNODE, 256, 0, stream>>>(hp, nbr, as_, ad_, b1, nullptr, hB_hi, hB_lo);
    // layer 2
    gemm_mfma<<<ggrid, 256, 0, stream>>>(hB_hi, hB_lo, Wt2h, Wt2l, hp);
    attvec_kernel<<<BATCH * NNODE / 4, 256, 0, stream>>>(hp, asrc2, adst2, as_, ad_);
    aggr_kernel<1, 1><<<BATCH * NNODE, 256, 0, stream>>>(hp, nbr, as_, ad_, b2, nullptr, hA_hi, hA_lo);
    // layer 3
    gemm_mfma<<<ggrid, 256, 0, stream>>>(hA_hi, hA_lo, Wt3h, Wt3l, hp);
    attvec_kernel<<<BATCH * NNODE / 4, 256, 0, stream>>>(hp, asrc3, adst3, as_, ad_);
    aggr_kernel<0, 0><<<BATCH * NNODE, 256, 0, stream>>>(hp, nbr, as_, ad_, b3, h3, nullptr, nullptr);
    // pool + classify
    maxpool_part<<<cgrid, 256, 0, stream>>>(h3, part);
    maxpool_fin<<<BATCH * DIM / 256, 256, 0, stream>>>(part, g);
    final_kernel<<<BATCH, 256, 0, stream>>>(g, Wc, bc, out);
}

// Round 7
// 504.557 us; speedup vs baseline: 2.3487x; 1.0909x over previous
//
#include <hip/hip_runtime.h>
#include <hip/hip_bf16.h>
#include <math.h>

#define BATCH 16
#define NNODE 1024
#define DIM   512
#define KNN   16
#define KP1   17
#define NCAND 24
#define NEG   0.2f
#define BT    128   // block tile
#define NCH   16    // n-chunks for column reductions

typedef __attribute__((ext_vector_type(8))) short bf16x8;
typedef __attribute__((ext_vector_type(4))) float f32x4;

__device__ __forceinline__ unsigned short f2bf(float f) {
    unsigned u = __float_as_uint(f);
    unsigned r = (u + 0x7FFFu + ((u >> 16) & 1u)) >> 16;   // RNE
    return (unsigned short)r;
}
__device__ __forceinline__ float bf2f(unsigned short h) {
    return __uint_as_float(((unsigned)h) << 16);
}
__device__ __forceinline__ void split_store(float v, unsigned short* hi, unsigned short* lo, size_t idx) {
    unsigned short h = f2bf(v);
    hi[idx] = h;
    lo[idx] = f2bf(v - bf2f(h));
}

// ---------------- column mean, stage 1: partial sums over 64-node chunks ----------------
__global__ __launch_bounds__(256) void colmean_part(const float* __restrict__ x, float* __restrict__ part) {
    int b = blockIdx.x, dc = blockIdx.y, ch = blockIdx.z;
    int d = dc * 256 + threadIdx.x;
    const float* p = x + ((size_t)b * NNODE + ch * (NNODE / NCH)) * DIM + d;
    float s = 0.f;
    #pragma unroll 4
    for (int n = 0; n < NNODE / NCH; ++n) s += p[(size_t)n * DIM];
    part[((size_t)b * NCH + ch) * DIM + d] = s;
}
__global__ void colmean_fin(const float* __restrict__ part, float* __restrict__ mean) {
    int id = blockIdx.x * 256 + threadIdx.x;   // b*DIM + d
    int b = id >> 9, d = id & (DIM - 1);
    float s = 0.f;
    #pragma unroll
    for (int ch = 0; ch < NCH; ++ch) s += part[((size_t)b * NCH + ch) * DIM + d];
    mean[id] = s * (1.0f / NNODE);
}

// ---------------- row squared norms of raw pos ----------------
__global__ void rowsq_kernel(const float* __restrict__ x, float* __restrict__ sq) {
    int row = blockIdx.x * 4 + (threadIdx.x >> 6);
    int lane = threadIdx.x & 63;
    const float* p = x + (size_t)row * DIM;
    float s = 0.f;
    for (int i = lane; i < DIM; i += 64) { float v = p[i]; s += v * v; }
    #pragma unroll
    for (int off = 32; off > 0; off >>= 1) s += __shfl_down(s, off, 64);
    if (lane == 0) sq[row] = s;
}

// ---------------- x -> bf16 (for approximate candidate distances) ----------------
__global__ void xtobf_kernel(const float* __restrict__ x, unsigned short* __restrict__ xh) {
    int id = blockIdx.x * 256 + threadIdx.x;
    float4 v = *(const float4*)(x + (size_t)id * 4);
    ushort4 o;
    o.x = f2bf(v.x); o.y = f2bf(v.y); o.z = f2bf(v.z); o.w = f2bf(v.w);
    *(ushort4*)(xh + (size_t)id * 4) = o;
}

// ---------------- approx distance matrix via bf16 MFMA (candidate stage) ----------------
__global__ __launch_bounds__(256, 2) void dist_mfma(const unsigned short* __restrict__ xh,
                                                    const float* __restrict__ sq,
                                                    float* __restrict__ d2) {
    __shared__ unsigned short AhL[128][40], BhL[128][40];
    int mt = blockIdx.y;
    int b = mt >> 3;
    int m0 = mt * BT;
    int n0 = blockIdx.x * BT;
    int bn0 = b * NNODE + n0;
    int t = threadIdx.x;
    int lane = t & 63, w = t >> 6;
    int wm = (w >> 1) * 64, wn = (w & 1) * 64;
    int fr = lane & 15, fk = (lane >> 4) * 8;
    f32x4 acc[4][4];
    #pragma unroll
    for (int i = 0; i < 4; ++i)
        #pragma unroll
        for (int j = 0; j < 4; ++j) acc[i][j] = (f32x4){0.f, 0.f, 0.f, 0.f};

    for (int k0 = 0; k0 < DIM; k0 += 32) {
        if (k0) __syncthreads();
        #pragma unroll
        for (int p = 0; p < 2; ++p) {
            int u = t + p * 256;
            int row = u >> 2, seg = (u & 3) * 8;
            *(uint4*)&AhL[row][seg] = *(const uint4*)(xh + (size_t)(m0 + row) * DIM + k0 + seg);
            *(uint4*)&BhL[row][seg] = *(const uint4*)(xh + (size_t)(bn0 + row) * DIM + k0 + seg);
        }
        __syncthreads();
        bf16x8 ah[4], bh[4];
        #pragma unroll
        for (int i = 0; i < 4; ++i) {
            ah[i] = *(const bf16x8*)&AhL[wm + i * 16 + fr][fk];
            bh[i] = *(const bf16x8*)&BhL[wn + i * 16 + fr][fk];
        }
        #pragma unroll
        for (int i = 0; i < 4; ++i)
            #pragma unroll
            for (int j = 0; j < 4; ++j)
                acc[i][j] = __builtin_amdgcn_mfma_f32_16x16x32_bf16(ah[i], bh[j], acc[i][j], 0, 0, 0);
    }
    const float* sqb = sq + b * NNODE;
    int mloc0 = m0 - b * NNODE;
    #pragma unroll
    for (int i = 0; i < 4; ++i) {
        int mloc = mloc0 + wm + i * 16 + (lane >> 4) * 4;
        #pragma unroll
        for (int j = 0; j < 4; ++j) {
            int n = n0 + wn + j * 16 + fr;
            float sqn = sqb[n];
            #pragma unroll
            for (int r = 0; r < 4; ++r) {
                float val = sqb[mloc + r] + sqn - 2.f * acc[i][j][r];
                if (mloc + r == n) val = INFINITY;
                d2[((size_t)b * NNODE + mloc + r) * NNODE + n] = val;
            }
        }
    }
}

// ---------------- top-24 smallest per row (approx): u32 keys + threshold walk ----------------
// key = (f32 bits truncated to 22) | 10-bit idx. Positive floats -> bit order = value order.
// Winners strictly increase in key order, so iter k = min over {key > lastWinner}: no removal.
__global__ __launch_bounds__(256) void knn_kernel(const float* __restrict__ d2, int* __restrict__ cand) {
    int row = blockIdx.x * 4 + (threadIdx.x >> 6);   // b*N + n
    int l = threadIdx.x & 63;
    const float* src = d2 + (size_t)row * NNODE;
    unsigned key[16];
    #pragma unroll
    for (int j = 0; j < 16; ++j) {
        unsigned v = __float_as_uint(src[l + (j << 6)]);
        key[j] = (v & 0xFFFFFC00u) | (unsigned)(l + (j << 6));
    }
    int* dst = cand + row * NCAND;
    unsigned T = 0;                                  // d2 ~ O(1000): key bits >> 0 always
    for (int it = 0; it < NCAND; ++it) {
        unsigned lmin = 0xFFFFFFFFu;
        #pragma unroll
        for (int j = 0; j < 16; ++j) {
            unsigned k = (key[j] > T) ? key[j] : 0xFFFFFFFFu;
            lmin = min(lmin, k);
        }
        #pragma unroll
        for (int off = 1; off < 64; off <<= 1) {
            unsigned o = (unsigned)__shfl_xor((int)lmin, off, 64);
            lmin = min(lmin, o);
        }
        T = lmin;
        if (l == 0) dst[it] = (int)(lmin & 1023u);
    }
}

// ---------------- exact f32 re-rank of candidates -> nbr[17] ----------------
__global__ __launch_bounds__(256) void rerank_kernel(const float* __restrict__ x,
                                                     const float* __restrict__ sq,
                                                     const int* __restrict__ cand,
                                                     int* __restrict__ nbr) {
    int row = blockIdx.x;                // b*N + m
    int b = row >> 10;
    int w = threadIdx.x >> 6, l = threadIdx.x & 63;
    const float* xm = x + (size_t)row * DIM;
    float4 m0v = *(const float4*)(xm + l * 8);
    float4 m1v = *(const float4*)(xm + l * 8 + 4);
    __shared__ float dval[NCAND];
    __shared__ int   didx[NCAND];
    const float* xb = x + (size_t)b * NNODE * DIM;
    const float* sqb = sq + b * NNODE;
    float sqm = sq[row];
    for (int c = w; c < NCAND; c += 4) {
        int j = cand[row * NCAND + c];
        const float* xj = xb + (size_t)j * DIM;
        float4 j0 = *(const float4*)(xj + l * 8);
        float4 j1 = *(const float4*)(xj + l * 8 + 4);
        float s = m0v.x * j0.x + m0v.y * j0.y + m0v.z * j0.z + m0v.w * j0.w
                + m1v.x * j1.x + m1v.y * j1.y + m1v.z * j1.z + m1v.w * j1.w;
        #pragma unroll
        for (int off = 32; off > 0; off >>= 1) s += __shfl_down(s, off, 64);
        if (l == 0) { dval[c] = sqm + sqb[j] - 2.f * s; didx[c] = j; }
    }
    __syncthreads();
    if (w == 0) {
        unsigned long long mykey = ~0ull;
        if (l < NCAND)
            mykey = ((unsigned long long)__float_as_uint(dval[l]) << 32) | (unsigned)didx[l];
        int* dst = nbr + row * KP1;
        for (int it = 0; it < KNN; ++it) {
            unsigned long long kmin = mykey;
            #pragma unroll
            for (int off = 1; off < 32; off <<= 1) {
                unsigned long long o = __shfl_xor(kmin, off, 64);
                if (o < kmin) kmin = o;
            }
            if (mykey == kmin && mykey != ~0ull) mykey = ~0ull;
            if (l == 0) dst[it] = (int)(kmin & 0xFFFFFFFFull);
        }
        if (l == 0) dst[KNN] = row & (NNODE - 1);
    }
}

// ---------------- per-graph max|x - mean| ----------------
__global__ void init_maxabs(unsigned* maxabs) { if (threadIdx.x < BATCH) maxabs[threadIdx.x] = 0u; }

__global__ __launch_bounds__(256) void maxabs_kernel(const float* __restrict__ x,
                                                     const float* __restrict__ mean,
                                                     unsigned* __restrict__ maxabs) {
    int b = blockIdx.y;
    const float* p = x + ((size_t)b * NNODE + blockIdx.x * 64) * DIM;
    const float* mb = mean + b * DIM;
    float m = 0.f;
    for (int i = threadIdx.x; i < 64 * DIM; i += 256) {
        int d = i & (DIM - 1);
        m = fmaxf(m, fabsf(p[i] - mb[d]));
    }
    __shared__ float red[256];
    red[threadIdx.x] = m; __syncthreads();
    for (int s = 128; s > 0; s >>= 1) {
        if (threadIdx.x < s) red[threadIdx.x] = fmaxf(red[threadIdx.x], red[threadIdx.x + s]);
        __syncthreads();
    }
    if (threadIdx.x == 0) atomicMax(maxabs + b, __float_as_uint(red[0]));
}

// ---------------- h0 = (x - mean) * 0.999999/maxabs -> split bf16 hi/lo ----------------
__global__ void normalize_kernel(const float* __restrict__ x, const float* __restrict__ mean,
                                 const unsigned* __restrict__ maxabs,
                                 unsigned short* __restrict__ h_hi, unsigned short* __restrict__ h_lo) {
    int id = blockIdx.x * 256 + threadIdx.x;
    int b = id >> 19;
    int d = id & (DIM - 1);
    float scale = 0.999999f / __uint_as_float(maxabs[b]);
    float v = (x[id] - mean[b * DIM + d]) * scale;
    split_store(v, h_hi, h_lo, id);
}

// ---------------- W[512x512] -> Wt hi/lo bf16 [n][k] (transpose + split) ----------------
__global__ void wsplit_kernel(const float* __restrict__ W,
                              unsigned short* __restrict__ Wh, unsigned short* __restrict__ Wl) {
    __shared__ float tile[32][33];
    int bx = blockIdx.x * 32, by = blockIdx.y * 32;
    int tx = threadIdx.x & 31, ty = threadIdx.x >> 5;
    #pragma unroll
    for (int i = 0; i < 4; ++i)
        tile[ty + i * 8][tx] = W[(size_t)(by + ty + i * 8) * DIM + bx + tx];
    __syncthreads();
    #pragma unroll
    for (int i = 0; i < 4; ++i) {
        int n = bx + ty + i * 8;
        float v = tile[tx][ty + i * 8];
        split_store(v, Wh, Wl, (size_t)n * DIM + by + tx);
    }
}

// ---------------- C f32 = (Ah+Al) . (Wh+Wl), split-bf16 MFMA ----------------
__global__ __launch_bounds__(256, 2) void gemm_mfma(const unsigned short* __restrict__ Agh,
                                                    const unsigned short* __restrict__ Agl,
                                                    const unsigned short* __restrict__ Bgh,
                                                    const unsigned short* __restrict__ Bgl,
                                                    float* __restrict__ C) {
    __shared__ unsigned short AhL[128][40], AlL[128][40], BhL[128][40], BlL[128][40];
    int m0 = blockIdx.y * BT, n0 = blockIdx.x * BT;
    int t = threadIdx.x;
    int lane = t & 63, w = t >> 6;
    int wm = (w >> 1) * 64, wn = (w & 1) * 64;
    int fr = lane & 15, fk = (lane >> 4) * 8;
    f32x4 acc[4][4];
    #pragma unroll
    for (int i = 0; i < 4; ++i)
        #pragma unroll
        for (int j = 0; j < 4; ++j) acc[i][j] = (f32x4){0.f, 0.f, 0.f, 0.f};

    for (int k0 = 0; k0 < DIM; k0 += 32) {
        if (k0) __syncthreads();
        #pragma unroll
        for (int p = 0; p < 2; ++p) {
            int u = t + p * 256;
            int row = u >> 2, seg = (u & 3) * 8;
            *(uint4*)&AhL[row][seg] = *(const uint4*)(Agh + (size_t)(m0 + row) * DIM + k0 + seg);
            *(uint4*)&AlL[row][seg] = *(const uint4*)(Agl + (size_t)(m0 + row) * DIM + k0 + seg);
            *(uint4*)&BhL[row][seg] = *(const uint4*)(Bgh + (size_t)(n0 + row) * DIM + k0 + seg);
            *(uint4*)&BlL[row][seg] = *(const uint4*)(Bgl + (size_t)(n0 + row) * DIM + k0 + seg);
        }
        __syncthreads();
        bf16x8 ah[4], al[4], bh[4], bl[4];
        #pragma unroll
        for (int i = 0; i < 4; ++i) {
            ah[i] = *(const bf16x8*)&AhL[wm + i * 16 + fr][fk];
            al[i] = *(const bf16x8*)&AlL[wm + i * 16 + fr][fk];
            bh[i] = *(const bf16x8*)&BhL[wn + i * 16 + fr][fk];
            bl[i] = *(const bf16x8*)&BlL[wn + i * 16 + fr][fk];
        }
        #pragma unroll
        for (int i = 0; i < 4; ++i)
            #pragma unroll
            for (int j = 0; j < 4; ++j) {
                acc[i][j] = __builtin_amdgcn_mfma_f32_16x16x32_bf16(ah[i], bh[j], acc[i][j], 0, 0, 0);
                acc[i][j] = __builtin_amdgcn_mfma_f32_16x16x32_bf16(ah[i], bl[j], acc[i][j], 0, 0, 0);
                acc[i][j] = __builtin_amdgcn_mfma_f32_16x16x32_bf16(al[i], bh[j], acc[i][j], 0, 0, 0);
            }
    }
    #pragma unroll
    for (int i = 0; i < 4; ++i) {
        int mrow = m0 + wm + i * 16 + (lane >> 4) * 4;
        #pragma unroll
        for (int j = 0; j < 4; ++j) {
            int col = n0 + wn + j * 16 + fr;
            #pragma unroll
            for (int r = 0; r < 4; ++r)
                C[(size_t)(mrow + r) * DIM + col] = acc[i][j][r];
        }
    }
}

// ---------------- a_s = hp @ asrc, a_d = hp @ adst (float4 loads) ----------------
__global__ void attvec_kernel(const float* __restrict__ hp, const float* __restrict__ asrc,
                              const float* __restrict__ adst, float* __restrict__ as_,
                              float* __restrict__ ad_) {
    int row = blockIdx.x * 4 + (threadIdx.x >> 6);
    int lane = threadIdx.x & 63;
    const float4* p = (const float4*)(hp + (size_t)row * DIM);
    const float4* s4 = (const float4*)asrc;
    const float4* d4 = (const float4*)adst;
    float4 a0 = p[lane], a1 = p[lane + 64];
    float4 u0 = s4[lane], u1 = s4[lane + 64];
    float4 v0 = d4[lane], v1 = d4[lane + 64];
    float s = a0.x * u0.x + a0.y * u0.y + a0.z * u0.z + a0.w * u0.w
            + a1.x * u1.x + a1.y * u1.y + a1.z * u1.z + a1.w * u1.w;
    float d = a0.x * v0.x + a0.y * v0.y + a0.z * v0.z + a0.w * v0.w
            + a1.x * v1.x + a1.y * v1.y + a1.z * v1.z + a1.w * v1.w;
    #pragma unroll
    for (int off = 32; off > 0; off >>= 1) { s += __shfl_down(s, off, 64); d += __shfl_down(d, off, 64); }
    if (lane == 0) { as_[row] = s; ad_[row] = d; }
}

// ---------------- GAT attention + aggregation (parallel softmax, float2 gather) ----------------
template<int RELU, int SPLIT>
__global__ __launch_bounds__(256) void aggr_kernel(const float* __restrict__ hp, const int* __restrict__ nbr,
                                                   const float* __restrict__ as_, const float* __restrict__ ad_,
                                                   const float* __restrict__ bias,
                                                   float* __restrict__ outf,
                                                   unsigned short* __restrict__ oh,
                                                   unsigned short* __restrict__ ol) {
    int id = blockIdx.x;                 // b*N + n
    int b = id >> 10;
    __shared__ float att[KP1];
    __shared__ int   jj[KP1];
    int t = threadIdx.x;
    if (t < 32) {
        float e = -INFINITY;
        int j = 0;
        if (t < KP1) {
            j = nbr[id * KP1 + t];
            jj[t] = j;
            e = as_[b * NNODE + j] + ad_[id];
            e = (e >= 0.f) ? e : NEG * e;
        }
        float mx = e;
        #pragma unroll
        for (int off = 16; off > 0; off >>= 1) mx = fmaxf(mx, __shfl_xor(mx, off, 64));
        float ex = (t < KP1) ? expf(e - mx) : 0.f;
        float sm = ex;
        #pragma unroll
        for (int off = 16; off > 0; off >>= 1) sm += __shfl_xor(sm, off, 64);
        if (t < KP1) att[t] = ex / sm;
    }
    __syncthreads();
    const float* base = hp + (size_t)b * NNODE * DIM;
    int d = t * 2;
    float2 o = *(const float2*)(bias + d);
    #pragma unroll
    for (int k = 0; k < KP1; ++k) {
        float a = att[k];
        float2 v = *(const float2*)(base + (size_t)jj[k] * DIM + d);
        o.x += a * v.x; o.y += a * v.y;
    }
    if (RELU) { o.x = fmaxf(o.x, 0.f); o.y = fmaxf(o.y, 0.f); }
    size_t idx = (size_t)id * DIM + d;
    if (SPLIT) { split_store(o.x, oh, ol, idx); split_store(o.y, oh, ol, idx + 1); }
    else       { *(float2*)(outf + idx) = o; }
}

// ---------------- global max pool, stage 1: partial max over 64-node chunks ----------------
__global__ __launch_bounds__(256) void maxpool_part(const float* __restrict__ h, float* __restrict__ part) {
    int b = blockIdx.x, dc = blockIdx.y, ch = blockIdx.z;
    int d = dc * 256 + threadIdx.x;
    const float* p = h + ((size_t)b * NNODE + ch * (NNODE / NCH)) * DIM + d;
    float m = -INFINITY;
    #pragma unroll 4
    for (int n = 0; n < NNODE / NCH; ++n) m = fmaxf(m, p[(size_t)n * DIM]);
    part[((size_t)b * NCH + ch) * DIM + d] = m;
}
__global__ void maxpool_fin(const float* __restrict__ part, float* __restrict__ g) {
    int id = blockIdx.x * 256 + threadIdx.x;   // b*DIM + d
    int b = id >> 9, d = id & (DIM - 1);
    float m = -INFINITY;
    #pragma unroll
    for (int ch = 0; ch < NCH; ++ch) m = fmaxf(m, part[((size_t)b * NCH + ch) * DIM + d]);
    g[id] = m;
}

// ---------------- final linear g @ Wc + bc ----------------
__global__ void final_kernel(const float* __restrict__ g, const float* __restrict__ Wc,
                             const float* __restrict__ bc, float* __restrict__ out) {
    int b = blockIdx.x, t = threadIdx.x;
    float s0 = 0.f, s1 = 0.f;
    for (int d = t; d < DIM; d += 256) {
        float v = g[b * DIM + d];
        s0 += v * Wc[d * 2 + 0];
        s1 += v * Wc[d * 2 + 1];
    }
    __shared__ float r0[256], r1[256];
    r0[t] = s0; r1[t] = s1; __syncthreads();
    for (int s = 128; s > 0; s >>= 1) {
        if (t < s) { r0[t] += r0[t + s]; r1[t] += r1[t + s]; }
        __syncthreads();
    }
    if (t == 0) { out[b * 2] = r0[0] + bc[0]; out[b * 2 + 1] = r1[0] + bc[1]; }
}

extern "C" void kernel_launch(void* const* d_in, const int* in_sizes, int n_in,
                              void* d_out, int out_size, void* d_ws, size_t ws_size,
                              hipStream_t stream) {
    const float* x     = (const float*)d_in[0];
    const float* W1    = (const float*)d_in[1];
    const float* asrc1 = (const float*)d_in[2];
    const float* adst1 = (const float*)d_in[3];
    const float* b1    = (const float*)d_in[4];
    const float* W2    = (const float*)d_in[5];
    const float* asrc2 = (const float*)d_in[6];
    const float* adst2 = (const float*)d_in[7];
    const float* b2    = (const float*)d_in[8];
    const float* W3    = (const float*)d_in[9];
    const float* asrc3 = (const float*)d_in[10];
    const float* adst3 = (const float*)d_in[11];
    const float* b3    = (const float*)d_in[12];
    const float* Wc    = (const float*)d_in[13];
    const float* bc    = (const float*)d_in[14];
    float* out = (float*)d_out;

    char* ws = (char*)d_ws;
    float*          d2    = (float*)ws;                            // 64MB (graph build only)
    float*          hp    = (float*)ws;                            // 32MB f32
    unsigned short* hA_hi = (unsigned short*)(ws + (32ull << 20)); // 16MB
    unsigned short* hA_lo = (unsigned short*)(ws + (48ull << 20)); // 16MB
    unsigned short* xh    = (unsigned short*)(ws + (64ull << 20)); // 16MB (graph build only)
    unsigned short* hB_hi = (unsigned short*)(ws + (64ull << 20)); // 16MB
    unsigned short* hB_lo = (unsigned short*)(ws + (80ull << 20)); // 16MB
    float*          h3    = (float*)(ws + (64ull << 20));          // 32MB, alias hB
    size_t off = 96ull << 20;
    unsigned short* Wt1h = (unsigned short*)(ws + off); off += (size_t)DIM * DIM * 2;
    unsigned short* Wt1l = (unsigned short*)(ws + off); off += (size_t)DIM * DIM * 2;
    unsigned short* Wt2h = (unsigned short*)(ws + off); off += (size_t)DIM * DIM * 2;
    unsigned short* Wt2l = (unsigned short*)(ws + off); off += (size_t)DIM * DIM * 2;
    unsigned short* Wt3h = (unsigned short*)(ws + off); off += (size_t)DIM * DIM * 2;
    unsigned short* Wt3l = (unsigned short*)(ws + off); off += (size_t)DIM * DIM * 2;
    int*      nbr    = (int*)(ws + off);      off += (size_t)BATCH * NNODE * KP1 * 4;
    int*      cand   = (int*)(ws + off);      off += (size_t)BATCH * NNODE * NCAND * 4;
    float*    sq     = (float*)(ws + off);    off += (size_t)BATCH * NNODE * 4;
    float*    mean   = (float*)(ws + off);    off += (size_t)BATCH * DIM * 4;
    unsigned* maxabs = (unsigned*)(ws + off); off += 256;
    float*    as_    = (float*)(ws + off);    off += (size_t)BATCH * NNODE * 4;
    float*    ad_    = (float*)(ws + off);    off += (size_t)BATCH * NNODE * 4;
    float*    g      = (float*)(ws + off);    off += (size_t)BATCH * DIM * 4;
    float*    part   = (float*)(ws + off);    off += (size_t)BATCH * NCH * DIM * 4;  // 512KB scratch
    (void)ws_size; (void)in_sizes; (void)n_in; (void)out_size;

    const dim3 cgrid(BATCH, DIM / 256, NCH);
    // ---- graph construction: approx bf16 MFMA distances + exact f32 re-rank ----
    colmean_part<<<cgrid, 256, 0, stream>>>(x, part);
    colmean_fin<<<BATCH * DIM / 256, 256, 0, stream>>>(part, mean);
    rowsq_kernel<<<BATCH * NNODE / 4, 256, 0, stream>>>(x, sq);
    xtobf_kernel<<<BATCH * NNODE * DIM / 1024, 256, 0, stream>>>(x, xh);
    dist_mfma<<<dim3(NNODE / BT, BATCH * NNODE / BT), 256, 0, stream>>>(xh, sq, d2);
    knn_kernel<<<BATCH * NNODE / 4, 256, 0, stream>>>(d2, cand);
    rerank_kernel<<<BATCH * NNODE, 256, 0, stream>>>(x, sq, cand, nbr);
    // ---- weights transpose + split ----
    wsplit_kernel<<<dim3(16, 16), 256, 0, stream>>>(W1, Wt1h, Wt1l);
    wsplit_kernel<<<dim3(16, 16), 256, 0, stream>>>(W2, Wt2h, Wt2l);
    wsplit_kernel<<<dim3(16, 16), 256, 0, stream>>>(W3, Wt3h, Wt3l);
    // ---- normalize -> hA (split bf16); d2/xh dead from here ----
    init_maxabs<<<1, 64, 0, stream>>>(maxabs);
    maxabs_kernel<<<dim3(16, BATCH), 256, 0, stream>>>(x, mean, maxabs);
    normalize_kernel<<<BATCH * NNODE * DIM / 256, 256, 0, stream>>>(x, mean, maxabs, hA_hi, hA_lo);

    const dim3 ggrid(DIM / BT, BATCH * NNODE / BT);   // (4, 128)
    // layer 1
    gemm_mfma<<<ggrid, 256, 0, stream>>>(hA_hi, hA_lo, Wt1h, Wt1l, hp);
    attvec_kernel<<<BATCH * NNODE / 4, 256, 0, stream>>>(hp, asrc1, adst1, as_, ad_);
    aggr_kernel<1, 1><<<BATCH * NNODE, 256, 0, stream>>>(hp, nbr, as_, ad_, b1, nullptr, hB_hi, hB_lo);
    // layer 2
    gemm_mfma<<<ggrid, 256, 0, stream>>>(hB_hi, hB_lo, Wt2h, Wt2l, hp);
    attvec_kernel<<<BATCH * NNODE / 4, 256, 0, stream>>>(hp, asrc2, adst2, as_, ad_);
    aggr_kernel<1, 1><<<BATCH * NNODE, 256, 0, stream>>>(hp, nbr, as_, ad_, b2, nullptr, hA_hi, hA_lo);
    // layer 3
    gemm_mfma<<<ggrid, 256, 0, stream>>>(hA_hi, hA_lo, Wt3h, Wt3l, hp);
    attvec_kernel<<<BATCH * NNODE / 4, 256, 0, stream>>>(hp, asrc3, adst3, as_, ad_);
    aggr_kernel<0, 0><<<BATCH * NNODE, 256, 0, stream>>>(hp, nbr, as_, ad_, b3, h3, nullptr, nullptr);
    // pool + classify
    maxpool_part<<<cgrid, 256, 0, stream>>>(h3, part);
    maxpool_fin<<<BATCH * DIM / 256, 256, 0, stream>>>(part, g);
    final_kernel<<<BATCH, 256, 0, stream>>>(g, Wc, bc, out);
}

// Round 8
// 492.788 us; speedup vs baseline: 2.4048x; 1.0239x over previous
//
#include <hip/hip_runtime.h>
#include <hip/hip_bf16.h>
#include <math.h>

#define BATCH 16
#define NNODE 1024
#define DIM   512
#define KNN   16
#define KP1   17
#define NCAND 24
#define NEG   0.2f
#define BT    128   // block tile
#define NCH   16    // n-chunks for column reductions

typedef __attribute__((ext_vector_type(8))) short bf16x8;
typedef __attribute__((ext_vector_type(4))) float f32x4;

__device__ __forceinline__ unsigned short f2bf(float f) {
    unsigned u = __float_as_uint(f);
    unsigned r = (u + 0x7FFFu + ((u >> 16) & 1u)) >> 16;   // RNE
    return (unsigned short)r;
}
__device__ __forceinline__ float bf2f(unsigned short h) {
    return __uint_as_float(((unsigned)h) << 16);
}
__device__ __forceinline__ void split_store(float v, unsigned short* hi, unsigned short* lo, size_t idx) {
    unsigned short h = f2bf(v);
    hi[idx] = h;
    lo[idx] = f2bf(v - bf2f(h));
}

// ---------------- column mean, stage 1: partial sums over 64-node chunks ----------------
__global__ __launch_bounds__(256) void colmean_part(const float* __restrict__ x, float* __restrict__ part) {
    int b = blockIdx.x, dc = blockIdx.y, ch = blockIdx.z;
    int d = dc * 256 + threadIdx.x;
    const float* p = x + ((size_t)b * NNODE + ch * (NNODE / NCH)) * DIM + d;
    float s = 0.f;
    #pragma unroll 4
    for (int n = 0; n < NNODE / NCH; ++n) s += p[(size_t)n * DIM];
    part[((size_t)b * NCH + ch) * DIM + d] = s;
}
__global__ void colmean_fin(const float* __restrict__ part, float* __restrict__ mean) {
    int id = blockIdx.x * 256 + threadIdx.x;   // b*DIM + d
    int b = id >> 9, d = id & (DIM - 1);
    float s = 0.f;
    #pragma unroll
    for (int ch = 0; ch < NCH; ++ch) s += part[((size_t)b * NCH + ch) * DIM + d];
    mean[id] = s * (1.0f / NNODE);
}

// ---------------- row squared norms of raw pos ----------------
__global__ void rowsq_kernel(const float* __restrict__ x, float* __restrict__ sq) {
    int row = blockIdx.x * 4 + (threadIdx.x >> 6);
    int lane = threadIdx.x & 63;
    const float* p = x + (size_t)row * DIM;
    float s = 0.f;
    for (int i = lane; i < DIM; i += 64) { float v = p[i]; s += v * v; }
    #pragma unroll
    for (int off = 32; off > 0; off >>= 1) s += __shfl_down(s, off, 64);
    if (lane == 0) sq[row] = s;
}

// ---------------- x -> bf16 (for approximate candidate distances) ----------------
__global__ void xtobf_kernel(const float* __restrict__ x, unsigned short* __restrict__ xh) {
    int id = blockIdx.x * 256 + threadIdx.x;
    float4 v = *(const float4*)(x + (size_t)id * 4);
    ushort4 o;
    o.x = f2bf(v.x); o.y = f2bf(v.y); o.z = f2bf(v.z); o.w = f2bf(v.w);
    *(ushort4*)(xh + (size_t)id * 4) = o;
}

// ---------------- approx distance matrix via bf16 MFMA (candidate stage) ----------------
__global__ __launch_bounds__(256, 2) void dist_mfma(const unsigned short* __restrict__ xh,
                                                    const float* __restrict__ sq,
                                                    float* __restrict__ d2) {
    __shared__ unsigned short AhL[128][40], BhL[128][40];
    int mt = blockIdx.y;
    int b = mt >> 3;
    int m0 = mt * BT;
    int n0 = blockIdx.x * BT;
    int bn0 = b * NNODE + n0;
    int t = threadIdx.x;
    int lane = t & 63, w = t >> 6;
    int wm = (w >> 1) * 64, wn = (w & 1) * 64;
    int fr = lane & 15, fk = (lane >> 4) * 8;
    f32x4 acc[4][4];
    #pragma unroll
    for (int i = 0; i < 4; ++i)
        #pragma unroll
        for (int j = 0; j < 4; ++j) acc[i][j] = (f32x4){0.f, 0.f, 0.f, 0.f};

    for (int k0 = 0; k0 < DIM; k0 += 32) {
        if (k0) __syncthreads();
        #pragma unroll
        for (int p = 0; p < 2; ++p) {
            int u = t + p * 256;
            int row = u >> 2, seg = (u & 3) * 8;
            *(uint4*)&AhL[row][seg] = *(const uint4*)(xh + (size_t)(m0 + row) * DIM + k0 + seg);
            *(uint4*)&BhL[row][seg] = *(const uint4*)(xh + (size_t)(bn0 + row) * DIM + k0 + seg);
        }
        __syncthreads();
        bf16x8 ah[4], bh[4];
        #pragma unroll
        for (int i = 0; i < 4; ++i) {
            ah[i] = *(const bf16x8*)&AhL[wm + i * 16 + fr][fk];
            bh[i] = *(const bf16x8*)&BhL[wn + i * 16 + fr][fk];
        }
        #pragma unroll
        for (int i = 0; i < 4; ++i)
            #pragma unroll
            for (int j = 0; j < 4; ++j)
                acc[i][j] = __builtin_amdgcn_mfma_f32_16x16x32_bf16(ah[i], bh[j], acc[i][j], 0, 0, 0);
    }
    const float* sqb = sq + b * NNODE;
    int mloc0 = m0 - b * NNODE;
    #pragma unroll
    for (int i = 0; i < 4; ++i) {
        int mloc = mloc0 + wm + i * 16 + (lane >> 4) * 4;
        #pragma unroll
        for (int j = 0; j < 4; ++j) {
            int n = n0 + wn + j * 16 + fr;
            float sqn = sqb[n];
            #pragma unroll
            for (int r = 0; r < 4; ++r) {
                float val = sqb[mloc + r] + sqn - 2.f * acc[i][j][r];
                if (mloc + r == n) val = INFINITY;
                d2[((size_t)b * NNODE + mloc + r) * NNODE + n] = val;
            }
        }
    }
}

// ---------------- top-24 smallest per row (approx): u32 keys + threshold walk ----------------
__global__ __launch_bounds__(256) void knn_kernel(const float* __restrict__ d2, int* __restrict__ cand) {
    int row = blockIdx.x * 4 + (threadIdx.x >> 6);   // b*N + n
    int l = threadIdx.x & 63;
    const float* src = d2 + (size_t)row * NNODE;
    unsigned key[16];
    #pragma unroll
    for (int j = 0; j < 16; ++j) {
        unsigned v = __float_as_uint(src[l + (j << 6)]);
        key[j] = (v & 0xFFFFFC00u) | (unsigned)(l + (j << 6));
    }
    int* dst = cand + row * NCAND;
    unsigned T = 0;
    for (int it = 0; it < NCAND; ++it) {
        unsigned lmin = 0xFFFFFFFFu;
        #pragma unroll
        for (int j = 0; j < 16; ++j) {
            unsigned k = (key[j] > T) ? key[j] : 0xFFFFFFFFu;
            lmin = min(lmin, k);
        }
        #pragma unroll
        for (int off = 1; off < 64; off <<= 1) {
            unsigned o = (unsigned)__shfl_xor((int)lmin, off, 64);
            lmin = min(lmin, o);
        }
        T = lmin;
        if (l == 0) dst[it] = (int)(lmin & 1023u);
    }
}

// ---------------- exact f32 re-rank of candidates -> nbr[17] ----------------
// XCD-swizzled: b = bid%16 so XCD (bid%8) serves graphs {b, b+8} = 4MB of x = one L2.
// Per wave: all 6 index loads, then all 12 gather loads issued before any reduction (ILP).
__global__ __launch_bounds__(256) void rerank_kernel(const float* __restrict__ x,
                                                     const float* __restrict__ sq,
                                                     const int* __restrict__ cand,
                                                     int* __restrict__ nbr) {
    int bid = blockIdx.x;
    int b = bid & (BATCH - 1);
    int m = bid >> 4;
    int row = b * NNODE + m;
    int w = threadIdx.x >> 6, l = threadIdx.x & 63;
    const float* xm = x + (size_t)row * DIM;
    float4 m0v = *(const float4*)(xm + l * 8);
    float4 m1v = *(const float4*)(xm + l * 8 + 4);
    __shared__ float dval[NCAND];
    __shared__ int   didx[NCAND];
    const float* xb = x + (size_t)b * NNODE * DIM;
    const float* sqb = sq + b * NNODE;
    float sqm = sq[row];

    int idx[6];
    #pragma unroll
    for (int i = 0; i < 6; ++i) idx[i] = cand[row * NCAND + w * 6 + i];
    float4 j0[6], j1[6];
    #pragma unroll
    for (int i = 0; i < 6; ++i) {
        const float* xj = xb + (size_t)idx[i] * DIM;
        j0[i] = *(const float4*)(xj + l * 8);
        j1[i] = *(const float4*)(xj + l * 8 + 4);
    }
    float s[6];
    #pragma unroll
    for (int i = 0; i < 6; ++i)
        s[i] = m0v.x * j0[i].x + m0v.y * j0[i].y + m0v.z * j0[i].z + m0v.w * j0[i].w
             + m1v.x * j1[i].x + m1v.y * j1[i].y + m1v.z * j1[i].z + m1v.w * j1[i].w;
    #pragma unroll
    for (int off = 32; off > 0; off >>= 1)
        #pragma unroll
        for (int i = 0; i < 6; ++i) s[i] += __shfl_down(s[i], off, 64);
    if (l == 0) {
        #pragma unroll
        for (int i = 0; i < 6; ++i) {
            dval[w * 6 + i] = sqm + sqb[idx[i]] - 2.f * s[i];
            didx[w * 6 + i] = idx[i];
        }
    }
    __syncthreads();
    if (w == 0) {
        unsigned long long mykey = ~0ull;
        if (l < NCAND)
            mykey = ((unsigned long long)__float_as_uint(dval[l]) << 32) | (unsigned)didx[l];
        int* dst = nbr + row * KP1;
        for (int it = 0; it < KNN; ++it) {
            unsigned long long kmin = mykey;
            #pragma unroll
            for (int off = 1; off < 32; off <<= 1) {
                unsigned long long o = __shfl_xor(kmin, off, 64);
                if (o < kmin) kmin = o;
            }
            if (mykey == kmin && mykey != ~0ull) mykey = ~0ull;
            if (l == 0) dst[it] = (int)(kmin & 0xFFFFFFFFull);
        }
        if (l == 0) dst[KNN] = m;
    }
}

// ---------------- per-graph max|x - mean| ----------------
__global__ void init_maxabs(unsigned* maxabs) { if (threadIdx.x < BATCH) maxabs[threadIdx.x] = 0u; }

__global__ __launch_bounds__(256) void maxabs_kernel(const float* __restrict__ x,
                                                     const float* __restrict__ mean,
                                                     unsigned* __restrict__ maxabs) {
    int b = blockIdx.y;
    const float* p = x + ((size_t)b * NNODE + blockIdx.x * 64) * DIM;
    const float* mb = mean + b * DIM;
    float m = 0.f;
    for (int i = threadIdx.x; i < 64 * DIM; i += 256) {
        int d = i & (DIM - 1);
        m = fmaxf(m, fabsf(p[i] - mb[d]));
    }
    __shared__ float red[256];
    red[threadIdx.x] = m; __syncthreads();
    for (int s = 128; s > 0; s >>= 1) {
        if (threadIdx.x < s) red[threadIdx.x] = fmaxf(red[threadIdx.x], red[threadIdx.x + s]);
        __syncthreads();
    }
    if (threadIdx.x == 0) atomicMax(maxabs + b, __float_as_uint(red[0]));
}

// ---------------- h0 = (x - mean) * 0.999999/maxabs -> split bf16 hi/lo ----------------
__global__ void normalize_kernel(const float* __restrict__ x, const float* __restrict__ mean,
                                 const unsigned* __restrict__ maxabs,
                                 unsigned short* __restrict__ h_hi, unsigned short* __restrict__ h_lo) {
    int id = blockIdx.x * 256 + threadIdx.x;
    int b = id >> 19;
    int d = id & (DIM - 1);
    float scale = 0.999999f / __uint_as_float(maxabs[b]);
    float v = (x[id] - mean[b * DIM + d]) * scale;
    split_store(v, h_hi, h_lo, id);
}

// ---------------- W[512x512] -> Wt hi/lo bf16 [n][k] (transpose + split) ----------------
__global__ void wsplit_kernel(const float* __restrict__ W,
                              unsigned short* __restrict__ Wh, unsigned short* __restrict__ Wl) {
    __shared__ float tile[32][33];
    int bx = blockIdx.x * 32, by = blockIdx.y * 32;
    int tx = threadIdx.x & 31, ty = threadIdx.x >> 5;
    #pragma unroll
    for (int i = 0; i < 4; ++i)
        tile[ty + i * 8][tx] = W[(size_t)(by + ty + i * 8) * DIM + bx + tx];
    __syncthreads();
    #pragma unroll
    for (int i = 0; i < 4; ++i) {
        int n = bx + ty + i * 8;
        float v = tile[tx][ty + i * 8];
        split_store(v, Wh, Wl, (size_t)n * DIM + by + tx);
    }
}

// ---------------- C f32 = (Ah+Al) . (Wh+Wl), split-bf16 MFMA ----------------
__global__ __launch_bounds__(256, 2) void gemm_mfma(const unsigned short* __restrict__ Agh,
                                                    const unsigned short* __restrict__ Agl,
                                                    const unsigned short* __restrict__ Bgh,
                                                    const unsigned short* __restrict__ Bgl,
                                                    float* __restrict__ C) {
    __shared__ unsigned short AhL[128][40], AlL[128][40], BhL[128][40], BlL[128][40];
    int m0 = blockIdx.y * BT, n0 = blockIdx.x * BT;
    int t = threadIdx.x;
    int lane = t & 63, w = t >> 6;
    int wm = (w >> 1) * 64, wn = (w & 1) * 64;
    int fr = lane & 15, fk = (lane >> 4) * 8;
    f32x4 acc[4][4];
    #pragma unroll
    for (int i = 0; i < 4; ++i)
        #pragma unroll
        for (int j = 0; j < 4; ++j) acc[i][j] = (f32x4){0.f, 0.f, 0.f, 0.f};

    for (int k0 = 0; k0 < DIM; k0 += 32) {
        if (k0) __syncthreads();
        #pragma unroll
        for (int p = 0; p < 2; ++p) {
            int u = t + p * 256;
            int row = u >> 2, seg = (u & 3) * 8;
            *(uint4*)&AhL[row][seg] = *(const uint4*)(Agh + (size_t)(m0 + row) * DIM + k0 + seg);
            *(uint4*)&AlL[row][seg] = *(const uint4*)(Agl + (size_t)(m0 + row) * DIM + k0 + seg);
            *(uint4*)&BhL[row][seg] = *(const uint4*)(Bgh + (size_t)(n0 + row) * DIM + k0 + seg);
            *(uint4*)&BlL[row][seg] = *(const uint4*)(Bgl + (size_t)(n0 + row) * DIM + k0 + seg);
        }
        __syncthreads();
        bf16x8 ah[4], al[4], bh[4], bl[4];
        #pragma unroll
        for (int i = 0; i < 4; ++i) {
            ah[i] = *(const bf16x8*)&AhL[wm + i * 16 + fr][fk];
            al[i] = *(const bf16x8*)&AlL[wm + i * 16 + fr][fk];
            bh[i] = *(const bf16x8*)&BhL[wn + i * 16 + fr][fk];
            bl[i] = *(const bf16x8*)&BlL[wn + i * 16 + fr][fk];
        }
        #pragma unroll
        for (int i = 0; i < 4; ++i)
            #pragma unroll
            for (int j = 0; j < 4; ++j) {
                acc[i][j] = __builtin_amdgcn_mfma_f32_16x16x32_bf16(ah[i], bh[j], acc[i][j], 0, 0, 0);
                acc[i][j] = __builtin_amdgcn_mfma_f32_16x16x32_bf16(ah[i], bl[j], acc[i][j], 0, 0, 0);
                acc[i][j] = __builtin_amdgcn_mfma_f32_16x16x32_bf16(al[i], bh[j], acc[i][j], 0, 0, 0);
            }
    }
    #pragma unroll
    for (int i = 0; i < 4; ++i) {
        int mrow = m0 + wm + i * 16 + (lane >> 4) * 4;
        #pragma unroll
        for (int j = 0; j < 4; ++j) {
            int col = n0 + wn + j * 16 + fr;
            #pragma unroll
            for (int r = 0; r < 4; ++r)
                C[(size_t)(mrow + r) * DIM + col] = acc[i][j][r];
        }
    }
}

// ---------------- a_s = hp @ asrc, a_d = hp @ adst (float4 loads) ----------------
__global__ void attvec_kernel(const float* __restrict__ hp, const float* __restrict__ asrc,
                              const float* __restrict__ adst, float* __restrict__ as_,
                              float* __restrict__ ad_) {
    int row = blockIdx.x * 4 + (threadIdx.x >> 6);
    int lane = threadIdx.x & 63;
    const float4* p = (const float4*)(hp + (size_t)row * DIM);
    const float4* s4 = (const float4*)asrc;
    const float4* d4 = (const float4*)adst;
    float4 a0 = p[lane], a1 = p[lane + 64];
    float4 u0 = s4[lane], u1 = s4[lane + 64];
    float4 v0 = d4[lane], v1 = d4[lane + 64];
    float s = a0.x * u0.x + a0.y * u0.y + a0.z * u0.z + a0.w * u0.w
            + a1.x * u1.x + a1.y * u1.y + a1.z * u1.z + a1.w * u1.w;
    float d = a0.x * v0.x + a0.y * v0.y + a0.z * v0.z + a0.w * v0.w
            + a1.x * v1.x + a1.y * v1.y + a1.z * v1.z + a1.w * v1.w;
    #pragma unroll
    for (int off = 32; off > 0; off >>= 1) { s += __shfl_down(s, off, 64); d += __shfl_down(d, off, 64); }
    if (lane == 0) { as_[row] = s; ad_[row] = d; }
}

// ---------------- GAT attention + aggregation (XCD-swizzled, parallel softmax) ----------------
template<int RELU, int SPLIT>
__global__ __launch_bounds__(256) void aggr_kernel(const float* __restrict__ hp, const int* __restrict__ nbr,
                                                   const float* __restrict__ as_, const float* __restrict__ ad_,
                                                   const float* __restrict__ bias,
                                                   float* __restrict__ outf,
                                                   unsigned short* __restrict__ oh,
                                                   unsigned short* __restrict__ ol) {
    int bid = blockIdx.x;
    int b = bid & (BATCH - 1);
    int id = b * NNODE + (bid >> 4);     // XCD bid%8 serves graphs {b, b+8}
    __shared__ float att[KP1];
    __shared__ int   jj[KP1];
    int t = threadIdx.x;
    if (t < 32) {
        float e = -INFINITY;
        int j = 0;
        if (t < KP1) {
            j = nbr[id * KP1 + t];
            jj[t] = j;
            e = as_[b * NNODE + j] + ad_[id];
            e = (e >= 0.f) ? e : NEG * e;
        }
        float mx = e;
        #pragma unroll
        for (int off = 16; off > 0; off >>= 1) mx = fmaxf(mx, __shfl_xor(mx, off, 64));
        float ex = (t < KP1) ? expf(e - mx) : 0.f;
        float sm = ex;
        #pragma unroll
        for (int off = 16; off > 0; off >>= 1) sm += __shfl_xor(sm, off, 64);
        if (t < KP1) att[t] = ex / sm;
    }
    __syncthreads();
    const float* base = hp + (size_t)b * NNODE * DIM;
    int d = t * 2;
    float2 o = *(const float2*)(bias + d);
    #pragma unroll
    for (int k = 0; k < KP1; ++k) {
        float a = att[k];
        float2 v = *(const float2*)(base + (size_t)jj[k] * DIM + d);
        o.x += a * v.x; o.y += a * v.y;
    }
    if (RELU) { o.x = fmaxf(o.x, 0.f); o.y = fmaxf(o.y, 0.f); }
    size_t idx = (size_t)id * DIM + d;
    if (SPLIT) { split_store(o.x, oh, ol, idx); split_store(o.y, oh, ol, idx + 1); }
    else       { *(float2*)(outf + idx) = o; }
}

// ---------------- global max pool, stage 1: partial max over 64-node chunks ----------------
__global__ __launch_bounds__(256) void maxpool_part(const float* __restrict__ h, float* __restrict__ part) {
    int b = blockIdx.x, dc = blockIdx.y, ch = blockIdx.z;
    int d = dc * 256 + threadIdx.x;
    const float* p = h + ((size_t)b * NNODE + ch * (NNODE / NCH)) * DIM + d;
    float m = -INFINITY;
    #pragma unroll 4
    for (int n = 0; n < NNODE / NCH; ++n) m = fmaxf(m, p[(size_t)n * DIM]);
    part[((size_t)b * NCH + ch) * DIM + d] = m;
}
__global__ void maxpool_fin(const float* __restrict__ part, float* __restrict__ g) {
    int id = blockIdx.x * 256 + threadIdx.x;   // b*DIM + d
    int b = id >> 9, d = id & (DIM - 1);
    float m = -INFINITY;
    #pragma unroll
    for (int ch = 0; ch < NCH; ++ch) m = fmaxf(m, part[((size_t)b * NCH + ch) * DIM + d]);
    g[id] = m;
}

// ---------------- final linear g @ Wc + bc ----------------
__global__ void final_kernel(const float* __restrict__ g, const float* __restrict__ Wc,
                             const float* __restrict__ bc, float* __restrict__ out) {
    int b = blockIdx.x, t = threadIdx.x;
    float s0 = 0.f, s1 = 0.f;
    for (int d = t; d < DIM; d += 256) {
        float v = g[b * DIM + d];
        s0 += v * Wc[d * 2 + 0];
        s1 += v * Wc[d * 2 + 1];
    }
    __shared__ float r0[256], r1[256];
    r0[t] = s0; r1[t] = s1; __syncthreads();
    for (int s = 128; s > 0; s >>= 1) {
        if (t < s) { r0[t] += r0[t + s]; r1[t] += r1[t + s]; }
        __syncthreads();
    }
    if (t == 0) { out[b * 2] = r0[0] + bc[0]; out[b * 2 + 1] = r1[0] + bc[1]; }
}

extern "C" void kernel_launch(void* const* d_in, const int* in_sizes, int n_in,
                              void* d_out, int out_size, void* d_ws, size_t ws_size,
                              hipStream_t stream) {
    const float* x     = (const float*)d_in[0];
    const float* W1    = (const float*)d_in[1];
    const float* asrc1 = (const float*)d_in[2];
    const float* adst1 = (const float*)d_in[3];
    const float* b1    = (const float*)d_in[4];
    const float* W2    = (const float*)d_in[5];
    const float* asrc2 = (const float*)d_in[6];
    const float* adst2 = (const float*)d_in[7];
    const float* b2    = (const float*)d_in[8];
    const float* W3    = (const float*)d_in[9];
    const float* asrc3 = (const float*)d_in[10];
    const float* adst3 = (const float*)d_in[11];
    const float* b3    = (const float*)d_in[12];
    const float* Wc    = (const float*)d_in[13];
    const float* bc    = (const float*)d_in[14];
    float* out = (float*)d_out;

    char* ws = (char*)d_ws;
    float*          d2    = (float*)ws;                            // 64MB (graph build only)
    float*          hp    = (float*)ws;                            // 32MB f32
    unsigned short* hA_hi = (unsigned short*)(ws + (32ull << 20)); // 16MB
    unsigned short* hA_lo = (unsigned short*)(ws + (48ull << 20)); // 16MB
    unsigned short* xh    = (unsigned short*)(ws + (64ull << 20)); // 16MB (graph build only)
    unsigned short* hB_hi = (unsigned short*)(ws + (64ull << 20)); // 16MB
    unsigned short* hB_lo = (unsigned short*)(ws + (80ull << 20)); // 16MB
    float*          h3    = (float*)(ws + (64ull << 20));          // 32MB, alias hB
    size_t off = 96ull << 20;
    unsigned short* Wt1h = (unsigned short*)(ws + off); off += (size_t)DIM * DIM * 2;
    unsigned short* Wt1l = (unsigned short*)(ws + off); off += (size_t)DIM * DIM * 2;
    unsigned short* Wt2h = (unsigned short*)(ws + off); off += (size_t)DIM * DIM * 2;
    unsigned short* Wt2l = (unsigned short*)(ws + off); off += (size_t)DIM * DIM * 2;
    unsigned short* Wt3h = (unsigned short*)(ws + off); off += (size_t)DIM * DIM * 2;
    unsigned short* Wt3l = (unsigned short*)(ws + off); off += (size_t)DIM * DIM * 2;
    int*      nbr    = (int*)(ws + off);      off += (size_t)BATCH * NNODE * KP1 * 4;
    int*      cand   = (int*)(ws + off);      off += (size_t)BATCH * NNODE * NCAND * 4;
    float*    sq     = (float*)(ws + off);    off += (size_t)BATCH * NNODE * 4;
    float*    mean   = (float*)(ws + off);    off += (size_t)BATCH * DIM * 4;
    unsigned* maxabs = (unsigned*)(ws + off); off += 256;
    float*    as_    = (float*)(ws + off);    off += (size_t)BATCH * NNODE * 4;
    float*    ad_    = (float*)(ws + off);    off += (size_t)BATCH * NNODE * 4;
    float*    g      = (float*)(ws + off);    off += (size_t)BATCH * DIM * 4;
    float*    part   = (float*)(ws + off);    off += (size_t)BATCH * NCH * DIM * 4;  // 512KB scratch
    (void)ws_size; (void)in_sizes; (void)n_in; (void)out_size;

    const dim3 cgrid(BATCH, DIM / 256, NCH);
    // ---- graph construction: approx bf16 MFMA distances + exact f32 re-rank ----
    colmean_part<<<cgrid, 256, 0, stream>>>(x, part);
    colmean_fin<<<BATCH * DIM / 256, 256, 0, stream>>>(part, mean);
    rowsq_kernel<<<BATCH * NNODE / 4, 256, 0, stream>>>(x, sq);
    xtobf_kernel<<<BATCH * NNODE * DIM / 1024, 256, 0, stream>>>(x, xh);
    dist_mfma<<<dim3(NNODE / BT, BATCH * NNODE / BT), 256, 0, stream>>>(xh, sq, d2);
    knn_kernel<<<BATCH * NNODE / 4, 256, 0, stream>>>(d2, cand);
    rerank_kernel<<<BATCH * NNODE, 256, 0, stream>>>(x, sq, cand, nbr);
    // ---- weights transpose + split ----
    wsplit_kernel<<<dim3(16, 16), 256, 0, stream>>>(W1, Wt1h, Wt1l);
    wsplit_kernel<<<dim3(16, 16), 256, 0, stream>>>(W2, Wt2h, Wt2l);
    wsplit_kernel<<<dim3(16, 16), 256, 0, stream>>>(W3, Wt3h, Wt3l);
    // ---- normalize -> hA (split bf16); d2/xh dead from here ----
    init_maxabs<<<1, 64, 0, stream>>>(maxabs);
    maxabs_kernel<<<dim3(16, BATCH), 256, 0, stream>>>(x, mean, maxabs);
    normalize_kernel<<<BATCH * NNODE * DIM / 256, 256, 0, stream>>>(x, mean, maxabs, hA_hi, hA_lo);

    const dim3 ggrid(DIM / BT, BATCH * NNODE / BT);   // (4, 128)
    // layer 1
    gemm_mfma<<<ggrid, 256, 0, stream>>>(hA_hi, hA_lo, Wt1h, Wt1l, hp);
    attvec_kernel<<<BATCH * NNODE / 4, 256, 0, stream>>>(hp, asrc1, adst1, as_, ad_);
    aggr_kernel<1, 1><<<BATCH * NNODE, 256, 0, stream>>>(hp, nbr, as_, ad_, b1, nullptr, hB_hi, hB_lo);
    // layer 2
    gemm_mfma<<<ggrid, 256, 0, stream>>>(hB_hi, hB_lo, Wt2h, Wt2l, hp);
    attvec_kernel<<<BATCH * NNODE / 4, 256, 0, stream>>>(hp, asrc2, adst2, as_, ad_);
    aggr_kernel<1, 1><<<BATCH * NNODE, 256, 0, stream>>>(hp, nbr, as_, ad_, b2, nullptr, hA_hi, hA_lo);
    // layer 3
    gemm_mfma<<<ggrid, 256, 0, stream>>>(hA_hi, hA_lo, Wt3h, Wt3l, hp);
    attvec_kernel<<<BATCH * NNODE / 4, 256, 0, stream>>>(hp, asrc3, adst3, as_, ad_);
    aggr_kernel<0, 0><<<BATCH * NNODE, 256, 0, stream>>>(hp, nbr, as_, ad_, b3, h3, nullptr, nullptr);
    // pool + classify
    maxpool_part<<<cgrid, 256, 0, stream>>>(h3, part);
    maxpool_fin<<<BATCH * DIM / 256, 256, 0, stream>>>(part, g);
    final_kernel<<<BATCH, 256, 0, stream>>>(g, Wc, bc, out);
}

// Round 9
// 456.571 us; speedup vs baseline: 2.5956x; 1.0793x over previous
//
#include <hip/hip_runtime.h>
#include <hip/hip_bf16.h>
#include <math.h>

#define BATCH 16
#define NNODE 1024
#define DIM   512
#define KNN   16
#define KP1   17
#define NCAND 20
#define NEG   0.2f
#define BT    128   // block tile
#define NCH   16    // n-chunks for column reductions

typedef __attribute__((ext_vector_type(8))) short bf16x8;
typedef __attribute__((ext_vector_type(4))) float f32x4;

__device__ __forceinline__ unsigned short f2bf(float f) {
    unsigned u = __float_as_uint(f);
    unsigned r = (u + 0x7FFFu + ((u >> 16) & 1u)) >> 16;   // RNE
    return (unsigned short)r;
}
__device__ __forceinline__ float bf2f(unsigned short h) {
    return __uint_as_float(((unsigned)h) << 16);
}
__device__ __forceinline__ void split_store(float v, unsigned short* hi, unsigned short* lo, size_t idx) {
    unsigned short h = f2bf(v);
    hi[idx] = h;
    lo[idx] = f2bf(v - bf2f(h));
}

// ---------------- column mean, stage 1: partial sums over 64-node chunks ----------------
__global__ __launch_bounds__(256) void colmean_part(const float* __restrict__ x, float* __restrict__ part) {
    int b = blockIdx.x, dc = blockIdx.y, ch = blockIdx.z;
    int d = dc * 256 + threadIdx.x;
    const float* p = x + ((size_t)b * NNODE + ch * (NNODE / NCH)) * DIM + d;
    float s = 0.f;
    #pragma unroll 4
    for (int n = 0; n < NNODE / NCH; ++n) s += p[(size_t)n * DIM];
    part[((size_t)b * NCH + ch) * DIM + d] = s;
}
__global__ void colmean_fin(const float* __restrict__ part, float* __restrict__ mean) {
    int id = blockIdx.x * 256 + threadIdx.x;   // b*DIM + d
    int b = id >> 9, d = id & (DIM - 1);
    float s = 0.f;
    #pragma unroll
    for (int ch = 0; ch < NCH; ++ch) s += part[((size_t)b * NCH + ch) * DIM + d];
    mean[id] = s * (1.0f / NNODE);
}

// ---------------- row squared norms of raw pos ----------------
__global__ void rowsq_kernel(const float* __restrict__ x, float* __restrict__ sq) {
    int row = blockIdx.x * 4 + (threadIdx.x >> 6);
    int lane = threadIdx.x & 63;
    const float* p = x + (size_t)row * DIM;
    float s = 0.f;
    for (int i = lane; i < DIM; i += 64) { float v = p[i]; s += v * v; }
    #pragma unroll
    for (int off = 32; off > 0; off >>= 1) s += __shfl_down(s, off, 64);
    if (lane == 0) sq[row] = s;
}

// ---------------- x -> bf16 (for approximate candidate distances) ----------------
__global__ void xtobf_kernel(const float* __restrict__ x, unsigned short* __restrict__ xh) {
    int id = blockIdx.x * 256 + threadIdx.x;
    float4 v = *(const float4*)(x + (size_t)id * 4);
    ushort4 o;
    o.x = f2bf(v.x); o.y = f2bf(v.y); o.z = f2bf(v.z); o.w = f2bf(v.w);
    *(ushort4*)(xh + (size_t)id * 4) = o;
}

// ---------------- approx distance matrix via bf16 MFMA (candidate stage) ----------------
__global__ __launch_bounds__(256, 2) void dist_mfma(const unsigned short* __restrict__ xh,
                                                    const float* __restrict__ sq,
                                                    float* __restrict__ d2) {
    __shared__ unsigned short AhL[128][40], BhL[128][40];
    int mt = blockIdx.y;
    int b = mt >> 3;
    int m0 = mt * BT;
    int n0 = blockIdx.x * BT;
    int bn0 = b * NNODE + n0;
    int t = threadIdx.x;
    int lane = t & 63, w = t >> 6;
    int wm = (w >> 1) * 64, wn = (w & 1) * 64;
    int fr = lane & 15, fk = (lane >> 4) * 8;
    f32x4 acc[4][4];
    #pragma unroll
    for (int i = 0; i < 4; ++i)
        #pragma unroll
        for (int j = 0; j < 4; ++j) acc[i][j] = (f32x4){0.f, 0.f, 0.f, 0.f};

    for (int k0 = 0; k0 < DIM; k0 += 32) {
        if (k0) __syncthreads();
        #pragma unroll
        for (int p = 0; p < 2; ++p) {
            int u = t + p * 256;
            int row = u >> 2, seg = (u & 3) * 8;
            *(uint4*)&AhL[row][seg] = *(const uint4*)(xh + (size_t)(m0 + row) * DIM + k0 + seg);
            *(uint4*)&BhL[row][seg] = *(const uint4*)(xh + (size_t)(bn0 + row) * DIM + k0 + seg);
        }
        __syncthreads();
        bf16x8 ah[4], bh[4];
        #pragma unroll
        for (int i = 0; i < 4; ++i) {
            ah[i] = *(const bf16x8*)&AhL[wm + i * 16 + fr][fk];
            bh[i] = *(const bf16x8*)&BhL[wn + i * 16 + fr][fk];
        }
        #pragma unroll
        for (int i = 0; i < 4; ++i)
            #pragma unroll
            for (int j = 0; j < 4; ++j)
                acc[i][j] = __builtin_amdgcn_mfma_f32_16x16x32_bf16(ah[i], bh[j], acc[i][j], 0, 0, 0);
    }
    const float* sqb = sq + b * NNODE;
    int mloc0 = m0 - b * NNODE;
    #pragma unroll
    for (int i = 0; i < 4; ++i) {
        int mloc = mloc0 + wm + i * 16 + (lane >> 4) * 4;
        #pragma unroll
        for (int j = 0; j < 4; ++j) {
            int n = n0 + wn + j * 16 + fr;
            float sqn = sqb[n];
            #pragma unroll
            for (int r = 0; r < 4; ++r) {
                float val = sqb[mloc + r] + sqn - 2.f * acc[i][j][r];
                if (mloc + r == n) val = INFINITY;
                d2[((size_t)b * NNODE + mloc + r) * NNODE + n] = val;
            }
        }
    }
}

// ---------------- top-20 smallest per row (approx): u32 keys + threshold walk ----------------
__global__ __launch_bounds__(256) void knn_kernel(const float* __restrict__ d2, int* __restrict__ cand) {
    int row = blockIdx.x * 4 + (threadIdx.x >> 6);   // b*N + n
    int l = threadIdx.x & 63;
    const float* src = d2 + (size_t)row * NNODE;
    unsigned key[16];
    #pragma unroll
    for (int j = 0; j < 16; ++j) {
        unsigned v = __float_as_uint(src[l + (j << 6)]);
        key[j] = (v & 0xFFFFFC00u) | (unsigned)(l + (j << 6));
    }
    int* dst = cand + row * NCAND;
    unsigned T = 0;
    for (int it = 0; it < NCAND; ++it) {
        unsigned lmin = 0xFFFFFFFFu;
        #pragma unroll
        for (int j = 0; j < 16; ++j) {
            unsigned k = (key[j] > T) ? key[j] : 0xFFFFFFFFu;
            lmin = min(lmin, k);
        }
        #pragma unroll
        for (int off = 1; off < 64; off <<= 1) {
            unsigned o = (unsigned)__shfl_xor((int)lmin, off, 64);
            lmin = min(lmin, o);
        }
        T = lmin;
        if (l == 0) dst[it] = (int)(lmin & 1023u);
    }
}

// ---------------- exact f32 re-rank: one wave per row, in-register rank selection ----------------
// XCD-swizzled (b = bid%16). All 20 candidate dots in one wave; shfl_xor leaves every lane
// with all 20 sums; lane l owns candidate l via static cndmask chain; rank = #{key < mine}.
__global__ __launch_bounds__(256) void rerank_kernel(const float* __restrict__ x,
                                                     const float* __restrict__ sq,
                                                     const int* __restrict__ cand,
                                                     int* __restrict__ nbr) {
    int bid = blockIdx.x;                 // 4096 blocks
    int b = bid & (BATCH - 1);
    int w = threadIdx.x >> 6, l = threadIdx.x & 63;
    int m = (bid >> 4) * 4 + w;
    int row = b * NNODE + m;
    const float* xb = x + (size_t)b * NNODE * DIM;
    const float* sqb = sq + b * NNODE;
    const float* xm = xb + (size_t)m * DIM;
    float4 m0v = *(const float4*)(xm + l * 8);
    float4 m1v = *(const float4*)(xm + l * 8 + 4);
    float sqm = sqb[m];

    int idx[NCAND];
    #pragma unroll
    for (int c = 0; c < NCAND; ++c) idx[c] = cand[row * NCAND + c];

    float s[NCAND];
    #pragma unroll
    for (int half = 0; half < 2; ++half) {
        float4 j0[10], j1[10];
        #pragma unroll
        for (int i = 0; i < 10; ++i) {
            const float* xj = xb + (size_t)idx[half * 10 + i] * DIM;
            j0[i] = *(const float4*)(xj + l * 8);
            j1[i] = *(const float4*)(xj + l * 8 + 4);
        }
        #pragma unroll
        for (int i = 0; i < 10; ++i)
            s[half * 10 + i] = m0v.x * j0[i].x + m0v.y * j0[i].y + m0v.z * j0[i].z + m0v.w * j0[i].w
                             + m1v.x * j1[i].x + m1v.y * j1[i].y + m1v.z * j1[i].z + m1v.w * j1[i].w;
    }
    #pragma unroll
    for (int off = 32; off > 0; off >>= 1)
        #pragma unroll
        for (int c = 0; c < NCAND; ++c) s[c] += __shfl_xor(s[c], off, 64);

    // all lanes now hold all 20 sums; build exact keys (f32 bits << 32 | idx)
    unsigned long long key[NCAND];
    #pragma unroll
    for (int c = 0; c < NCAND; ++c) {
        float dv = sqm + sqb[idx[c]] - 2.f * s[c];
        key[c] = ((unsigned long long)__float_as_uint(dv) << 32) | (unsigned)idx[c];
    }
    // lane l owns candidate l (static-index selection chain)
    unsigned long long mykey = ~0ull;
    int myidx = 0;
    #pragma unroll
    for (int c = 0; c < NCAND; ++c) {
        if (l == c) { mykey = key[c]; myidx = idx[c]; }
    }
    int rank = 0;
    #pragma unroll
    for (int c = 0; c < NCAND; ++c) rank += (key[c] < mykey) ? 1 : 0;

    int* dst = nbr + row * KP1;
    if (l < NCAND && rank < KNN) dst[rank] = myidx;
    if (l == 0) dst[KNN] = m;
}

// ---------------- per-graph max|x - mean| ----------------
__global__ void init_maxabs(unsigned* maxabs) { if (threadIdx.x < BATCH) maxabs[threadIdx.x] = 0u; }

__global__ __launch_bounds__(256) void maxabs_kernel(const float* __restrict__ x,
                                                     const float* __restrict__ mean,
                                                     unsigned* __restrict__ maxabs) {
    int b = blockIdx.y;
    const float* p = x + ((size_t)b * NNODE + blockIdx.x * 64) * DIM;
    const float* mb = mean + b * DIM;
    float m = 0.f;
    for (int i = threadIdx.x; i < 64 * DIM; i += 256) {
        int d = i & (DIM - 1);
        m = fmaxf(m, fabsf(p[i] - mb[d]));
    }
    __shared__ float red[256];
    red[threadIdx.x] = m; __syncthreads();
    for (int s = 128; s > 0; s >>= 1) {
        if (threadIdx.x < s) red[threadIdx.x] = fmaxf(red[threadIdx.x], red[threadIdx.x + s]);
        __syncthreads();
    }
    if (threadIdx.x == 0) atomicMax(maxabs + b, __float_as_uint(red[0]));
}

// ---------------- h0 = (x - mean) * 0.999999/maxabs -> split bf16 hi/lo ----------------
__global__ void normalize_kernel(const float* __restrict__ x, const float* __restrict__ mean,
                                 const unsigned* __restrict__ maxabs,
                                 unsigned short* __restrict__ h_hi, unsigned short* __restrict__ h_lo) {
    int id = blockIdx.x * 256 + threadIdx.x;
    int b = id >> 19;
    int d = id & (DIM - 1);
    float scale = 0.999999f / __uint_as_float(maxabs[b]);
    float v = (x[id] - mean[b * DIM + d]) * scale;
    split_store(v, h_hi, h_lo, id);
}

// ---------------- W[512x512] -> Wt hi/lo bf16 [n][k] (transpose + split) ----------------
__global__ void wsplit_kernel(const float* __restrict__ W,
                              unsigned short* __restrict__ Wh, unsigned short* __restrict__ Wl) {
    __shared__ float tile[32][33];
    int bx = blockIdx.x * 32, by = blockIdx.y * 32;
    int tx = threadIdx.x & 31, ty = threadIdx.x >> 5;
    #pragma unroll
    for (int i = 0; i < 4; ++i)
        tile[ty + i * 8][tx] = W[(size_t)(by + ty + i * 8) * DIM + bx + tx];
    __syncthreads();
    #pragma unroll
    for (int i = 0; i < 4; ++i) {
        int n = bx + ty + i * 8;
        float v = tile[tx][ty + i * 8];
        split_store(v, Wh, Wl, (size_t)n * DIM + by + tx);
    }
}

// ---------------- C f32 = (Ah+Al) . (Wh+Wl), split-bf16 MFMA ----------------
__global__ __launch_bounds__(256, 2) void gemm_mfma(const unsigned short* __restrict__ Agh,
                                                    const unsigned short* __restrict__ Agl,
                                                    const unsigned short* __restrict__ Bgh,
                                                    const unsigned short* __restrict__ Bgl,
                                                    float* __restrict__ C) {
    __shared__ unsigned short AhL[128][40], AlL[128][40], BhL[128][40], BlL[128][40];
    int m0 = blockIdx.y * BT, n0 = blockIdx.x * BT;
    int t = threadIdx.x;
    int lane = t & 63, w = t >> 6;
    int wm = (w >> 1) * 64, wn = (w & 1) * 64;
    int fr = lane & 15, fk = (lane >> 4) * 8;
    f32x4 acc[4][4];
    #pragma unroll
    for (int i = 0; i < 4; ++i)
        #pragma unroll
        for (int j = 0; j < 4; ++j) acc[i][j] = (f32x4){0.f, 0.f, 0.f, 0.f};

    for (int k0 = 0; k0 < DIM; k0 += 32) {
        if (k0) __syncthreads();
        #pragma unroll
        for (int p = 0; p < 2; ++p) {
            int u = t + p * 256;
            int row = u >> 2, seg = (u & 3) * 8;
            *(uint4*)&AhL[row][seg] = *(const uint4*)(Agh + (size_t)(m0 + row) * DIM + k0 + seg);
            *(uint4*)&AlL[row][seg] = *(const uint4*)(Agl + (size_t)(m0 + row) * DIM + k0 + seg);
            *(uint4*)&BhL[row][seg] = *(const uint4*)(Bgh + (size_t)(n0 + row) * DIM + k0 + seg);
            *(uint4*)&BlL[row][seg] = *(const uint4*)(Bgl + (size_t)(n0 + row) * DIM + k0 + seg);
        }
        __syncthreads();
        bf16x8 ah[4], al[4], bh[4], bl[4];
        #pragma unroll
        for (int i = 0; i < 4; ++i) {
            ah[i] = *(const bf16x8*)&AhL[wm + i * 16 + fr][fk];
            al[i] = *(const bf16x8*)&AlL[wm + i * 16 + fr][fk];
            bh[i] = *(const bf16x8*)&BhL[wn + i * 16 + fr][fk];
            bl[i] = *(const bf16x8*)&BlL[wn + i * 16 + fr][fk];
        }
        #pragma unroll
        for (int i = 0; i < 4; ++i)
            #pragma unroll
            for (int j = 0; j < 4; ++j) {
                acc[i][j] = __builtin_amdgcn_mfma_f32_16x16x32_bf16(ah[i], bh[j], acc[i][j], 0, 0, 0);
                acc[i][j] = __builtin_amdgcn_mfma_f32_16x16x32_bf16(ah[i], bl[j], acc[i][j], 0, 0, 0);
                acc[i][j] = __builtin_amdgcn_mfma_f32_16x16x32_bf16(al[i], bh[j], acc[i][j], 0, 0, 0);
            }
    }
    #pragma unroll
    for (int i = 0; i < 4; ++i) {
        int mrow = m0 + wm + i * 16 + (lane >> 4) * 4;
        #pragma unroll
        for (int j = 0; j < 4; ++j) {
            int col = n0 + wn + j * 16 + fr;
            #pragma unroll
            for (int r = 0; r < 4; ++r)
                C[(size_t)(mrow + r) * DIM + col] = acc[i][j][r];
        }
    }
}

// ---------------- a_s = hp @ asrc, a_d = hp @ adst (float4 loads) ----------------
__global__ void attvec_kernel(const float* __restrict__ hp, const float* __restrict__ asrc,
                              const float* __restrict__ adst, float* __restrict__ as_,
                              float* __restrict__ ad_) {
    int row = blockIdx.x * 4 + (threadIdx.x >> 6);
    int lane = threadIdx.x & 63;
    const float4* p = (const float4*)(hp + (size_t)row * DIM);
    const float4* s4 = (const float4*)asrc;
    const float4* d4 = (const float4*)adst;
    float4 a0 = p[lane], a1 = p[lane + 64];
    float4 u0 = s4[lane], u1 = s4[lane + 64];
    float4 v0 = d4[lane], v1 = d4[lane + 64];
    float s = a0.x * u0.x + a0.y * u0.y + a0.z * u0.z + a0.w * u0.w
            + a1.x * u1.x + a1.y * u1.y + a1.z * u1.z + a1.w * u1.w;
    float d = a0.x * v0.x + a0.y * v0.y + a0.z * v0.z + a0.w * v0.w
            + a1.x * v1.x + a1.y * v1.y + a1.z * v1.z + a1.w * v1.w;
    #pragma unroll
    for (int off = 32; off > 0; off >>= 1) { s += __shfl_down(s, off, 64); d += __shfl_down(d, off, 64); }
    if (lane == 0) { as_[row] = s; ad_[row] = d; }
}

// ---------------- GAT attention + aggregation (XCD-swizzled, parallel softmax) ----------------
template<int RELU, int SPLIT>
__global__ __launch_bounds__(256) void aggr_kernel(const float* __restrict__ hp, const int* __restrict__ nbr,
                                                   const float* __restrict__ as_, const float* __restrict__ ad_,
                                                   const float* __restrict__ bias,
                                                   float* __restrict__ outf,
                                                   unsigned short* __restrict__ oh,
                                                   unsigned short* __restrict__ ol) {
    int bid = blockIdx.x;
    int b = bid & (BATCH - 1);
    int id = b * NNODE + (bid >> 4);     // XCD bid%8 serves graphs {b, b+8}
    __shared__ float att[KP1];
    __shared__ int   jj[KP1];
    int t = threadIdx.x;
    if (t < 32) {
        float e = -INFINITY;
        int j = 0;
        if (t < KP1) {
            j = nbr[id * KP1 + t];
            jj[t] = j;
            e = as_[b * NNODE + j] + ad_[id];
            e = (e >= 0.f) ? e : NEG * e;
        }
        float mx = e;
        #pragma unroll
        for (int off = 16; off > 0; off >>= 1) mx = fmaxf(mx, __shfl_xor(mx, off, 64));
        float ex = (t < KP1) ? expf(e - mx) : 0.f;
        float sm = ex;
        #pragma unroll
        for (int off = 16; off > 0; off >>= 1) sm += __shfl_xor(sm, off, 64);
        if (t < KP1) att[t] = ex / sm;
    }
    __syncthreads();
    const float* base = hp + (size_t)b * NNODE * DIM;
    int d = t * 2;
    float2 o = *(const float2*)(bias + d);
    #pragma unroll
    for (int k = 0; k < KP1; ++k) {
        float a = att[k];
        float2 v = *(const float2*)(base + (size_t)jj[k] * DIM + d);
        o.x += a * v.x; o.y += a * v.y;
    }
    if (RELU) { o.x = fmaxf(o.x, 0.f); o.y = fmaxf(o.y, 0.f); }
    size_t idx = (size_t)id * DIM + d;
    if (SPLIT) { split_store(o.x, oh, ol, idx); split_store(o.y, oh, ol, idx + 1); }
    else       { *(float2*)(outf + idx) = o; }
}

// ---------------- global max pool, stage 1: partial max over 64-node chunks ----------------
__global__ __launch_bounds__(256) void maxpool_part(const float* __restrict__ h, float* __restrict__ part) {
    int b = blockIdx.x, dc = blockIdx.y, ch = blockIdx.z;
    int d = dc * 256 + threadIdx.x;
    const float* p = h + ((size_t)b * NNODE + ch * (NNODE / NCH)) * DIM + d;
    float m = -INFINITY;
    #pragma unroll 4
    for (int n = 0; n < NNODE / NCH; ++n) m = fmaxf(m, p[(size_t)n * DIM]);
    part[((size_t)b * NCH + ch) * DIM + d] = m;
}
__global__ void maxpool_fin(const float* __restrict__ part, float* __restrict__ g) {
    int id = blockIdx.x * 256 + threadIdx.x;   // b*DIM + d
    int b = id >> 9, d = id & (DIM - 1);
    float m = -INFINITY;
    #pragma unroll
    for (int ch = 0; ch < NCH; ++ch) m = fmaxf(m, part[((size_t)b * NCH + ch) * DIM + d]);
    g[id] = m;
}

// ---------------- final linear g @ Wc + bc ----------------
__global__ void final_kernel(const float* __restrict__ g, const float* __restrict__ Wc,
                             const float* __restrict__ bc, float* __restrict__ out) {
    int b = blockIdx.x, t = threadIdx.x;
    float s0 = 0.f, s1 = 0.f;
    for (int d = t; d < DIM; d += 256) {
        float v = g[b * DIM + d];
        s0 += v * Wc[d * 2 + 0];
        s1 += v * Wc[d * 2 + 1];
    }
    __shared__ float r0[256], r1[256];
    r0[t] = s0; r1[t] = s1; __syncthreads();
    for (int s = 128; s > 0; s >>= 1) {
        if (t < s) { r0[t] += r0[t + s]; r1[t] += r1[t + s]; }
        __syncthreads();
    }
    if (t == 0) { out[b * 2] = r0[0] + bc[0]; out[b * 2 + 1] = r1[0] + bc[1]; }
}

extern "C" void kernel_launch(void* const* d_in, const int* in_sizes, int n_in,
                              void* d_out, int out_size, void* d_ws, size_t ws_size,
                              hipStream_t stream) {
    const float* x     = (const float*)d_in[0];
    const float* W1    = (const float*)d_in[1];
    const float* asrc1 = (const float*)d_in[2];
    const float* adst1 = (const float*)d_in[3];
    const float* b1    = (const float*)d_in[4];
    const float* W2    = (const float*)d_in[5];
    const float* asrc2 = (const float*)d_in[6];
    const float* adst2 = (const float*)d_in[7];
    const float* b2    = (const float*)d_in[8];
    const float* W3    = (const float*)d_in[9];
    const float* asrc3 = (const float*)d_in[10];
    const float* adst3 = (const float*)d_in[11];
    const float* b3    = (const float*)d_in[12];
    const float* Wc    = (const float*)d_in[13];
    const float* bc    = (const float*)d_in[14];
    float* out = (float*)d_out;

    char* ws = (char*)d_ws;
    float*          d2    = (float*)ws;                            // 64MB (graph build only)
    float*          hp    = (float*)ws;                            // 32MB f32
    unsigned short* hA_hi = (unsigned short*)(ws + (32ull << 20)); // 16MB
    unsigned short* hA_lo = (unsigned short*)(ws + (48ull << 20)); // 16MB
    unsigned short* xh    = (unsigned short*)(ws + (64ull << 20)); // 16MB (graph build only)
    unsigned short* hB_hi = (unsigned short*)(ws + (64ull << 20)); // 16MB
    unsigned short* hB_lo = (unsigned short*)(ws + (80ull << 20)); // 16MB
    float*          h3    = (float*)(ws + (64ull << 20));          // 32MB, alias hB
    size_t off = 96ull << 20;
    unsigned short* Wt1h = (unsigned short*)(ws + off); off += (size_t)DIM * DIM * 2;
    unsigned short* Wt1l = (unsigned short*)(ws + off); off += (size_t)DIM * DIM * 2;
    unsigned short* Wt2h = (unsigned short*)(ws + off); off += (size_t)DIM * DIM * 2;
    unsigned short* Wt2l = (unsigned short*)(ws + off); off += (size_t)DIM * DIM * 2;
    unsigned short* Wt3h = (unsigned short*)(ws + off); off += (size_t)DIM * DIM * 2;
    unsigned short* Wt3l = (unsigned short*)(ws + off); off += (size_t)DIM * DIM * 2;
    int*      nbr    = (int*)(ws + off);      off += (size_t)BATCH * NNODE * KP1 * 4;
    int*      cand   = (int*)(ws + off);      off += (size_t)BATCH * NNODE * NCAND * 4;
    float*    sq     = (float*)(ws + off);    off += (size_t)BATCH * NNODE * 4;
    float*    mean   = (float*)(ws + off);    off += (size_t)BATCH * DIM * 4;
    unsigned* maxabs = (unsigned*)(ws + off); off += 256;
    float*    as_    = (float*)(ws + off);    off += (size_t)BATCH * NNODE * 4;
    float*    ad_    = (float*)(ws + off);    off += (size_t)BATCH * NNODE * 4;
    float*    g      = (float*)(ws + off);    off += (size_t)BATCH * DIM * 4;
    float*    part   = (float*)(ws + off);    off += (size_t)BATCH * NCH * DIM * 4;  // 512KB scratch
    (void)ws_size; (void)in_sizes; (void)n_in; (void)out_size;

    const dim3 cgrid(BATCH, DIM / 256, NCH);
    // ---- graph construction: approx bf16 MFMA distances + exact f32 re-rank ----
    colmean_part<<<cgrid, 256, 0, stream>>>(x, part);
    colmean_fin<<<BATCH * DIM / 256, 256, 0, stream>>>(part, mean);
    rowsq_kernel<<<BATCH * NNODE / 4, 256, 0, stream>>>(x, sq);
    xtobf_kernel<<<BATCH * NNODE * DIM / 1024, 256, 0, stream>>>(x, xh);
    dist_mfma<<<dim3(NNODE / BT, BATCH * NNODE / BT), 256, 0, stream>>>(xh, sq, d2);
    knn_kernel<<<BATCH * NNODE / 4, 256, 0, stream>>>(d2, cand);
    rerank_kernel<<<BATCH * NNODE / 4, 256, 0, stream>>>(x, sq, cand, nbr);
    // ---- weights transpose + split ----
    wsplit_kernel<<<dim3(16, 16), 256, 0, stream>>>(W1, Wt1h, Wt1l);
    wsplit_kernel<<<dim3(16, 16), 256, 0, stream>>>(W2, Wt2h, Wt2l);
    wsplit_kernel<<<dim3(16, 16), 256, 0, stream>>>(W3, Wt3h, Wt3l);
    // ---- normalize -> hA (split bf16); d2/xh dead from here ----
    init_maxabs<<<1, 64, 0, stream>>>(maxabs);
    maxabs_kernel<<<dim3(16, BATCH), 256, 0, stream>>>(x, mean, maxabs);
    normalize_kernel<<<BATCH * NNODE * DIM / 256, 256, 0, stream>>>(x, mean, maxabs, hA_hi, hA_lo);

    const dim3 ggrid(DIM / BT, BATCH * NNODE / BT);   // (4, 128)
    // layer 1
    gemm_mfma<<<ggrid, 256, 0, stream>>>(hA_hi, hA_lo, Wt1h, Wt1l, hp);
    attvec_kernel<<<BATCH * NNODE / 4, 256, 0, stream>>>(hp, asrc1, adst1, as_, ad_);
    aggr_kernel<1, 1><<<BATCH * NNODE, 256, 0, stream>>>(hp, nbr, as_, ad_, b1, nullptr, hB_hi, hB_lo);
    // layer 2
    gemm_mfma<<<ggrid, 256, 0, stream>>>(hB_hi, hB_lo, Wt2h, Wt2l, hp);
    attvec_kernel<<<BATCH * NNODE / 4, 256, 0, stream>>>(hp, asrc2, adst2, as_, ad_);
    aggr_kernel<1, 1><<<BATCH * NNODE, 256, 0, stream>>>(hp, nbr, as_, ad_, b2, nullptr, hA_hi, hA_lo);
    // layer 3
    gemm_mfma<<<ggrid, 256, 0, stream>>>(hA_hi, hA_lo, Wt3h, Wt3l, hp);
    attvec_kernel<<<BATCH * NNODE / 4, 256, 0, stream>>>(hp, asrc3, adst3, as_, ad_);
    aggr_kernel<0, 0><<<BATCH * NNODE, 256, 0, stream>>>(hp, nbr, as_, ad_, b3, h3, nullptr, nullptr);
    // pool + classify
    maxpool_part<<<cgrid, 256, 0, stream>>>(h3, part);
    maxpool_fin<<<BATCH * DIM / 256, 256, 0, stream>>>(part, g);
    final_kernel<<<BATCH, 256, 0, stream>>>(g, Wc, bc, out);
}

// Round 10
// 422.893 us; speedup vs baseline: 2.8023x; 1.0796x over previous
//
#include <hip/hip_runtime.h>
#include <hip/hip_bf16.h>
#include <math.h>

#define BATCH 16
#define NNODE 1024
#define DIM   512
#define KNN   16
#define KP1   17
#define NCAND 20
#define NEG   0.2f
#define BT    128   // block tile
#define NCH   16    // n-chunks for column reductions

typedef __attribute__((ext_vector_type(8))) short bf16x8;
typedef __attribute__((ext_vector_type(4))) float f32x4;

__device__ __forceinline__ unsigned short f2bf(float f) {
    unsigned u = __float_as_uint(f);
    unsigned r = (u + 0x7FFFu + ((u >> 16) & 1u)) >> 16;   // RNE
    return (unsigned short)r;
}
__device__ __forceinline__ float bf2f(unsigned short h) {
    return __uint_as_float(((unsigned)h) << 16);
}
__device__ __forceinline__ void split_store(float v, unsigned short* hi, unsigned short* lo, size_t idx) {
    unsigned short h = f2bf(v);
    hi[idx] = h;
    lo[idx] = f2bf(v - bf2f(h));
}

// ---------------- column mean, stage 1: partial sums over 64-node chunks ----------------
__global__ __launch_bounds__(256) void colmean_part(const float* __restrict__ x, float* __restrict__ part) {
    int b = blockIdx.x, dc = blockIdx.y, ch = blockIdx.z;
    int d = dc * 256 + threadIdx.x;
    const float* p = x + ((size_t)b * NNODE + ch * (NNODE / NCH)) * DIM + d;
    float s = 0.f;
    #pragma unroll 4
    for (int n = 0; n < NNODE / NCH; ++n) s += p[(size_t)n * DIM];
    part[((size_t)b * NCH + ch) * DIM + d] = s;
}
__global__ void colmean_fin(const float* __restrict__ part, float* __restrict__ mean) {
    int id = blockIdx.x * 256 + threadIdx.x;   // b*DIM + d
    int b = id >> 9, d = id & (DIM - 1);
    float s = 0.f;
    #pragma unroll
    for (int ch = 0; ch < NCH; ++ch) s += part[((size_t)b * NCH + ch) * DIM + d];
    mean[id] = s * (1.0f / NNODE);
}

// ---------------- row squared norms of raw pos ----------------
__global__ void rowsq_kernel(const float* __restrict__ x, float* __restrict__ sq) {
    int row = blockIdx.x * 4 + (threadIdx.x >> 6);
    int lane = threadIdx.x & 63;
    const float* p = x + (size_t)row * DIM;
    float s = 0.f;
    for (int i = lane; i < DIM; i += 64) { float v = p[i]; s += v * v; }
    #pragma unroll
    for (int off = 32; off > 0; off >>= 1) s += __shfl_down(s, off, 64);
    if (lane == 0) sq[row] = s;
}

// ---------------- x -> bf16 (for approximate candidate distances) ----------------
__global__ void xtobf_kernel(const float* __restrict__ x, unsigned short* __restrict__ xh) {
    int id = blockIdx.x * 256 + threadIdx.x;
    float4 v = *(const float4*)(x + (size_t)id * 4);
    ushort4 o;
    o.x = f2bf(v.x); o.y = f2bf(v.y); o.z = f2bf(v.z); o.w = f2bf(v.w);
    *(ushort4*)(xh + (size_t)id * 4) = o;
}

// ---------------- approx distance matrix via bf16 MFMA (candidate stage) ----------------
__global__ __launch_bounds__(256, 2) void dist_mfma(const unsigned short* __restrict__ xh,
                                                    const float* __restrict__ sq,
                                                    float* __restrict__ d2) {
    __shared__ unsigned short AhL[128][40], BhL[128][40];
    int mt = blockIdx.y;
    int b = mt >> 3;
    int m0 = mt * BT;
    int n0 = blockIdx.x * BT;
    int bn0 = b * NNODE + n0;
    int t = threadIdx.x;
    int lane = t & 63, w = t >> 6;
    int wm = (w >> 1) * 64, wn = (w & 1) * 64;
    int fr = lane & 15, fk = (lane >> 4) * 8;
    f32x4 acc[4][4];
    #pragma unroll
    for (int i = 0; i < 4; ++i)
        #pragma unroll
        for (int j = 0; j < 4; ++j) acc[i][j] = (f32x4){0.f, 0.f, 0.f, 0.f};

    for (int k0 = 0; k0 < DIM; k0 += 32) {
        if (k0) __syncthreads();
        #pragma unroll
        for (int p = 0; p < 2; ++p) {
            int u = t + p * 256;
            int row = u >> 2, seg = (u & 3) * 8;
            *(uint4*)&AhL[row][seg] = *(const uint4*)(xh + (size_t)(m0 + row) * DIM + k0 + seg);
            *(uint4*)&BhL[row][seg] = *(const uint4*)(xh + (size_t)(bn0 + row) * DIM + k0 + seg);
        }
        __syncthreads();
        bf16x8 ah[4], bh[4];
        #pragma unroll
        for (int i = 0; i < 4; ++i) {
            ah[i] = *(const bf16x8*)&AhL[wm + i * 16 + fr][fk];
            bh[i] = *(const bf16x8*)&BhL[wn + i * 16 + fr][fk];
        }
        #pragma unroll
        for (int i = 0; i < 4; ++i)
            #pragma unroll
            for (int j = 0; j < 4; ++j)
                acc[i][j] = __builtin_amdgcn_mfma_f32_16x16x32_bf16(ah[i], bh[j], acc[i][j], 0, 0, 0);
    }
    const float* sqb = sq + b * NNODE;
    int mloc0 = m0 - b * NNODE;
    #pragma unroll
    for (int i = 0; i < 4; ++i) {
        int mloc = mloc0 + wm + i * 16 + (lane >> 4) * 4;
        #pragma unroll
        for (int j = 0; j < 4; ++j) {
            int n = n0 + wn + j * 16 + fr;
            float sqn = sqb[n];
            #pragma unroll
            for (int r = 0; r < 4; ++r) {
                float val = sqb[mloc + r] + sqn - 2.f * acc[i][j][r];
                if (mloc + r == n) val = INFINITY;
                d2[((size_t)b * NNODE + mloc + r) * NNODE + n] = val;
            }
        }
    }
}

// ---------------- top-20 smallest per row (approx): u32 keys + threshold walk ----------------
__global__ __launch_bounds__(256) void knn_kernel(const float* __restrict__ d2, int* __restrict__ cand) {
    int row = blockIdx.x * 4 + (threadIdx.x >> 6);   // b*N + n
    int l = threadIdx.x & 63;
    const float* src = d2 + (size_t)row * NNODE;
    unsigned key[16];
    #pragma unroll
    for (int j = 0; j < 16; ++j) {
        unsigned v = __float_as_uint(src[l + (j << 6)]);
        key[j] = (v & 0xFFFFFC00u) | (unsigned)(l + (j << 6));
    }
    int* dst = cand + row * NCAND;
    unsigned T = 0;
    for (int it = 0; it < NCAND; ++it) {
        unsigned lmin = 0xFFFFFFFFu;
        #pragma unroll
        for (int j = 0; j < 16; ++j) {
            unsigned k = (key[j] > T) ? key[j] : 0xFFFFFFFFu;
            lmin = min(lmin, k);
        }
        #pragma unroll
        for (int off = 1; off < 64; off <<= 1) {
            unsigned o = (unsigned)__shfl_xor((int)lmin, off, 64);
            lmin = min(lmin, o);
        }
        T = lmin;
        if (l == 0) dst[it] = (int)(lmin & 1023u);
    }
}

// ---------------- exact f32 re-rank: one wave per row, in-register rank selection ----------------
__global__ __launch_bounds__(256) void rerank_kernel(const float* __restrict__ x,
                                                     const float* __restrict__ sq,
                                                     const int* __restrict__ cand,
                                                     int* __restrict__ nbr) {
    int bid = blockIdx.x;                 // 4096 blocks
    int b = bid & (BATCH - 1);
    int w = threadIdx.x >> 6, l = threadIdx.x & 63;
    int m = (bid >> 4) * 4 + w;
    int row = b * NNODE + m;
    const float* xb = x + (size_t)b * NNODE * DIM;
    const float* sqb = sq + b * NNODE;
    const float* xm = xb + (size_t)m * DIM;
    float4 m0v = *(const float4*)(xm + l * 8);
    float4 m1v = *(const float4*)(xm + l * 8 + 4);
    float sqm = sqb[m];

    int idx[NCAND];
    #pragma unroll
    for (int c = 0; c < NCAND; ++c) idx[c] = cand[row * NCAND + c];

    float s[NCAND];
    #pragma unroll
    for (int half = 0; half < 2; ++half) {
        float4 j0[10], j1[10];
        #pragma unroll
        for (int i = 0; i < 10; ++i) {
            const float* xj = xb + (size_t)idx[half * 10 + i] * DIM;
            j0[i] = *(const float4*)(xj + l * 8);
            j1[i] = *(const float4*)(xj + l * 8 + 4);
        }
        #pragma unroll
        for (int i = 0; i < 10; ++i)
            s[half * 10 + i] = m0v.x * j0[i].x + m0v.y * j0[i].y + m0v.z * j0[i].z + m0v.w * j0[i].w
                             + m1v.x * j1[i].x + m1v.y * j1[i].y + m1v.z * j1[i].z + m1v.w * j1[i].w;
    }
    #pragma unroll
    for (int off = 32; off > 0; off >>= 1)
        #pragma unroll
        for (int c = 0; c < NCAND; ++c) s[c] += __shfl_xor(s[c], off, 64);

    unsigned long long key[NCAND];
    #pragma unroll
    for (int c = 0; c < NCAND; ++c) {
        float dv = sqm + sqb[idx[c]] - 2.f * s[c];
        key[c] = ((unsigned long long)__float_as_uint(dv) << 32) | (unsigned)idx[c];
    }
    unsigned long long mykey = ~0ull;
    int myidx = 0;
    #pragma unroll
    for (int c = 0; c < NCAND; ++c) {
        if (l == c) { mykey = key[c]; myidx = idx[c]; }
    }
    int rank = 0;
    #pragma unroll
    for (int c = 0; c < NCAND; ++c) rank += (key[c] < mykey) ? 1 : 0;

    int* dst = nbr + row * KP1;
    if (l < NCAND && rank < KNN) dst[rank] = myidx;
    if (l == 0) dst[KNN] = m;
}

// ---------------- per-graph max|x - mean| ----------------
__global__ void init_maxabs(unsigned* maxabs) { if (threadIdx.x < BATCH) maxabs[threadIdx.x] = 0u; }

__global__ __launch_bounds__(256) void maxabs_kernel(const float* __restrict__ x,
                                                     const float* __restrict__ mean,
                                                     unsigned* __restrict__ maxabs) {
    int b = blockIdx.y;
    const float* p = x + ((size_t)b * NNODE + blockIdx.x * 64) * DIM;
    const float* mb = mean + b * DIM;
    float m = 0.f;
    for (int i = threadIdx.x; i < 64 * DIM; i += 256) {
        int d = i & (DIM - 1);
        m = fmaxf(m, fabsf(p[i] - mb[d]));
    }
    __shared__ float red[256];
    red[threadIdx.x] = m; __syncthreads();
    for (int s = 128; s > 0; s >>= 1) {
        if (threadIdx.x < s) red[threadIdx.x] = fmaxf(red[threadIdx.x], red[threadIdx.x + s]);
        __syncthreads();
    }
    if (threadIdx.x == 0) atomicMax(maxabs + b, __float_as_uint(red[0]));
}

// ---------------- h0 = (x - mean) * 0.999999/maxabs -> split bf16 hi/lo ----------------
__global__ void normalize_kernel(const float* __restrict__ x, const float* __restrict__ mean,
                                 const unsigned* __restrict__ maxabs,
                                 unsigned short* __restrict__ h_hi, unsigned short* __restrict__ h_lo) {
    int id = blockIdx.x * 256 + threadIdx.x;
    int b = id >> 19;
    int d = id & (DIM - 1);
    float scale = 0.999999f / __uint_as_float(maxabs[b]);
    float v = (x[id] - mean[b * DIM + d]) * scale;
    split_store(v, h_hi, h_lo, id);
}

// ---------------- W[512x512] -> Wt hi/lo bf16 [n][k] (transpose + split) ----------------
__global__ void wsplit_kernel(const float* __restrict__ W,
                              unsigned short* __restrict__ Wh, unsigned short* __restrict__ Wl) {
    __shared__ float tile[32][33];
    int bx = blockIdx.x * 32, by = blockIdx.y * 32;
    int tx = threadIdx.x & 31, ty = threadIdx.x >> 5;
    #pragma unroll
    for (int i = 0; i < 4; ++i)
        tile[ty + i * 8][tx] = W[(size_t)(by + ty + i * 8) * DIM + bx + tx];
    __syncthreads();
    #pragma unroll
    for (int i = 0; i < 4; ++i) {
        int n = bx + ty + i * 8;
        float v = tile[tx][ty + i * 8];
        split_store(v, Wh, Wl, (size_t)n * DIM + by + tx);
    }
}

// ---------------- C f32 = (Ah+Al) . (Wh+Wl), split-bf16 MFMA ----------------
__global__ __launch_bounds__(256, 2) void gemm_mfma(const unsigned short* __restrict__ Agh,
                                                    const unsigned short* __restrict__ Agl,
                                                    const unsigned short* __restrict__ Bgh,
                                                    const unsigned short* __restrict__ Bgl,
                                                    float* __restrict__ C) {
    __shared__ unsigned short AhL[128][40], AlL[128][40], BhL[128][40], BlL[128][40];
    int m0 = blockIdx.y * BT, n0 = blockIdx.x * BT;
    int t = threadIdx.x;
    int lane = t & 63, w = t >> 6;
    int wm = (w >> 1) * 64, wn = (w & 1) * 64;
    int fr = lane & 15, fk = (lane >> 4) * 8;
    f32x4 acc[4][4];
    #pragma unroll
    for (int i = 0; i < 4; ++i)
        #pragma unroll
        for (int j = 0; j < 4; ++j) acc[i][j] = (f32x4){0.f, 0.f, 0.f, 0.f};

    for (int k0 = 0; k0 < DIM; k0 += 32) {
        if (k0) __syncthreads();
        #pragma unroll
        for (int p = 0; p < 2; ++p) {
            int u = t + p * 256;
            int row = u >> 2, seg = (u & 3) * 8;
            *(uint4*)&AhL[row][seg] = *(const uint4*)(Agh + (size_t)(m0 + row) * DIM + k0 + seg);
            *(uint4*)&AlL[row][seg] = *(const uint4*)(Agl + (size_t)(m0 + row) * DIM + k0 + seg);
            *(uint4*)&BhL[row][seg] = *(const uint4*)(Bgh + (size_t)(n0 + row) * DIM + k0 + seg);
            *(uint4*)&BlL[row][seg] = *(const uint4*)(Bgl + (size_t)(n0 + row) * DIM + k0 + seg);
        }
        __syncthreads();
        bf16x8 ah[4], al[4], bh[4], bl[4];
        #pragma unroll
        for (int i = 0; i < 4; ++i) {
            ah[i] = *(const bf16x8*)&AhL[wm + i * 16 + fr][fk];
            al[i] = *(const bf16x8*)&AlL[wm + i * 16 + fr][fk];
            bh[i] = *(const bf16x8*)&BhL[wn + i * 16 + fr][fk];
            bl[i] = *(const bf16x8*)&BlL[wn + i * 16 + fr][fk];
        }
        #pragma unroll
        for (int i = 0; i < 4; ++i)
            #pragma unroll
            for (int j = 0; j < 4; ++j) {
                acc[i][j] = __builtin_amdgcn_mfma_f32_16x16x32_bf16(ah[i], bh[j], acc[i][j], 0, 0, 0);
                acc[i][j] = __builtin_amdgcn_mfma_f32_16x16x32_bf16(ah[i], bl[j], acc[i][j], 0, 0, 0);
                acc[i][j] = __builtin_amdgcn_mfma_f32_16x16x32_bf16(al[i], bh[j], acc[i][j], 0, 0, 0);
            }
    }
    #pragma unroll
    for (int i = 0; i < 4; ++i) {
        int mrow = m0 + wm + i * 16 + (lane >> 4) * 4;
        #pragma unroll
        for (int j = 0; j < 4; ++j) {
            int col = n0 + wn + j * 16 + fr;
            #pragma unroll
            for (int r = 0; r < 4; ++r)
                C[(size_t)(mrow + r) * DIM + col] = acc[i][j][r];
        }
    }
}

// ---------------- a_s = hp @ asrc, a_d = hp @ adst (float4 loads) ----------------
__global__ void attvec_kernel(const float* __restrict__ hp, const float* __restrict__ asrc,
                              const float* __restrict__ adst, float* __restrict__ as_,
                              float* __restrict__ ad_) {
    int row = blockIdx.x * 4 + (threadIdx.x >> 6);
    int lane = threadIdx.x & 63;
    const float4* p = (const float4*)(hp + (size_t)row * DIM);
    const float4* s4 = (const float4*)asrc;
    const float4* d4 = (const float4*)adst;
    float4 a0 = p[lane], a1 = p[lane + 64];
    float4 u0 = s4[lane], u1 = s4[lane + 64];
    float4 v0 = d4[lane], v1 = d4[lane + 64];
    float s = a0.x * u0.x + a0.y * u0.y + a0.z * u0.z + a0.w * u0.w
            + a1.x * u1.x + a1.y * u1.y + a1.z * u1.z + a1.w * u1.w;
    float d = a0.x * v0.x + a0.y * v0.y + a0.z * v0.z + a0.w * v0.w
            + a1.x * v1.x + a1.y * v1.y + a1.z * v1.z + a1.w * v1.w;
    #pragma unroll
    for (int off = 32; off > 0; off >>= 1) { s += __shfl_down(s, off, 64); d += __shfl_down(d, off, 64); }
    if (lane == 0) { as_[row] = s; ad_[row] = d; }
}

// ---------------- GAT attention + aggregation: wave-per-node, float4 gathers ----------------
// XCD-swizzled (b = bid%16). No __syncthreads: each wave writes & reads only its own LDS slice.
template<int RELU, int SPLIT>
__global__ __launch_bounds__(256) void aggr_kernel(const float* __restrict__ hp, const int* __restrict__ nbr,
                                                   const float* __restrict__ as_, const float* __restrict__ ad_,
                                                   const float* __restrict__ bias,
                                                   float* __restrict__ outf,
                                                   unsigned short* __restrict__ oh,
                                                   unsigned short* __restrict__ ol) {
    __shared__ float attL[4][KP1];
    __shared__ int   jjL[4][KP1];
    int bid = blockIdx.x;                 // B*N/4 blocks
    int b = bid & (BATCH - 1);
    int w = threadIdx.x >> 6, l = threadIdx.x & 63;
    int n = (bid >> 4) * 4 + w;
    int id = b * NNODE + n;

    float e = -INFINITY;
    if (l < KP1) {
        int j = nbr[id * KP1 + l];
        jjL[w][l] = j;
        e = as_[b * NNODE + j] + ad_[id];
        e = (e >= 0.f) ? e : NEG * e;
    }
    float mx = e;
    #pragma unroll
    for (int off = 16; off > 0; off >>= 1) mx = fmaxf(mx, __shfl_xor(mx, off, 64));
    float ex = (l < KP1) ? expf(e - mx) : 0.f;
    float sm = ex;
    #pragma unroll
    for (int off = 16; off > 0; off >>= 1) sm += __shfl_xor(sm, off, 64);
    if (l < KP1) attL[w][l] = ex / sm;
    // same-wave LDS write->read: compiler orders via lgkmcnt, no barrier needed

    const float* base = hp + (size_t)b * NNODE * DIM;
    int d0 = l * 8;
    const float4* b4 = (const float4*)(bias + d0);
    float4 o0 = b4[0], o1 = b4[1];
    #pragma unroll
    for (int k = 0; k < KP1; ++k) {
        float a = attL[w][k];
        const float* vp = base + (size_t)jjL[w][k] * DIM + d0;
        float4 v0 = *(const float4*)vp;
        float4 v1 = *(const float4*)(vp + 4);
        o0.x += a * v0.x; o0.y += a * v0.y; o0.z += a * v0.z; o0.w += a * v0.w;
        o1.x += a * v1.x; o1.y += a * v1.y; o1.z += a * v1.z; o1.w += a * v1.w;
    }
    if (RELU) {
        o0.x = fmaxf(o0.x, 0.f); o0.y = fmaxf(o0.y, 0.f); o0.z = fmaxf(o0.z, 0.f); o0.w = fmaxf(o0.w, 0.f);
        o1.x = fmaxf(o1.x, 0.f); o1.y = fmaxf(o1.y, 0.f); o1.z = fmaxf(o1.z, 0.f); o1.w = fmaxf(o1.w, 0.f);
    }
    size_t idx = (size_t)id * DIM + d0;
    if (SPLIT) {
        float v[8] = {o0.x, o0.y, o0.z, o0.w, o1.x, o1.y, o1.z, o1.w};
        unsigned hi[4], lo[4];
        #pragma unroll
        for (int i = 0; i < 4; ++i) {
            unsigned short h0 = f2bf(v[2 * i]),     h1 = f2bf(v[2 * i + 1]);
            unsigned short l0 = f2bf(v[2 * i] - bf2f(h0));
            unsigned short l1 = f2bf(v[2 * i + 1] - bf2f(h1));
            hi[i] = (unsigned)h0 | ((unsigned)h1 << 16);
            lo[i] = (unsigned)l0 | ((unsigned)l1 << 16);
        }
        *(uint4*)(oh + idx) = *(uint4*)hi;
        *(uint4*)(ol + idx) = *(uint4*)lo;
    } else {
        *(float4*)(outf + idx) = o0;
        *(float4*)(outf + idx + 4) = o1;
    }
}

// ---------------- global max pool, stage 1: partial max over 64-node chunks ----------------
__global__ __launch_bounds__(256) void maxpool_part(const float* __restrict__ h, float* __restrict__ part) {
    int b = blockIdx.x, dc = blockIdx.y, ch = blockIdx.z;
    int d = dc * 256 + threadIdx.x;
    const float* p = h + ((size_t)b * NNODE + ch * (NNODE / NCH)) * DIM + d;
    float m = -INFINITY;
    #pragma unroll 4
    for (int n = 0; n < NNODE / NCH; ++n) m = fmaxf(m, p[(size_t)n * DIM]);
    part[((size_t)b * NCH + ch) * DIM + d] = m;
}
__global__ void maxpool_fin(const float* __restrict__ part, float* __restrict__ g) {
    int id = blockIdx.x * 256 + threadIdx.x;   // b*DIM + d
    int b = id >> 9, d = id & (DIM - 1);
    float m = -INFINITY;
    #pragma unroll
    for (int ch = 0; ch < NCH; ++ch) m = fmaxf(m, part[((size_t)b * NCH + ch) * DIM + d]);
    g[id] = m;
}

// ---------------- final linear g @ Wc + bc ----------------
__global__ void final_kernel(const float* __restrict__ g, const float* __restrict__ Wc,
                             const float* __restrict__ bc, float* __restrict__ out) {
    int b = blockIdx.x, t = threadIdx.x;
    float s0 = 0.f, s1 = 0.f;
    for (int d = t; d < DIM; d += 256) {
        float v = g[b * DIM + d];
        s0 += v * Wc[d * 2 + 0];
        s1 += v * Wc[d * 2 + 1];
    }
    __shared__ float r0[256], r1[256];
    r0[t] = s0; r1[t] = s1; __syncthreads();
    for (int s = 128; s > 0; s >>= 1) {
        if (t < s) { r0[t] += r0[t + s]; r1[t] += r1[t + s]; }
        __syncthreads();
    }
    if (t == 0) { out[b * 2] = r0[0] + bc[0]; out[b * 2 + 1] = r1[0] + bc[1]; }
}

extern "C" void kernel_launch(void* const* d_in, const int* in_sizes, int n_in,
                              void* d_out, int out_size, void* d_ws, size_t ws_size,
                              hipStream_t stream) {
    const float* x     = (const float*)d_in[0];
    const float* W1    = (const float*)d_in[1];
    const float* asrc1 = (const float*)d_in[2];
    const float* adst1 = (const float*)d_in[3];
    const float* b1    = (const float*)d_in[4];
    const float* W2    = (const float*)d_in[5];
    const float* asrc2 = (const float*)d_in[6];
    const float* adst2 = (const float*)d_in[7];
    const float* b2    = (const float*)d_in[8];
    const float* W3    = (const float*)d_in[9];
    const float* asrc3 = (const float*)d_in[10];
    const float* adst3 = (const float*)d_in[11];
    const float* b3    = (const float*)d_in[12];
    const float* Wc    = (const float*)d_in[13];
    const float* bc    = (const float*)d_in[14];
    float* out = (float*)d_out;

    char* ws = (char*)d_ws;
    float*          d2    = (float*)ws;                            // 64MB (graph build only)
    float*          hp    = (float*)ws;                            // 32MB f32
    unsigned short* hA_hi = (unsigned short*)(ws + (32ull << 20)); // 16MB
    unsigned short* hA_lo = (unsigned short*)(ws + (48ull << 20)); // 16MB
    unsigned short* xh    = (unsigned short*)(ws + (64ull << 20)); // 16MB (graph build only)
    unsigned short* hB_hi = (unsigned short*)(ws + (64ull << 20)); // 16MB
    unsigned short* hB_lo = (unsigned short*)(ws + (80ull << 20)); // 16MB
    float*          h3    = (float*)(ws + (64ull << 20));          // 32MB, alias hB
    size_t off = 96ull << 20;
    unsigned short* Wt1h = (unsigned short*)(ws + off); off += (size_t)DIM * DIM * 2;
    unsigned short* Wt1l = (unsigned short*)(ws + off); off += (size_t)DIM * DIM * 2;
    unsigned short* Wt2h = (unsigned short*)(ws + off); off += (size_t)DIM * DIM * 2;
    unsigned short* Wt2l = (unsigned short*)(ws + off); off += (size_t)DIM * DIM * 2;
    unsigned short* Wt3h = (unsigned short*)(ws + off); off += (size_t)DIM * DIM * 2;
    unsigned short* Wt3l = (unsigned short*)(ws + off); off += (size_t)DIM * DIM * 2;
    int*      nbr    = (int*)(ws + off);      off += (size_t)BATCH * NNODE * KP1 * 4;
    int*      cand   = (int*)(ws + off);      off += (size_t)BATCH * NNODE * NCAND * 4;
    float*    sq     = (float*)(ws + off);    off += (size_t)BATCH * NNODE * 4;
    float*    mean   = (float*)(ws + off);    off += (size_t)BATCH * DIM * 4;
    unsigned* maxabs = (unsigned*)(ws + off); off += 256;
    float*    as_    = (float*)(ws + off);    off += (size_t)BATCH * NNODE * 4;
    float*    ad_    = (float*)(ws + off);    off += (size_t)BATCH * NNODE * 4;
    float*    g      = (float*)(ws + off);    off += (size_t)BATCH * DIM * 4;
    float*    part   = (float*)(ws + off);    off += (size_t)BATCH * NCH * DIM * 4;  // 512KB scratch
    (void)ws_size; (void)in_sizes; (void)n_in; (void)out_size;

    const dim3 cgrid(BATCH, DIM / 256, NCH);
    // ---- graph construction: approx bf16 MFMA distances + exact f32 re-rank ----
    colmean_part<<<cgrid, 256, 0, stream>>>(x, part);
    colmean_fin<<<BATCH * DIM / 256, 256, 0, stream>>>(part, mean);
    rowsq_kernel<<<BATCH * NNODE / 4, 256, 0, stream>>>(x, sq);
    xtobf_kernel<<<BATCH * NNODE * DIM / 1024, 256, 0, stream>>>(x, xh);
    dist_mfma<<<dim3(NNODE / BT, BATCH * NNODE / BT), 256, 0, stream>>>(xh, sq, d2);
    knn_kernel<<<BATCH * NNODE / 4, 256, 0, stream>>>(d2, cand);
    rerank_kernel<<<BATCH * NNODE / 4, 256, 0, stream>>>(x, sq, cand, nbr);
    // ---- weights transpose + split ----
    wsplit_kernel<<<dim3(16, 16), 256, 0, stream>>>(W1, Wt1h, Wt1l);
    wsplit_kernel<<<dim3(16, 16), 256, 0, stream>>>(W2, Wt2h, Wt2l);
    wsplit_kernel<<<dim3(16, 16), 256, 0, stream>>>(W3, Wt3h, Wt3l);
    // ---- normalize -> hA (split bf16); d2/xh dead from here ----
    init_maxabs<<<1, 64, 0, stream>>>(maxabs);
    maxabs_kernel<<<dim3(16, BATCH), 256, 0, stream>>>(x, mean, maxabs);
    normalize_kernel<<<BATCH * NNODE * DIM / 256, 256, 0, stream>>>(x, mean, maxabs, hA_hi, hA_lo);

    const dim3 ggrid(DIM / BT, BATCH * NNODE / BT);   // (4, 128)
    // layer 1
    gemm_mfma<<<ggrid, 256, 0, stream>>>(hA_hi, hA_lo, Wt1h, Wt1l, hp);
    attvec_kernel<<<BATCH * NNODE / 4, 256, 0, stream>>>(hp, asrc1, adst1, as_, ad_);
    aggr_kernel<1, 1><<<BATCH * NNODE / 4, 256, 0, stream>>>(hp, nbr, as_, ad_, b1, nullptr, hB_hi, hB_lo);
    // layer 2
    gemm_mfma<<<ggrid, 256, 0, stream>>>(hB_hi, hB_lo, Wt2h, Wt2l, hp);
    attvec_kernel<<<BATCH * NNODE / 4, 256, 0, stream>>>(hp, asrc2, adst2, as_, ad_);
    aggr_kernel<1, 1><<<BATCH * NNODE / 4, 256, 0, stream>>>(hp, nbr, as_, ad_, b2, nullptr, hA_hi, hA_lo);
    // layer 3
    gemm_mfma<<<ggrid, 256, 0, stream>>>(hA_hi, hA_lo, Wt3h, Wt3l, hp);
    attvec_kernel<<<BATCH * NNODE / 4, 256, 0, stream>>>(hp, asrc3, adst3, as_, ad_);
    aggr_kernel<0, 0><<<BATCH * NNODE / 4, 256, 0, stream>>>(hp, nbr, as_, ad_, b3, h3, nullptr, nullptr);
    // pool + classify
    maxpool_part<<<cgrid, 256, 0, stream>>>(h3, part);
    maxpool_fin<<<BATCH * DIM / 256, 256, 0, stream>>>(part, g);
    final_kernel<<<BATCH, 256, 0, stream>>>(g, Wc, bc, out);
}

// Round 11
// 422.562 us; speedup vs baseline: 2.8045x; 1.0008x over previous
//
#include <hip/hip_runtime.h>
#include <hip/hip_bf16.h>
#include <math.h>

#define BATCH 16
#define NNODE 1024
#define DIM   512
#define KNN   16
#define KP1   17
#define NCAND 18
#define NEG   0.2f
#define BT    128   // block tile
#define NCH   16    // n-chunks for column reductions

typedef __attribute__((ext_vector_type(8))) short bf16x8;
typedef __attribute__((ext_vector_type(4))) float f32x4;

__device__ __forceinline__ unsigned short f2bf(float f) {
    unsigned u = __float_as_uint(f);
    unsigned r = (u + 0x7FFFu + ((u >> 16) & 1u)) >> 16;   // RNE
    return (unsigned short)r;
}
__device__ __forceinline__ float bf2f(unsigned short h) {
    return __uint_as_float(((unsigned)h) << 16);
}
__device__ __forceinline__ void split_store(float v, unsigned short* hi, unsigned short* lo, size_t idx) {
    unsigned short h = f2bf(v);
    hi[idx] = h;
    lo[idx] = f2bf(v - bf2f(h));
}

// ---------------- zero maxabs + encoded max-pool accumulator ----------------
__global__ void init_misc(unsigned* __restrict__ maxabs, unsigned* __restrict__ genc) {
    int gid = blockIdx.x * 256 + threadIdx.x;
    if (gid < BATCH) maxabs[gid] = 0u;
    if (gid < BATCH * DIM) genc[gid] = 0u;        // enc(-INF) > 0, so 0 is identity
}

// ---------------- column mean, stage 1: partial sums over 64-node chunks ----------------
__global__ __launch_bounds__(256) void colmean_part(const float* __restrict__ x, float* __restrict__ part) {
    int b = blockIdx.x, dc = blockIdx.y, ch = blockIdx.z;
    int d = dc * 256 + threadIdx.x;
    const float* p = x + ((size_t)b * NNODE + ch * (NNODE / NCH)) * DIM + d;
    float s = 0.f;
    #pragma unroll 4
    for (int n = 0; n < NNODE / NCH; ++n) s += p[(size_t)n * DIM];
    part[((size_t)b * NCH + ch) * DIM + d] = s;
}
__global__ void colmean_fin(const float* __restrict__ part, float* __restrict__ mean) {
    int id = blockIdx.x * 256 + threadIdx.x;   // b*DIM + d
    int b = id >> 9, d = id & (DIM - 1);
    float s = 0.f;
    #pragma unroll
    for (int ch = 0; ch < NCH; ++ch) s += part[((size_t)b * NCH + ch) * DIM + d];
    mean[id] = s * (1.0f / NNODE);
}

// ---------------- fused: row squared norms + x -> bf16 (one pass over x) ----------------
__global__ __launch_bounds__(256) void rowsq_xtobf(const float* __restrict__ x,
                                                   float* __restrict__ sq,
                                                   unsigned short* __restrict__ xh) {
    int row = blockIdx.x * 4 + (threadIdx.x >> 6);
    int l = threadIdx.x & 63;
    const float* p = x + (size_t)row * DIM + l * 8;
    float4 a = *(const float4*)p;
    float4 b = *(const float4*)(p + 4);
    float s = a.x * a.x + a.y * a.y + a.z * a.z + a.w * a.w
            + b.x * b.x + b.y * b.y + b.z * b.z + b.w * b.w;
    ushort4 ha, hb;
    ha.x = f2bf(a.x); ha.y = f2bf(a.y); ha.z = f2bf(a.z); ha.w = f2bf(a.w);
    hb.x = f2bf(b.x); hb.y = f2bf(b.y); hb.z = f2bf(b.z); hb.w = f2bf(b.w);
    unsigned short* q = xh + (size_t)row * DIM + l * 8;
    *(ushort4*)q = ha;
    *(ushort4*)(q + 4) = hb;
    #pragma unroll
    for (int off = 32; off > 0; off >>= 1) s += __shfl_down(s, off, 64);
    if (l == 0) sq[row] = s;
}

// ---------------- approx distances via bf16 MFMA -> u32 selection keys ----------------
// key = (f32 bits of d2, truncated to top 22 bits) | node index; diag = 0xFFFFFFFF
__global__ __launch_bounds__(256, 2) void dist_mfma(const unsigned short* __restrict__ xh,
                                                    const float* __restrict__ sq,
                                                    unsigned* __restrict__ keys) {
    __shared__ unsigned short AhL[128][40], BhL[128][40];
    int mt = blockIdx.y;
    int b = mt >> 3;
    int m0 = mt * BT;
    int n0 = blockIdx.x * BT;
    int bn0 = b * NNODE + n0;
    int t = threadIdx.x;
    int lane = t & 63, w = t >> 6;
    int wm = (w >> 1) * 64, wn = (w & 1) * 64;
    int fr = lane & 15, fk = (lane >> 4) * 8;
    f32x4 acc[4][4];
    #pragma unroll
    for (int i = 0; i < 4; ++i)
        #pragma unroll
        for (int j = 0; j < 4; ++j) acc[i][j] = (f32x4){0.f, 0.f, 0.f, 0.f};

    for (int k0 = 0; k0 < DIM; k0 += 32) {
        if (k0) __syncthreads();
        #pragma unroll
        for (int p = 0; p < 2; ++p) {
            int u = t + p * 256;
            int row = u >> 2, seg = (u & 3) * 8;
            *(uint4*)&AhL[row][seg] = *(const uint4*)(xh + (size_t)(m0 + row) * DIM + k0 + seg);
            *(uint4*)&BhL[row][seg] = *(const uint4*)(xh + (size_t)(bn0 + row) * DIM + k0 + seg);
        }
        __syncthreads();
        bf16x8 ah[4], bh[4];
        #pragma unroll
        for (int i = 0; i < 4; ++i) {
            ah[i] = *(const bf16x8*)&AhL[wm + i * 16 + fr][fk];
            bh[i] = *(const bf16x8*)&BhL[wn + i * 16 + fr][fk];
        }
        #pragma unroll
        for (int i = 0; i < 4; ++i)
            #pragma unroll
            for (int j = 0; j < 4; ++j)
                acc[i][j] = __builtin_amdgcn_mfma_f32_16x16x32_bf16(ah[i], bh[j], acc[i][j], 0, 0, 0);
    }
    const float* sqb = sq + b * NNODE;
    int mloc0 = m0 - b * NNODE;
    #pragma unroll
    for (int i = 0; i < 4; ++i) {
        int mloc = mloc0 + wm + i * 16 + (lane >> 4) * 4;
        #pragma unroll
        for (int j = 0; j < 4; ++j) {
            int n = n0 + wn + j * 16 + fr;
            float sqn = sqb[n];
            #pragma unroll
            for (int r = 0; r < 4; ++r) {
                float val = sqb[mloc + r] + sqn - 2.f * acc[i][j][r];
                unsigned kv = (__float_as_uint(val) & 0xFFFFFC00u) | (unsigned)n;
                if (mloc + r == n) kv = 0xFFFFFFFFu;
                keys[((size_t)b * NNODE + mloc + r) * NNODE + n] = kv;
            }
        }
    }
}

// ---------------- top-18 smallest keys per row: threshold walk ----------------
__global__ __launch_bounds__(256) void knn_kernel(const unsigned* __restrict__ keys, int* __restrict__ cand) {
    int row = blockIdx.x * 4 + (threadIdx.x >> 6);   // b*N + n
    int l = threadIdx.x & 63;
    const unsigned* src = keys + (size_t)row * NNODE;
    unsigned key[16];
    #pragma unroll
    for (int j = 0; j < 16; ++j) key[j] = src[l + (j << 6)];
    int* dst = cand + row * NCAND;
    unsigned T = 0;
    for (int it = 0; it < NCAND; ++it) {
        unsigned lmin = 0xFFFFFFFFu;
        #pragma unroll
        for (int j = 0; j < 16; ++j) {
            unsigned k = (key[j] > T) ? key[j] : 0xFFFFFFFFu;
            lmin = min(lmin, k);
        }
        #pragma unroll
        for (int off = 1; off < 64; off <<= 1) {
            unsigned o = (unsigned)__shfl_xor((int)lmin, off, 64);
            lmin = min(lmin, o);
        }
        T = lmin;
        if (l == 0) dst[it] = (int)(lmin & 1023u);
    }
}

// ---------------- exact f32 re-rank: wave per row, in-register rank selection ----------------
// XCD-swizzled (b = bid%16). 3 gather batches of 6 (peak 48 VGPR of j-data).
__global__ __launch_bounds__(256) void rerank_kernel(const float* __restrict__ x,
                                                     const float* __restrict__ sq,
                                                     const int* __restrict__ cand,
                                                     int* __restrict__ nbr) {
    int bid = blockIdx.x;                 // 4096 blocks
    int b = bid & (BATCH - 1);
    int w = threadIdx.x >> 6, l = threadIdx.x & 63;
    int m = (bid >> 4) * 4 + w;
    int row = b * NNODE + m;
    const float* xb = x + (size_t)b * NNODE * DIM;
    const float* sqb = sq + b * NNODE;
    const float* xm = xb + (size_t)m * DIM;
    float4 m0v = *(const float4*)(xm + l * 8);
    float4 m1v = *(const float4*)(xm + l * 8 + 4);
    float sqm = sqb[m];

    int idx[NCAND];
    #pragma unroll
    for (int c = 0; c < NCAND; ++c) idx[c] = cand[row * NCAND + c];

    float s[NCAND];
    #pragma unroll
    for (int hf = 0; hf < 3; ++hf) {
        float4 j0[6], j1[6];
        #pragma unroll
        for (int i = 0; i < 6; ++i) {
            const float* xj = xb + (size_t)idx[hf * 6 + i] * DIM;
            j0[i] = *(const float4*)(xj + l * 8);
            j1[i] = *(const float4*)(xj + l * 8 + 4);
        }
        #pragma unroll
        for (int i = 0; i < 6; ++i)
            s[hf * 6 + i] = m0v.x * j0[i].x + m0v.y * j0[i].y + m0v.z * j0[i].z + m0v.w * j0[i].w
                          + m1v.x * j1[i].x + m1v.y * j1[i].y + m1v.z * j1[i].z + m1v.w * j1[i].w;
    }
    #pragma unroll
    for (int off = 32; off > 0; off >>= 1)
        #pragma unroll
        for (int c = 0; c < NCAND; ++c) s[c] += __shfl_xor(s[c], off, 64);

    // dv[c] identical on all lanes; lane l owns candidate l; rank = #{(dv,idx) < mine}
    float dv[NCAND];
    #pragma unroll
    for (int c = 0; c < NCAND; ++c) dv[c] = sqm + sqb[idx[c]] - 2.f * s[c];

    float mydv = 0.f; int myidx = 0;
    #pragma unroll
    for (int c = 0; c < NCAND; ++c)
        if (l == c) { mydv = dv[c]; myidx = idx[c]; }

    int rank = 0;
    #pragma unroll
    for (int c = 0; c < NCAND; ++c)
        rank += (dv[c] < mydv || (dv[c] == mydv && idx[c] < myidx)) ? 1 : 0;

    int* dst = nbr + row * KP1;
    if (l < NCAND && rank < KNN) dst[rank] = myidx;
    if (l == 0) dst[KNN] = m;
}

// ---------------- per-graph max|x - mean| ----------------
__global__ __launch_bounds__(256) void maxabs_kernel(const float* __restrict__ x,
                                                     const float* __restrict__ mean,
                                                     unsigned* __restrict__ maxabs) {
    int b = blockIdx.y;
    const float* p = x + ((size_t)b * NNODE + blockIdx.x * 64) * DIM;
    const float* mb = mean + b * DIM;
    float m = 0.f;
    for (int i = threadIdx.x; i < 64 * DIM; i += 256) {
        int d = i & (DIM - 1);
        m = fmaxf(m, fabsf(p[i] - mb[d]));
    }
    __shared__ float red[256];
    red[threadIdx.x] = m; __syncthreads();
    for (int s = 128; s > 0; s >>= 1) {
        if (threadIdx.x < s) red[threadIdx.x] = fmaxf(red[threadIdx.x], red[threadIdx.x + s]);
        __syncthreads();
    }
    if (threadIdx.x == 0) atomicMax(maxabs + b, __float_as_uint(red[0]));
}

// ---------------- h0 = (x - mean) * 0.999999/maxabs -> split bf16 hi/lo ----------------
__global__ void normalize_kernel(const float* __restrict__ x, const float* __restrict__ mean,
                                 const unsigned* __restrict__ maxabs,
                                 unsigned short* __restrict__ h_hi, unsigned short* __restrict__ h_lo) {
    int id = blockIdx.x * 256 + threadIdx.x;
    int b = id >> 19;
    int d = id & (DIM - 1);
    float scale = 0.999999f / __uint_as_float(maxabs[b]);
    float v = (x[id] - mean[b * DIM + d]) * scale;
    split_store(v, h_hi, h_lo, id);
}

// ---------------- W[512x512] -> Wt hi/lo bf16 [n][k], all 3 layers in one launch ----------------
__global__ void wsplit_kernel(const float* __restrict__ W1, const float* __restrict__ W2,
                              const float* __restrict__ W3,
                              unsigned short* __restrict__ Wh1, unsigned short* __restrict__ Wl1,
                              unsigned short* __restrict__ Wh2, unsigned short* __restrict__ Wl2,
                              unsigned short* __restrict__ Wh3, unsigned short* __restrict__ Wl3) {
    int z = blockIdx.z;
    const float* W = (z == 0) ? W1 : (z == 1) ? W2 : W3;
    unsigned short* Wh = (z == 0) ? Wh1 : (z == 1) ? Wh2 : Wh3;
    unsigned short* Wl = (z == 0) ? Wl1 : (z == 1) ? Wl2 : Wl3;
    __shared__ float tile[32][33];
    int bx = blockIdx.x * 32, by = blockIdx.y * 32;
    int tx = threadIdx.x & 31, ty = threadIdx.x >> 5;
    #pragma unroll
    for (int i = 0; i < 4; ++i)
        tile[ty + i * 8][tx] = W[(size_t)(by + ty + i * 8) * DIM + bx + tx];
    __syncthreads();
    #pragma unroll
    for (int i = 0; i < 4; ++i) {
        int n = bx + ty + i * 8;
        float v = tile[tx][ty + i * 8];
        split_store(v, Wh, Wl, (size_t)n * DIM + by + tx);
    }
}

// ---------------- C f32 = (Ah+Al) . (Wh+Wl), split-bf16 MFMA ----------------
__global__ __launch_bounds__(256, 2) void gemm_mfma(const unsigned short* __restrict__ Agh,
                                                    const unsigned short* __restrict__ Agl,
                                                    const unsigned short* __restrict__ Bgh,
                                                    const unsigned short* __restrict__ Bgl,
                                                    float* __restrict__ C) {
    __shared__ unsigned short AhL[128][40], AlL[128][40], BhL[128][40], BlL[128][40];
    int m0 = blockIdx.y * BT, n0 = blockIdx.x * BT;
    int t = threadIdx.x;
    int lane = t & 63, w = t >> 6;
    int wm = (w >> 1) * 64, wn = (w & 1) * 64;
    int fr = lane & 15, fk = (lane >> 4) * 8;
    f32x4 acc[4][4];
    #pragma unroll
    for (int i = 0; i < 4; ++i)
        #pragma unroll
        for (int j = 0; j < 4; ++j) acc[i][j] = (f32x4){0.f, 0.f, 0.f, 0.f};

    for (int k0 = 0; k0 < DIM; k0 += 32) {
        if (k0) __syncthreads();
        #pragma unroll
        for (int p = 0; p < 2; ++p) {
            int u = t + p * 256;
            int row = u >> 2, seg = (u & 3) * 8;
            *(uint4*)&AhL[row][seg] = *(const uint4*)(Agh + (size_t)(m0 + row) * DIM + k0 + seg);
            *(uint4*)&AlL[row][seg] = *(const uint4*)(Agl + (size_t)(m0 + row) * DIM + k0 + seg);
            *(uint4*)&BhL[row][seg] = *(const uint4*)(Bgh + (size_t)(n0 + row) * DIM + k0 + seg);
            *(uint4*)&BlL[row][seg] = *(const uint4*)(Bgl + (size_t)(n0 + row) * DIM + k0 + seg);
        }
        __syncthreads();
        bf16x8 ah[4], al[4], bh[4], bl[4];
        #pragma unroll
        for (int i = 0; i < 4; ++i) {
            ah[i] = *(const bf16x8*)&AhL[wm + i * 16 + fr][fk];
            al[i] = *(const bf16x8*)&AlL[wm + i * 16 + fr][fk];
            bh[i] = *(const bf16x8*)&BhL[wn + i * 16 + fr][fk];
            bl[i] = *(const bf16x8*)&BlL[wn + i * 16 + fr][fk];
        }
        #pragma unroll
        for (int i = 0; i < 4; ++i)
            #pragma unroll
            for (int j = 0; j < 4; ++j) {
                acc[i][j] = __builtin_amdgcn_mfma_f32_16x16x32_bf16(ah[i], bh[j], acc[i][j], 0, 0, 0);
                acc[i][j] = __builtin_amdgcn_mfma_f32_16x16x32_bf16(ah[i], bl[j], acc[i][j], 0, 0, 0);
                acc[i][j] = __builtin_amdgcn_mfma_f32_16x16x32_bf16(al[i], bh[j], acc[i][j], 0, 0, 0);
            }
    }
    #pragma unroll
    for (int i = 0; i < 4; ++i) {
        int mrow = m0 + wm + i * 16 + (lane >> 4) * 4;
        #pragma unroll
        for (int j = 0; j < 4; ++j) {
            int col = n0 + wn + j * 16 + fr;
            #pragma unroll
            for (int r = 0; r < 4; ++r)
                C[(size_t)(mrow + r) * DIM + col] = acc[i][j][r];
        }
    }
}

// ---------------- a_s = hp @ asrc, a_d = hp @ adst (float4 loads) ----------------
__global__ void attvec_kernel(const float* __restrict__ hp, const float* __restrict__ asrc,
                              const float* __restrict__ adst, float* __restrict__ as_,
                              float* __restrict__ ad_) {
    int row = blockIdx.x * 4 + (threadIdx.x >> 6);
    int lane = threadIdx.x & 63;
    const float4* p = (const float4*)(hp + (size_t)row * DIM);
    const float4* s4 = (const float4*)asrc;
    const float4* d4 = (const float4*)adst;
    float4 a0 = p[lane], a1 = p[lane + 64];
    float4 u0 = s4[lane], u1 = s4[lane + 64];
    float4 v0 = d4[lane], v1 = d4[lane + 64];
    float s = a0.x * u0.x + a0.y * u0.y + a0.z * u0.z + a0.w * u0.w
            + a1.x * u1.x + a1.y * u1.y + a1.z * u1.z + a1.w * u1.w;
    float d = a0.x * v0.x + a0.y * v0.y + a0.z * v0.z + a0.w * v0.w
            + a1.x * v1.x + a1.y * v1.y + a1.z * v1.z + a1.w * v1.w;
    #pragma unroll
    for (int off = 32; off > 0; off >>= 1) { s += __shfl_down(s, off, 64); d += __shfl_down(d, off, 64); }
    if (lane == 0) { as_[row] = s; ad_[row] = d; }
}

// ---------------- GAT attention + aggregation: wave-per-node, float4 gathers ----------------
template<int RELU, int SPLIT>
__global__ __launch_bounds__(256) void aggr_kernel(const float* __restrict__ hp, const int* __restrict__ nbr,
                                                   const float* __restrict__ as_, const float* __restrict__ ad_,
                                                   const float* __restrict__ bias,
                                                   float* __restrict__ outf,
                                                   unsigned short* __restrict__ oh,
                                                   unsigned short* __restrict__ ol) {
    __shared__ float attL[4][KP1];
    __shared__ int   jjL[4][KP1];
    int bid = blockIdx.x;                 // B*N/4 blocks
    int b = bid & (BATCH - 1);
    int w = threadIdx.x >> 6, l = threadIdx.x & 63;
    int n = (bid >> 4) * 4 + w;
    int id = b * NNODE + n;

    float e = -INFINITY;
    if (l < KP1) {
        int j = nbr[id * KP1 + l];
        jjL[w][l] = j;
        e = as_[b * NNODE + j] + ad_[id];
        e = (e >= 0.f) ? e : NEG * e;
    }
    float mx = e;
    #pragma unroll
    for (int off = 16; off > 0; off >>= 1) mx = fmaxf(mx, __shfl_xor(mx, off, 64));
    float ex = (l < KP1) ? expf(e - mx) : 0.f;
    float sm = ex;
    #pragma unroll
    for (int off = 16; off > 0; off >>= 1) sm += __shfl_xor(sm, off, 64);
    if (l < KP1) attL[w][l] = ex / sm;

    const float* base = hp + (size_t)b * NNODE * DIM;
    int d0 = l * 8;
    const float4* b4 = (const float4*)(bias + d0);
    float4 o0 = b4[0], o1 = b4[1];
    #pragma unroll
    for (int k = 0; k < KP1; ++k) {
        float a = attL[w][k];
        const float* vp = base + (size_t)jjL[w][k] * DIM + d0;
        float4 v0 = *(const float4*)vp;
        float4 v1 = *(const float4*)(vp + 4);
        o0.x += a * v0.x; o0.y += a * v0.y; o0.z += a * v0.z; o0.w += a * v0.w;
        o1.x += a * v1.x; o1.y += a * v1.y; o1.z += a * v1.z; o1.w += a * v1.w;
    }
    if (RELU) {
        o0.x = fmaxf(o0.x, 0.f); o0.y = fmaxf(o0.y, 0.f); o0.z = fmaxf(o0.z, 0.f); o0.w = fmaxf(o0.w, 0.f);
        o1.x = fmaxf(o1.x, 0.f); o1.y = fmaxf(o1.y, 0.f); o1.z = fmaxf(o1.z, 0.f); o1.w = fmaxf(o1.w, 0.f);
    }
    size_t idx = (size_t)id * DIM + d0;
    if (SPLIT) {
        float v[8] = {o0.x, o0.y, o0.z, o0.w, o1.x, o1.y, o1.z, o1.w};
        unsigned hi[4], lo[4];
        #pragma unroll
        for (int i = 0; i < 4; ++i) {
            unsigned short h0 = f2bf(v[2 * i]),     h1 = f2bf(v[2 * i + 1]);
            unsigned short l0 = f2bf(v[2 * i] - bf2f(h0));
            unsigned short l1 = f2bf(v[2 * i + 1] - bf2f(h1));
            hi[i] = (unsigned)h0 | ((unsigned)h1 << 16);
            lo[i] = (unsigned)l0 | ((unsigned)l1 << 16);
        }
        *(uint4*)(oh + idx) = *(uint4*)hi;
        *(uint4*)(ol + idx) = *(uint4*)lo;
    } else {
        *(float4*)(outf + idx) = o0;
        *(float4*)(outf + idx + 4) = o1;
    }
}

// ---------------- global max pool: single kernel, monotonic-encoded atomicMax ----------------
__global__ __launch_bounds__(256) void maxpool_atomic(const float* __restrict__ h, unsigned* __restrict__ genc) {
    int b = blockIdx.x, dc = blockIdx.y, ch = blockIdx.z;
    int d = dc * 256 + threadIdx.x;
    const float* p = h + ((size_t)b * NNODE + ch * (NNODE / NCH)) * DIM + d;
    float m = -INFINITY;
    #pragma unroll 4
    for (int n = 0; n < NNODE / NCH; ++n) m = fmaxf(m, p[(size_t)n * DIM]);
    unsigned u = __float_as_uint(m);
    unsigned enc = (u & 0x80000000u) ? ~u : (u | 0x80000000u);   // order-preserving f32->u32
    atomicMax(genc + b * DIM + d, enc);
}

// ---------------- final linear g @ Wc + bc (decodes genc) ----------------
__global__ void final_kernel(const unsigned* __restrict__ genc, const float* __restrict__ Wc,
                             const float* __restrict__ bc, float* __restrict__ out) {
    int b = blockIdx.x, t = threadIdx.x;
    float s0 = 0.f, s1 = 0.f;
    for (int d = t; d < DIM; d += 256) {
        unsigned e = genc[b * DIM + d];
        unsigned u = (e & 0x80000000u) ? (e ^ 0x80000000u) : ~e;
        float v = __uint_as_float(u);
        s0 += v * Wc[d * 2 + 0];
        s1 += v * Wc[d * 2 + 1];
    }
    __shared__ float r0[256], r1[256];
    r0[t] = s0; r1[t] = s1; __syncthreads();
    for (int s = 128; s > 0; s >>= 1) {
        if (t < s) { r0[t] += r0[t + s]; r1[t] += r1[t + s]; }
        __syncthreads();
    }
    if (t == 0) { out[b * 2] = r0[0] + bc[0]; out[b * 2 + 1] = r1[0] + bc[1]; }
}

extern "C" void kernel_launch(void* const* d_in, const int* in_sizes, int n_in,
                              void* d_out, int out_size, void* d_ws, size_t ws_size,
                              hipStream_t stream) {
    const float* x     = (const float*)d_in[0];
    const float* W1    = (const float*)d_in[1];
    const float* asrc1 = (const float*)d_in[2];
    const float* adst1 = (const float*)d_in[3];
    const float* b1    = (const float*)d_in[4];
    const float* W2    = (const float*)d_in[5];
    const float* asrc2 = (const float*)d_in[6];
    const float* adst2 = (const float*)d_in[7];
    const float* b2    = (const float*)d_in[8];
    const float* W3    = (const float*)d_in[9];
    const float* asrc3 = (const float*)d_in[10];
    const float* adst3 = (const float*)d_in[11];
    const float* b3    = (const float*)d_in[12];
    const float* Wc    = (const float*)d_in[13];
    const float* bc    = (const float*)d_in[14];
    float* out = (float*)d_out;

    char* ws = (char*)d_ws;
    unsigned*       keys  = (unsigned*)ws;                         // 64MB (graph build only)
    float*          hp    = (float*)ws;                            // 32MB f32
    unsigned short* hA_hi = (unsigned short*)(ws + (32ull << 20)); // 16MB
    unsigned short* hA_lo = (unsigned short*)(ws + (48ull << 20)); // 16MB
    unsigned short* xh    = (unsigned short*)(ws + (64ull << 20)); // 16MB (graph build only)
    unsigned short* hB_hi = (unsigned short*)(ws + (64ull << 20)); // 16MB
    unsigned short* hB_lo = (unsigned short*)(ws + (80ull << 20)); // 16MB
    float*          h3    = (float*)(ws + (64ull << 20));          // 32MB, alias hB
    size_t off = 96ull << 20;
    unsigned short* Wt1h = (unsigned short*)(ws + off); off += (size_t)DIM * DIM * 2;
    unsigned short* Wt1l = (unsigned short*)(ws + off); off += (size_t)DIM * DIM * 2;
    unsigned short* Wt2h = (unsigned short*)(ws + off); off += (size_t)DIM * DIM * 2;
    unsigned short* Wt2l = (unsigned short*)(ws + off); off += (size_t)DIM * DIM * 2;
    unsigned short* Wt3h = (unsigned short*)(ws + off); off += (size_t)DIM * DIM * 2;
    unsigned short* Wt3l = (unsigned short*)(ws + off); off += (size_t)DIM * DIM * 2;
    int*      nbr    = (int*)(ws + off);      off += (size_t)BATCH * NNODE * KP1 * 4;
    int*      cand   = (int*)(ws + off);      off += (size_t)BATCH * NNODE * NCAND * 4;
    float*    sq     = (float*)(ws + off);    off += (size_t)BATCH * NNODE * 4;
    float*    mean   = (float*)(ws + off);    off += (size_t)BATCH * DIM * 4;
    unsigned* maxabs = (unsigned*)(ws + off); off += 256;
    float*    as_    = (float*)(ws + off);    off += (size_t)BATCH * NNODE * 4;
    float*    ad_    = (float*)(ws + off);    off += (size_t)BATCH * NNODE * 4;
    unsigned* genc   = (unsigned*)(ws + off); off += (size_t)BATCH * DIM * 4;
    float*    part   = (float*)(ws + off);    off += (size_t)BATCH * NCH * DIM * 4;  // 512KB scratch
    (void)ws_size; (void)in_sizes; (void)n_in; (void)out_size;

    const dim3 cgrid(BATCH, DIM / 256, NCH);
    // ---- graph construction: approx bf16 MFMA keys + exact f32 re-rank ----
    init_misc<<<32, 256, 0, stream>>>(maxabs, genc);
    colmean_part<<<cgrid, 256, 0, stream>>>(x, part);
    colmean_fin<<<BATCH * DIM / 256, 256, 0, stream>>>(part, mean);
    rowsq_xtobf<<<BATCH * NNODE / 4, 256, 0, stream>>>(x, sq, xh);
    dist_mfma<<<dim3(NNODE / BT, BATCH * NNODE / BT), 256, 0, stream>>>(xh, sq, keys);
    knn_kernel<<<BATCH * NNODE / 4, 256, 0, stream>>>(keys, cand);
    rerank_kernel<<<BATCH * NNODE / 4, 256, 0, stream>>>(x, sq, cand, nbr);
    // ---- weights transpose + split (one launch) ----
    wsplit_kernel<<<dim3(16, 16, 3), 256, 0, stream>>>(W1, W2, W3, Wt1h, Wt1l, Wt2h, Wt2l, Wt3h, Wt3l);
    // ---- normalize -> hA (split bf16); keys/xh dead from here ----
    maxabs_kernel<<<dim3(16, BATCH), 256, 0, stream>>>(x, mean, maxabs);
    normalize_kernel<<<BATCH * NNODE * DIM / 256, 256, 0, stream>>>(x, mean, maxabs, hA_hi, hA_lo);

    const dim3 ggrid(DIM / BT, BATCH * NNODE / BT);   // (4, 128)
    // layer 1
    gemm_mfma<<<ggrid, 256, 0, stream>>>(hA_hi, hA_lo, Wt1h, Wt1l, hp);
    attvec_kernel<<<BATCH * NNODE / 4, 256, 0, stream>>>(hp, asrc1, adst1, as_, ad_);
    aggr_kernel<1, 1><<<BATCH * NNODE / 4, 256, 0, stream>>>(hp, nbr, as_, ad_, b1, nullptr, hB_hi, hB_lo);
    // layer 2
    gemm_mfma<<<ggrid, 256, 0, stream>>>(hB_hi, hB_lo, Wt2h, Wt2l, hp);
    attvec_kernel<<<BATCH * NNODE / 4, 256, 0, stream>>>(hp, asrc2, adst2, as_, ad_);
    aggr_kernel<1, 1><<<BATCH * NNODE / 4, 256, 0, stream>>>(hp, nbr, as_, ad_, b2, nullptr, hA_hi, hA_lo);
    // layer 3
    gemm_mfma<<<ggrid, 256, 0, stream>>>(hA_hi, hA_lo, Wt3h, Wt3l, hp);
    attvec_kernel<<<BATCH * NNODE / 4, 256, 0, stream>>>(hp, asrc3, adst3, as_, ad_);
    aggr_kernel<0, 0><<<BATCH * NNODE / 4, 256, 0, stream>>>(hp, nbr, as_, ad_, b3, h3, nullptr, nullptr);
    // pool + classify
    maxpool_atomic<<<cgrid, 256, 0, stream>>>(h3, genc);
    final_kernel<<<BATCH, 256, 0, stream>>>(genc, Wc, bc, out);
}

// Round 12
// 406.347 us; speedup vs baseline: 2.9164x; 1.0399x over previous
//
#include <hip/hip_runtime.h>
#include <hip/hip_bf16.h>
#include <math.h>

#define BATCH 16
#define NNODE 1024
#define DIM   512
#define KNN   16
#define KP1   17
#define NCAND 18
#define NEG   0.2f
#define BT    128   // block tile
#define NCH   16    // n-chunks for column reductions

typedef __attribute__((ext_vector_type(8))) short bf16x8;
typedef __attribute__((ext_vector_type(4))) float f32x4;

__device__ __forceinline__ unsigned short f2bf(float f) {
    unsigned u = __float_as_uint(f);
    unsigned r = (u + 0x7FFFu + ((u >> 16) & 1u)) >> 16;   // RNE
    return (unsigned short)r;
}
__device__ __forceinline__ float bf2f(unsigned short h) {
    return __uint_as_float(((unsigned)h) << 16);
}
__device__ __forceinline__ void split_store(float v, unsigned short* hi, unsigned short* lo, size_t idx) {
    unsigned short h = f2bf(v);
    hi[idx] = h;
    lo[idx] = f2bf(v - bf2f(h));
}

// ---------------- zero maxabs + encoded max-pool accumulator ----------------
__global__ void init_misc(unsigned* __restrict__ maxabs, unsigned* __restrict__ genc) {
    int gid = blockIdx.x * 256 + threadIdx.x;
    if (gid < BATCH) maxabs[gid] = 0u;
    if (gid < BATCH * DIM) genc[gid] = 0u;        // enc(-INF) > 0, so 0 is identity
}

// ---------------- column mean, stage 1: partial sums over 64-node chunks ----------------
__global__ __launch_bounds__(256) void colmean_part(const float* __restrict__ x, float* __restrict__ part) {
    int b = blockIdx.x, dc = blockIdx.y, ch = blockIdx.z;
    int d = dc * 256 + threadIdx.x;
    const float* p = x + ((size_t)b * NNODE + ch * (NNODE / NCH)) * DIM + d;
    float s = 0.f;
    #pragma unroll 4
    for (int n = 0; n < NNODE / NCH; ++n) s += p[(size_t)n * DIM];
    part[((size_t)b * NCH + ch) * DIM + d] = s;
}
__global__ void colmean_fin(const float* __restrict__ part, float* __restrict__ mean) {
    int id = blockIdx.x * 256 + threadIdx.x;   // b*DIM + d
    int b = id >> 9, d = id & (DIM - 1);
    float s = 0.f;
    #pragma unroll
    for (int ch = 0; ch < NCH; ++ch) s += part[((size_t)b * NCH + ch) * DIM + d];
    mean[id] = s * (1.0f / NNODE);
}

// ---------------- fused: row squared norms + x -> bf16 (one pass over x) ----------------
__global__ __launch_bounds__(256) void rowsq_xtobf(const float* __restrict__ x,
                                                   float* __restrict__ sq,
                                                   unsigned short* __restrict__ xh) {
    int row = blockIdx.x * 4 + (threadIdx.x >> 6);
    int l = threadIdx.x & 63;
    const float* p = x + (size_t)row * DIM + l * 8;
    float4 a = *(const float4*)p;
    float4 b = *(const float4*)(p + 4);
    float s = a.x * a.x + a.y * a.y + a.z * a.z + a.w * a.w
            + b.x * b.x + b.y * b.y + b.z * b.z + b.w * b.w;
    ushort4 ha, hb;
    ha.x = f2bf(a.x); ha.y = f2bf(a.y); ha.z = f2bf(a.z); ha.w = f2bf(a.w);
    hb.x = f2bf(b.x); hb.y = f2bf(b.y); hb.z = f2bf(b.z); hb.w = f2bf(b.w);
    unsigned short* q = xh + (size_t)row * DIM + l * 8;
    *(ushort4*)q = ha;
    *(ushort4*)(q + 4) = hb;
    #pragma unroll
    for (int off = 32; off > 0; off >>= 1) s += __shfl_down(s, off, 64);
    if (l == 0) sq[row] = s;
}

// ---------------- approx distances via bf16 MFMA -> u32 selection keys ----------------
// key = (f32 bits of d2, truncated to top 22 bits) | node index; diag = 0xFFFFFFFF
__global__ __launch_bounds__(256, 2) void dist_mfma(const unsigned short* __restrict__ xh,
                                                    const float* __restrict__ sq,
                                                    unsigned* __restrict__ keys) {
    __shared__ unsigned short AhL[128][40], BhL[128][40];
    int mt = blockIdx.y;
    int b = mt >> 3;
    int m0 = mt * BT;
    int n0 = blockIdx.x * BT;
    int bn0 = b * NNODE + n0;
    int t = threadIdx.x;
    int lane = t & 63, w = t >> 6;
    int wm = (w >> 1) * 64, wn = (w & 1) * 64;
    int fr = lane & 15, fk = (lane >> 4) * 8;
    f32x4 acc[4][4];
    #pragma unroll
    for (int i = 0; i < 4; ++i)
        #pragma unroll
        for (int j = 0; j < 4; ++j) acc[i][j] = (f32x4){0.f, 0.f, 0.f, 0.f};

    for (int k0 = 0; k0 < DIM; k0 += 32) {
        if (k0) __syncthreads();
        #pragma unroll
        for (int p = 0; p < 2; ++p) {
            int u = t + p * 256;
            int row = u >> 2, seg = (u & 3) * 8;
            *(uint4*)&AhL[row][seg] = *(const uint4*)(xh + (size_t)(m0 + row) * DIM + k0 + seg);
            *(uint4*)&BhL[row][seg] = *(const uint4*)(xh + (size_t)(bn0 + row) * DIM + k0 + seg);
        }
        __syncthreads();
        bf16x8 ah[4], bh[4];
        #pragma unroll
        for (int i = 0; i < 4; ++i) {
            ah[i] = *(const bf16x8*)&AhL[wm + i * 16 + fr][fk];
            bh[i] = *(const bf16x8*)&BhL[wn + i * 16 + fr][fk];
        }
        #pragma unroll
        for (int i = 0; i < 4; ++i)
            #pragma unroll
            for (int j = 0; j < 4; ++j)
                acc[i][j] = __builtin_amdgcn_mfma_f32_16x16x32_bf16(ah[i], bh[j], acc[i][j], 0, 0, 0);
    }
    const float* sqb = sq + b * NNODE;
    int mloc0 = m0 - b * NNODE;
    #pragma unroll
    for (int i = 0; i < 4; ++i) {
        int mloc = mloc0 + wm + i * 16 + (lane >> 4) * 4;
        #pragma unroll
        for (int j = 0; j < 4; ++j) {
            int n = n0 + wn + j * 16 + fr;
            float sqn = sqb[n];
            #pragma unroll
            for (int r = 0; r < 4; ++r) {
                float val = sqb[mloc + r] + sqn - 2.f * acc[i][j][r];
                unsigned kv = (__float_as_uint(val) & 0xFFFFFC00u) | (unsigned)n;
                if (mloc + r == n) kv = 0xFFFFFFFFu;
                keys[((size_t)b * NNODE + mloc + r) * NNODE + n] = kv;
            }
        }
    }
}

// ---------------- top-18 smallest keys per row: threshold walk ----------------
__global__ __launch_bounds__(256) void knn_kernel(const unsigned* __restrict__ keys, int* __restrict__ cand) {
    int row = blockIdx.x * 4 + (threadIdx.x >> 6);   // b*N + n
    int l = threadIdx.x & 63;
    const unsigned* src = keys + (size_t)row * NNODE;
    unsigned key[16];
    #pragma unroll
    for (int j = 0; j < 16; ++j) key[j] = src[l + (j << 6)];
    int* dst = cand + row * NCAND;
    unsigned T = 0;
    for (int it = 0; it < NCAND; ++it) {
        unsigned lmin = 0xFFFFFFFFu;
        #pragma unroll
        for (int j = 0; j < 16; ++j) {
            unsigned k = (key[j] > T) ? key[j] : 0xFFFFFFFFu;
            lmin = min(lmin, k);
        }
        #pragma unroll
        for (int off = 1; off < 64; off <<= 1) {
            unsigned o = (unsigned)__shfl_xor((int)lmin, off, 64);
            lmin = min(lmin, o);
        }
        T = lmin;
        if (l == 0) dst[it] = (int)(lmin & 1023u);
    }
}

// ---------------- exact f32 re-rank: wave per row (R9-measured structure, NCAND=18) ----------------
// XCD-swizzled (b = bid%16). All 18 dots in one wave; shfl_xor leaves every lane with all 18
// sums; lane l owns candidate l via static chain; rank = #{u64 key < mine}.
__global__ __launch_bounds__(256) void rerank_kernel(const float* __restrict__ x,
                                                     const float* __restrict__ sq,
                                                     const int* __restrict__ cand,
                                                     int* __restrict__ nbr) {
    int bid = blockIdx.x;                 // 4096 blocks
    int b = bid & (BATCH - 1);
    int w = threadIdx.x >> 6, l = threadIdx.x & 63;
    int m = (bid >> 4) * 4 + w;
    int row = b * NNODE + m;
    const float* xb = x + (size_t)b * NNODE * DIM;
    const float* sqb = sq + b * NNODE;
    const float* xm = xb + (size_t)m * DIM;
    float4 m0v = *(const float4*)(xm + l * 8);
    float4 m1v = *(const float4*)(xm + l * 8 + 4);
    float sqm = sqb[m];

    int idx[NCAND];
    #pragma unroll
    for (int c = 0; c < NCAND; ++c) idx[c] = cand[row * NCAND + c];

    float s[NCAND];
    #pragma unroll
    for (int half = 0; half < 2; ++half) {
        float4 j0[9], j1[9];
        #pragma unroll
        for (int i = 0; i < 9; ++i) {
            const float* xj = xb + (size_t)idx[half * 9 + i] * DIM;
            j0[i] = *(const float4*)(xj + l * 8);
            j1[i] = *(const float4*)(xj + l * 8 + 4);
        }
        #pragma unroll
        for (int i = 0; i < 9; ++i)
            s[half * 9 + i] = m0v.x * j0[i].x + m0v.y * j0[i].y + m0v.z * j0[i].z + m0v.w * j0[i].w
                            + m1v.x * j1[i].x + m1v.y * j1[i].y + m1v.z * j1[i].z + m1v.w * j1[i].w;
    }
    #pragma unroll
    for (int off = 32; off > 0; off >>= 1)
        #pragma unroll
        for (int c = 0; c < NCAND; ++c) s[c] += __shfl_xor(s[c], off, 64);

    unsigned long long key[NCAND];
    #pragma unroll
    for (int c = 0; c < NCAND; ++c) {
        float dv = sqm + sqb[idx[c]] - 2.f * s[c];
        key[c] = ((unsigned long long)__float_as_uint(dv) << 32) | (unsigned)idx[c];
    }
    unsigned long long mykey = ~0ull;
    int myidx = 0;
    #pragma unroll
    for (int c = 0; c < NCAND; ++c) {
        if (l == c) { mykey = key[c]; myidx = idx[c]; }
    }
    int rank = 0;
    #pragma unroll
    for (int c = 0; c < NCAND; ++c) rank += (key[c] < mykey) ? 1 : 0;

    int* dst = nbr + row * KP1;
    if (l < NCAND && rank < KNN) dst[rank] = myidx;
    if (l == 0) dst[KNN] = m;
}

// ---------------- per-graph max|x - mean| ----------------
__global__ __launch_bounds__(256) void maxabs_kernel(const float* __restrict__ x,
                                                     const float* __restrict__ mean,
                                                     unsigned* __restrict__ maxabs) {
    int b = blockIdx.y;
    const float* p = x + ((size_t)b * NNODE + blockIdx.x * 64) * DIM;
    const float* mb = mean + b * DIM;
    float m = 0.f;
    for (int i = threadIdx.x; i < 64 * DIM; i += 256) {
        int d = i & (DIM - 1);
        m = fmaxf(m, fabsf(p[i] - mb[d]));
    }
    __shared__ float red[256];
    red[threadIdx.x] = m; __syncthreads();
    for (int s = 128; s > 0; s >>= 1) {
        if (threadIdx.x < s) red[threadIdx.x] = fmaxf(red[threadIdx.x], red[threadIdx.x + s]);
        __syncthreads();
    }
    if (threadIdx.x == 0) atomicMax(maxabs + b, __float_as_uint(red[0]));
}

// ---------------- h0 = (x - mean) * 0.999999/maxabs -> split bf16 hi/lo ----------------
__global__ void normalize_kernel(const float* __restrict__ x, const float* __restrict__ mean,
                                 const unsigned* __restrict__ maxabs,
                                 unsigned short* __restrict__ h_hi, unsigned short* __restrict__ h_lo) {
    int id = blockIdx.x * 256 + threadIdx.x;
    int b = id >> 19;
    int d = id & (DIM - 1);
    float scale = 0.999999f / __uint_as_float(maxabs[b]);
    float v = (x[id] - mean[b * DIM + d]) * scale;
    split_store(v, h_hi, h_lo, id);
}

// ---------------- W[512x512] -> Wt hi/lo bf16 [n][k], all 3 layers in one launch ----------------
__global__ void wsplit_kernel(const float* __restrict__ W1, const float* __restrict__ W2,
                              const float* __restrict__ W3,
                              unsigned short* __restrict__ Wh1, unsigned short* __restrict__ Wl1,
                              unsigned short* __restrict__ Wh2, unsigned short* __restrict__ Wl2,
                              unsigned short* __restrict__ Wh3, unsigned short* __restrict__ Wl3) {
    int z = blockIdx.z;
    const float* W = (z == 0) ? W1 : (z == 1) ? W2 : W3;
    unsigned short* Wh = (z == 0) ? Wh1 : (z == 1) ? Wh2 : Wh3;
    unsigned short* Wl = (z == 0) ? Wl1 : (z == 1) ? Wl2 : Wl3;
    __shared__ float tile[32][33];
    int bx = blockIdx.x * 32, by = blockIdx.y * 32;
    int tx = threadIdx.x & 31, ty = threadIdx.x >> 5;
    #pragma unroll
    for (int i = 0; i < 4; ++i)
        tile[ty + i * 8][tx] = W[(size_t)(by + ty + i * 8) * DIM + bx + tx];
    __syncthreads();
    #pragma unroll
    for (int i = 0; i < 4; ++i) {
        int n = bx + ty + i * 8;
        float v = tile[tx][ty + i * 8];
        split_store(v, Wh, Wl, (size_t)n * DIM + by + tx);
    }
}

// ---------------- C f32 = (Ah+Al) . (Wh+Wl), split-bf16 MFMA (product-major order) ----------------
__global__ __launch_bounds__(256, 2) void gemm_mfma(const unsigned short* __restrict__ Agh,
                                                    const unsigned short* __restrict__ Agl,
                                                    const unsigned short* __restrict__ Bgh,
                                                    const unsigned short* __restrict__ Bgl,
                                                    float* __restrict__ C) {
    __shared__ unsigned short AhL[128][40], AlL[128][40], BhL[128][40], BlL[128][40];
    int m0 = blockIdx.y * BT, n0 = blockIdx.x * BT;
    int t = threadIdx.x;
    int lane = t & 63, w = t >> 6;
    int wm = (w >> 1) * 64, wn = (w & 1) * 64;
    int fr = lane & 15, fk = (lane >> 4) * 8;
    f32x4 acc[4][4];
    #pragma unroll
    for (int i = 0; i < 4; ++i)
        #pragma unroll
        for (int j = 0; j < 4; ++j) acc[i][j] = (f32x4){0.f, 0.f, 0.f, 0.f};

    for (int k0 = 0; k0 < DIM; k0 += 32) {
        if (k0) __syncthreads();
        #pragma unroll
        for (int p = 0; p < 2; ++p) {
            int u = t + p * 256;
            int row = u >> 2, seg = (u & 3) * 8;
            *(uint4*)&AhL[row][seg] = *(const uint4*)(Agh + (size_t)(m0 + row) * DIM + k0 + seg);
            *(uint4*)&AlL[row][seg] = *(const uint4*)(Agl + (size_t)(m0 + row) * DIM + k0 + seg);
            *(uint4*)&BhL[row][seg] = *(const uint4*)(Bgh + (size_t)(n0 + row) * DIM + k0 + seg);
            *(uint4*)&BlL[row][seg] = *(const uint4*)(Bgl + (size_t)(n0 + row) * DIM + k0 + seg);
        }
        __syncthreads();
        bf16x8 ah[4], al[4], bh[4], bl[4];
        #pragma unroll
        for (int i = 0; i < 4; ++i) {
            ah[i] = *(const bf16x8*)&AhL[wm + i * 16 + fr][fk];
            al[i] = *(const bf16x8*)&AlL[wm + i * 16 + fr][fk];
            bh[i] = *(const bf16x8*)&BhL[wn + i * 16 + fr][fk];
            bl[i] = *(const bf16x8*)&BlL[wn + i * 16 + fr][fk];
        }
        // product-major: consecutive MFMAs hit different acc[i][j] (reuse distance 16,
        // vs 3 dependent back-to-back in the fragment-major order)
        #pragma unroll
        for (int i = 0; i < 4; ++i)
            #pragma unroll
            for (int j = 0; j < 4; ++j)
                acc[i][j] = __builtin_amdgcn_mfma_f32_16x16x32_bf16(ah[i], bh[j], acc[i][j], 0, 0, 0);
        #pragma unroll
        for (int i = 0; i < 4; ++i)
            #pragma unroll
            for (int j = 0; j < 4; ++j)
                acc[i][j] = __builtin_amdgcn_mfma_f32_16x16x32_bf16(ah[i], bl[j], acc[i][j], 0, 0, 0);
        #pragma unroll
        for (int i = 0; i < 4; ++i)
            #pragma unroll
            for (int j = 0; j < 4; ++j)
                acc[i][j] = __builtin_amdgcn_mfma_f32_16x16x32_bf16(al[i], bh[j], acc[i][j], 0, 0, 0);
    }
    #pragma unroll
    for (int i = 0; i < 4; ++i) {
        int mrow = m0 + wm + i * 16 + (lane >> 4) * 4;
        #pragma unroll
        for (int j = 0; j < 4; ++j) {
            int col = n0 + wn + j * 16 + fr;
            #pragma unroll
            for (int r = 0; r < 4; ++r)
                C[(size_t)(mrow + r) * DIM + col] = acc[i][j][r];
        }
    }
}

// ---------------- a_s = hp @ asrc, a_d = hp @ adst (float4 loads) ----------------
__global__ void attvec_kernel(const float* __restrict__ hp, const float* __restrict__ asrc,
                              const float* __restrict__ adst, float* __restrict__ as_,
                              float* __restrict__ ad_) {
    int row = blockIdx.x * 4 + (threadIdx.x >> 6);
    int lane = threadIdx.x & 63;
    const float4* p = (const float4*)(hp + (size_t)row * DIM);
    const float4* s4 = (const float4*)asrc;
    const float4* d4 = (const float4*)adst;
    float4 a0 = p[lane], a1 = p[lane + 64];
    float4 u0 = s4[lane], u1 = s4[lane + 64];
    float4 v0 = d4[lane], v1 = d4[lane + 64];
    float s = a0.x * u0.x + a0.y * u0.y + a0.z * u0.z + a0.w * u0.w
            + a1.x * u1.x + a1.y * u1.y + a1.z * u1.z + a1.w * u1.w;
    float d = a0.x * v0.x + a0.y * v0.y + a0.z * v0.z + a0.w * v0.w
            + a1.x * v1.x + a1.y * v1.y + a1.z * v1.z + a1.w * v1.w;
    #pragma unroll
    for (int off = 32; off > 0; off >>= 1) { s += __shfl_down(s, off, 64); d += __shfl_down(d, off, 64); }
    if (lane == 0) { as_[row] = s; ad_[row] = d; }
}

// ---------------- GAT attention + aggregation: wave-per-node, float4 gathers ----------------
template<int RELU, int SPLIT>
__global__ __launch_bounds__(256) void aggr_kernel(const float* __restrict__ hp, const int* __restrict__ nbr,
                                                   const float* __restrict__ as_, const float* __restrict__ ad_,
                                                   const float* __restrict__ bias,
                                                   float* __restrict__ outf,
                                                   unsigned short* __restrict__ oh,
                                                   unsigned short* __restrict__ ol) {
    __shared__ float attL[4][KP1];
    __shared__ int   jjL[4][KP1];
    int bid = blockIdx.x;                 // B*N/4 blocks
    int b = bid & (BATCH - 1);
    int w = threadIdx.x >> 6, l = threadIdx.x & 63;
    int n = (bid >> 4) * 4 + w;
    int id = b * NNODE + n;

    float e = -INFINITY;
    if (l < KP1) {
        int j = nbr[id * KP1 + l];
        jjL[w][l] = j;
        e = as_[b * NNODE + j] + ad_[id];
        e = (e >= 0.f) ? e : NEG * e;
    }
    float mx = e;
    #pragma unroll
    for (int off = 16; off > 0; off >>= 1) mx = fmaxf(mx, __shfl_xor(mx, off, 64));
    float ex = (l < KP1) ? expf(e - mx) : 0.f;
    float sm = ex;
    #pragma unroll
    for (int off = 16; off > 0; off >>= 1) sm += __shfl_xor(sm, off, 64);
    if (l < KP1) attL[w][l] = ex / sm;

    const float* base = hp + (size_t)b * NNODE * DIM;
    int d0 = l * 8;
    const float4* b4 = (const float4*)(bias + d0);
    float4 o0 = b4[0], o1 = b4[1];
    #pragma unroll
    for (int k = 0; k < KP1; ++k) {
        float a = attL[w][k];
        const float* vp = base + (size_t)jjL[w][k] * DIM + d0;
        float4 v0 = *(const float4*)vp;
        float4 v1 = *(const float4*)(vp + 4);
        o0.x += a * v0.x; o0.y += a * v0.y; o0.z += a * v0.z; o0.w += a * v0.w;
        o1.x += a * v1.x; o1.y += a * v1.y; o1.z += a * v1.z; o1.w += a * v1.w;
    }
    if (RELU) {
        o0.x = fmaxf(o0.x, 0.f); o0.y = fmaxf(o0.y, 0.f); o0.z = fmaxf(o0.z, 0.f); o0.w = fmaxf(o0.w, 0.f);
        o1.x = fmaxf(o1.x, 0.f); o1.y = fmaxf(o1.y, 0.f); o1.z = fmaxf(o1.z, 0.f); o1.w = fmaxf(o1.w, 0.f);
    }
    size_t idx = (size_t)id * DIM + d0;
    if (SPLIT) {
        float v[8] = {o0.x, o0.y, o0.z, o0.w, o1.x, o1.y, o1.z, o1.w};
        unsigned hi[4], lo[4];
        #pragma unroll
        for (int i = 0; i < 4; ++i) {
            unsigned short h0 = f2bf(v[2 * i]),     h1 = f2bf(v[2 * i + 1]);
            unsigned short l0 = f2bf(v[2 * i] - bf2f(h0));
            unsigned short l1 = f2bf(v[2 * i + 1] - bf2f(h1));
            hi[i] = (unsigned)h0 | ((unsigned)h1 << 16);
            lo[i] = (unsigned)l0 | ((unsigned)l1 << 16);
        }
        *(uint4*)(oh + idx) = *(uint4*)hi;
        *(uint4*)(ol + idx) = *(uint4*)lo;
    } else {
        *(float4*)(outf + idx) = o0;
        *(float4*)(outf + idx + 4) = o1;
    }
}

// ---------------- global max pool: single kernel, monotonic-encoded atomicMax ----------------
__global__ __launch_bounds__(256) void maxpool_atomic(const float* __restrict__ h, unsigned* __restrict__ genc) {
    int b = blockIdx.x, dc = blockIdx.y, ch = blockIdx.z;
    int d = dc * 256 + threadIdx.x;
    const float* p = h + ((size_t)b * NNODE + ch * (NNODE / NCH)) * DIM + d;
    float m = -INFINITY;
    #pragma unroll 4
    for (int n = 0; n < NNODE / NCH; ++n) m = fmaxf(m, p[(size_t)n * DIM]);
    unsigned u = __float_as_uint(m);
    unsigned enc = (u & 0x80000000u) ? ~u : (u | 0x80000000u);   // order-preserving f32->u32
    atomicMax(genc + b * DIM + d, enc);
}

// ---------------- final linear g @ Wc + bc (decodes genc) ----------------
__global__ void final_kernel(const unsigned* __restrict__ genc, const float* __restrict__ Wc,
                             const float* __restrict__ bc, float* __restrict__ out) {
    int b = blockIdx.x, t = threadIdx.x;
    float s0 = 0.f, s1 = 0.f;
    for (int d = t; d < DIM; d += 256) {
        unsigned e = genc[b * DIM + d];
        unsigned u = (e & 0x80000000u) ? (e ^ 0x80000000u) : ~e;
        float v = __uint_as_float(u);
        s0 += v * Wc[d * 2 + 0];
        s1 += v * Wc[d * 2 + 1];
    }
    __shared__ float r0[256], r1[256];
    r0[t] = s0; r1[t] = s1; __syncthreads();
    for (int s = 128; s > 0; s >>= 1) {
        if (t < s) { r0[t] += r0[t + s]; r1[t] += r1[t + s]; }
        __syncthreads();
    }
    if (t == 0) { out[b * 2] = r0[0] + bc[0]; out[b * 2 + 1] = r1[0] + bc[1]; }
}

extern "C" void kernel_launch(void* const* d_in, const int* in_sizes, int n_in,
                              void* d_out, int out_size, void* d_ws, size_t ws_size,
                              hipStream_t stream) {
    const float* x     = (const float*)d_in[0];
    const float* W1    = (const float*)d_in[1];
    const float* asrc1 = (const float*)d_in[2];
    const float* adst1 = (const float*)d_in[3];
    const float* b1    = (const float*)d_in[4];
    const float* W2    = (const float*)d_in[5];
    const float* asrc2 = (const float*)d_in[6];
    const float* adst2 = (const float*)d_in[7];
    const float* b2    = (const float*)d_in[8];
    const float* W3    = (const float*)d_in[9];
    const float* asrc3 = (const float*)d_in[10];
    const float* adst3 = (const float*)d_in[11];
    const float* b3    = (const float*)d_in[12];
    const float* Wc    = (const float*)d_in[13];
    const float* bc    = (const float*)d_in[14];
    float* out = (float*)d_out;

    char* ws = (char*)d_ws;
    unsigned*       keys  = (unsigned*)ws;                         // 64MB (graph build only)
    float*          hp    = (float*)ws;                            // 32MB f32
    unsigned short* hA_hi = (unsigned short*)(ws + (32ull << 20)); // 16MB
    unsigned short* hA_lo = (unsigned short*)(ws + (48ull << 20)); // 16MB
    unsigned short* xh    = (unsigned short*)(ws + (64ull << 20)); // 16MB (graph build only)
    unsigned short* hB_hi = (unsigned short*)(ws + (64ull << 20)); // 16MB
    unsigned short* hB_lo = (unsigned short*)(ws + (80ull << 20)); // 16MB
    float*          h3    = (float*)(ws + (64ull << 20));          // 32MB, alias hB
    size_t off = 96ull << 20;
    unsigned short* Wt1h = (unsigned short*)(ws + off); off += (size_t)DIM * DIM * 2;
    unsigned short* Wt1l = (unsigned short*)(ws + off); off += (size_t)DIM * DIM * 2;
    unsigned short* Wt2h = (unsigned short*)(ws + off); off += (size_t)DIM * DIM * 2;
    unsigned short* Wt2l = (unsigned short*)(ws + off); off += (size_t)DIM * DIM * 2;
    unsigned short* Wt3h = (unsigned short*)(ws + off); off += (size_t)DIM * DIM * 2;
    unsigned short* Wt3l = (unsigned short*)(ws + off); off += (size_t)DIM * DIM * 2;
    int*      nbr    = (int*)(ws + off);      off += (size_t)BATCH * NNODE * KP1 * 4;
    int*      cand   = (int*)(ws + off);      off += (size_t)BATCH * NNODE * NCAND * 4;
    float*    sq     = (float*)(ws + off);    off += (size_t)BATCH * NNODE * 4;
    float*    mean   = (float*)(ws + off);    off += (size_t)BATCH * DIM * 4;
    unsigned* maxabs = (unsigned*)(ws + off); off += 256;
    float*    as_    = (float*)(ws + off);    off += (size_t)BATCH * NNODE * 4;
    float*    ad_    = (float*)(ws + off);    off += (size_t)BATCH * NNODE * 4;
    unsigned* genc   = (unsigned*)(ws + off); off += (size_t)BATCH * DIM * 4;
    float*    part   = (float*)(ws + off);    off += (size_t)BATCH * NCH * DIM * 4;  // 512KB scratch
    (void)ws_size; (void)in_sizes; (void)n_in; (void)out_size;

    const dim3 cgrid(BATCH, DIM / 256, NCH);
    // ---- graph construction: approx bf16 MFMA keys + exact f32 re-rank ----
    init_misc<<<32, 256, 0, stream>>>(maxabs, genc);
    colmean_part<<<cgrid, 256, 0, stream>>>(x, part);
    colmean_fin<<<BATCH * DIM / 256, 256, 0, stream>>>(part, mean);
    rowsq_xtobf<<<BATCH * NNODE / 4, 256, 0, stream>>>(x, sq, xh);
    dist_mfma<<<dim3(NNODE / BT, BATCH * NNODE / BT), 256, 0, stream>>>(xh, sq, keys);
    knn_kernel<<<BATCH * NNODE / 4, 256, 0, stream>>>(keys, cand);
    rerank_kernel<<<BATCH * NNODE / 4, 256, 0, stream>>>(x, sq, cand, nbr);
    // ---- weights transpose + split (one launch) ----
    wsplit_kernel<<<dim3(16, 16, 3), 256, 0, stream>>>(W1, W2, W3, Wt1h, Wt1l, Wt2h, Wt2l, Wt3h, Wt3l);
    // ---- normalize -> hA (split bf16); keys/xh dead from here ----
    maxabs_kernel<<<dim3(16, BATCH), 256, 0, stream>>>(x, mean, maxabs);
    normalize_kernel<<<BATCH * NNODE * DIM / 256, 256, 0, stream>>>(x, mean, maxabs, hA_hi, hA_lo);

    const dim3 ggrid(DIM / BT, BATCH * NNODE / BT);   // (4, 128)
    // layer 1
    gemm_mfma<<<ggrid, 256, 0, stream>>>(hA_hi, hA_lo, Wt1h, Wt1l, hp);
    attvec_kernel<<<BATCH * NNODE / 4, 256, 0, stream>>>(hp, asrc1, adst1, as_, ad_);
    aggr_kernel<1, 1><<<BATCH * NNODE / 4, 256, 0, stream>>>(hp, nbr, as_, ad_, b1, nullptr, hB_hi, hB_lo);
    // layer 2
    gemm_mfma<<<ggrid, 256, 0, stream>>>(hB_hi, hB_lo, Wt2h, Wt2l, hp);
    attvec_kernel<<<BATCH * NNODE / 4, 256, 0, stream>>>(hp, asrc2, adst2, as_, ad_);
    aggr_kernel<1, 1><<<BATCH * NNODE / 4, 256, 0, stream>>>(hp, nbr, as_, ad_, b2, nullptr, hA_hi, hA_lo);
    // layer 3
    gemm_mfma<<<ggrid, 256, 0, stream>>>(hA_hi, hA_lo, Wt3h, Wt3l, hp);
    attvec_kernel<<<BATCH * NNODE / 4, 256, 0, stream>>>(hp, asrc3, adst3, as_, ad_);
    aggr_kernel<0, 0><<<BATCH * NNODE / 4, 256, 0, stream>>>(hp, nbr, as_, ad_, b3, h3, nullptr, nullptr);
    // pool + classify
    maxpool_atomic<<<cgrid, 256, 0, stream>>>(h3, genc);
    final_kernel<<<BATCH, 256, 0, stream>>>(genc, Wc, bc, out);
}